// Round 1
// baseline (5476.550 us; speedup 1.0000x reference)
//
#include <hip/hip_runtime.h>
#include <hip/hip_bf16.h>
#include <math.h>

#define T_TOK 2048
#define B_SZ 2
#define L_SEQ 1024
#define D_MOD 1024
#define N_H 16
#define N_KV 4
#define N_CH 8
#define N_E 8
#define FF_DIM 4096
#define DC_K 4
#define EPS_F 1e-6f

__device__ __forceinline__ float gelu_exact(float x) {
    return 0.5f * x * (1.0f + erff(x * 0.70710678118654752f));
}

// ---------------- RMSNorm: one block per row, 256 threads, D=1024 ----------------
__global__ __launch_bounds__(256) void rmsnorm_kernel(const float* __restrict__ x,
                                                      const float* __restrict__ w,
                                                      float* __restrict__ out) {
    int row = blockIdx.x;
    int tid = threadIdx.x;
    const float* xr = x + (size_t)row * D_MOD;
    float4 v = ((const float4*)xr)[tid];
    float ss = v.x * v.x + v.y * v.y + v.z * v.z + v.w * v.w;
    __shared__ float red[256];
    red[tid] = ss;
    __syncthreads();
    for (int s = 128; s > 0; s >>= 1) {
        if (tid < s) red[tid] += red[tid + s];
        __syncthreads();
    }
    float mean = red[0] * (1.0f / D_MOD);
    float inv = 1.0f / sqrtf(mean + EPS_F);
    float4 wv = ((const float4*)w)[tid];
    float4 o;
    o.x = v.x * inv * wv.x;
    o.y = v.y * inv * wv.y;
    o.z = v.z * inv * wv.z;
    o.w = v.w * inv * wv.w;
    ((float4*)(out + (size_t)row * D_MOD))[tid] = o;
}

// ---------------- Tiled GEMM: C[M,N] = A[M,K]@B[K,N] (+bias)(+res) ----------------
// 64x64 tile, BK=16, 256 threads, 4x4 per thread. M%64==0, N%64==0, K%16==0.
__global__ __launch_bounds__(256) void gemm_kernel(const float* __restrict__ A,
                                                   const float* __restrict__ B,
                                                   const float* __restrict__ bias,
                                                   const float* __restrict__ res,
                                                   float* __restrict__ C,
                                                   int M, int N, int K) {
    __shared__ float As[16][64];
    __shared__ float Bs[16][64];
    int tid = threadIdx.x;
    int row0 = blockIdx.y * 64, col0 = blockIdx.x * 64;
    int am = tid >> 2, ak = (tid & 3) << 2;
    int bk = tid >> 4, bn = (tid & 15) << 2;
    int tm = (tid >> 4) << 2, tn = (tid & 15) << 2;
    float acc[4][4] = {};
    const float* Ap = A + (size_t)(row0 + am) * K + ak;
    const float* Bp = B + (size_t)bk * N + col0 + bn;
    for (int k0 = 0; k0 < K; k0 += 16) {
        float4 a4 = *(const float4*)(Ap + k0);
        float4 b4 = *(const float4*)(Bp + (size_t)k0 * N);
        As[ak + 0][am] = a4.x;
        As[ak + 1][am] = a4.y;
        As[ak + 2][am] = a4.z;
        As[ak + 3][am] = a4.w;
        *(float4*)&Bs[bk][bn] = b4;
        __syncthreads();
#pragma unroll
        for (int kk = 0; kk < 16; ++kk) {
            float4 a = *(const float4*)&As[kk][tm];
            float4 b = *(const float4*)&Bs[kk][tn];
            acc[0][0] += a.x * b.x; acc[0][1] += a.x * b.y; acc[0][2] += a.x * b.z; acc[0][3] += a.x * b.w;
            acc[1][0] += a.y * b.x; acc[1][1] += a.y * b.y; acc[1][2] += a.y * b.z; acc[1][3] += a.y * b.w;
            acc[2][0] += a.z * b.x; acc[2][1] += a.z * b.y; acc[2][2] += a.z * b.z; acc[2][3] += a.z * b.w;
            acc[3][0] += a.w * b.x; acc[3][1] += a.w * b.y; acc[3][2] += a.w * b.z; acc[3][3] += a.w * b.w;
        }
        __syncthreads();
    }
#pragma unroll
    for (int i = 0; i < 4; ++i) {
        int r = row0 + tm + i;
#pragma unroll
        for (int j = 0; j < 4; ++j) {
            int c = col0 + tn + j;
            float v = acc[i][j];
            if (bias) v += bias[c];
            if (res) v += res[(size_t)r * N + c];
            C[(size_t)r * N + c] = v;
        }
    }
}

// ---------------- Attention: one block (256 thr) per (b, h, q-row) ----------------
// Q: [B,L,nh,HD], K/V: [B,L,nkv,HD], O: [B,L,nh,HD]. Full (non-causal) softmax.
template <int HD>
__global__ __launch_bounds__(256) void attn_kernel(const float* __restrict__ Q,
                                                   const float* __restrict__ Km,
                                                   const float* __restrict__ Vm,
                                                   float* __restrict__ O,
                                                   int nh, int nkv, float scale) {
    int qpos = blockIdx.x, h = blockIdx.y, b = blockIdx.z;
    int kvh = h / (nh / nkv);
    int Dq = nh * HD, Dk = nkv * HD;
    __shared__ float qs[HD];
    __shared__ float sc[L_SEQ];
    __shared__ float red[256];
    int tid = threadIdx.x;
    const float* qrow = Q + (size_t)(b * L_SEQ + qpos) * Dq + h * HD;
    for (int d = tid; d < HD; d += 256) qs[d] = qrow[d] * scale;
    __syncthreads();
    const float* kb = Km + (size_t)b * L_SEQ * Dk + (size_t)kvh * HD;
    for (int j = tid; j < L_SEQ; j += 256) {
        const float* kr = kb + (size_t)j * Dk;
        float acc = 0.f;
#pragma unroll 8
        for (int d = 0; d < HD; ++d) acc += qs[d] * kr[d];
        sc[j] = acc;
    }
    __syncthreads();
    float m = -1e30f;
    for (int j = tid; j < L_SEQ; j += 256) m = fmaxf(m, sc[j]);
    red[tid] = m;
    __syncthreads();
    for (int s = 128; s > 0; s >>= 1) {
        if (tid < s) red[tid] = fmaxf(red[tid], red[tid + s]);
        __syncthreads();
    }
    m = red[0];
    __syncthreads();
    float ssum = 0.f;
    for (int j = tid; j < L_SEQ; j += 256) {
        float e = expf(sc[j] - m);
        sc[j] = e;
        ssum += e;
    }
    red[tid] = ssum;
    __syncthreads();
    for (int s = 128; s > 0; s >>= 1) {
        if (tid < s) red[tid] += red[tid + s];
        __syncthreads();
    }
    float inv = 1.0f / red[0];
    __syncthreads();
    const int NG = 256 / HD;
    int g = tid / HD, d = tid % HD;
    const float* vb = Vm + (size_t)b * L_SEQ * Dk + (size_t)kvh * HD + d;
    float acc = 0.f;
    for (int j = g; j < L_SEQ; j += NG) acc += sc[j] * vb[(size_t)j * Dk];
    red[tid] = acc;
    __syncthreads();
    if (g == 0) {
#pragma unroll
        for (int gg = 1; gg < NG; ++gg) acc += red[gg * HD + d];
        O[(size_t)(b * L_SEQ + qpos) * Dq + h * HD + d] = acc * inv;
    }
}

// ---------------- DeltaNet conv + gate: gated = conv(value) * silu(gate) ----------------
// gv: [T, 2D] (gate | value), cw: [D,1,DC], out gated: [T, D]
__global__ __launch_bounds__(256) void conv_gate_kernel(const float* __restrict__ gv,
                                                        const float* __restrict__ cw,
                                                        const float* __restrict__ cb,
                                                        float* __restrict__ gated) {
    int idx = blockIdx.x * 256 + threadIdx.x;
    if (idx >= T_TOK * D_MOD) return;
    int d = idx & (D_MOD - 1);
    int t = idx >> 10;
    int l = t & (L_SEQ - 1);
    float conv = cb[d];
#pragma unroll
    for (int i = 0; i < DC_K; ++i) {
        int lp = l - (DC_K - 1) + i;
        if (lp >= 0)
            conv += gv[(size_t)(t - l + lp) * (2 * D_MOD) + D_MOD + d] * cw[d * DC_K + i];
    }
    float gate = gv[(size_t)t * (2 * D_MOD) + d];
    float sig = 1.0f / (1.0f + expf(-gate));
    gated[(size_t)t * D_MOD + d] = conv * (gate * sig);
}

// ---------------- MoE routing ----------------
__global__ __launch_bounds__(256) void route_kernel(const float* __restrict__ g,
                                                    const float* __restrict__ wg,
                                                    int* __restrict__ tIdx,
                                                    float* __restrict__ tScore,
                                                    int* __restrict__ counts) {
    int t = blockIdx.x, tid = threadIdx.x;
    __shared__ float gs[D_MOD];
    __shared__ float logits[N_E];
    ((float4*)gs)[tid] = ((const float4*)(g + (size_t)t * D_MOD))[tid];
    __syncthreads();
    int e = tid >> 5, lane = tid & 31;
    const float* w = wg + (size_t)e * D_MOD;
    float p = 0.f;
    for (int d = lane; d < D_MOD; d += 32) p += gs[d] * w[d];
    for (int o = 16; o > 0; o >>= 1) p += __shfl_down(p, o, 32);
    if (lane == 0) logits[e] = p;
    __syncthreads();
    if (tid == 0) {
        float mx = logits[0];
        for (int e2 = 1; e2 < N_E; ++e2) mx = fmaxf(mx, logits[e2]);
        float pe[N_E];
        float Z = 0.f;
        for (int e2 = 0; e2 < N_E; ++e2) {
            pe[e2] = expf(logits[e2] - mx);
            Z += pe[e2];
        }
        int i0 = 0;
        float b0 = pe[0];
        for (int e2 = 1; e2 < N_E; ++e2)
            if (pe[e2] > b0) { b0 = pe[e2]; i0 = e2; }
        int i1 = -1;
        float b1 = -1.f;
        for (int e2 = 0; e2 < N_E; ++e2)
            if (e2 != i0 && pe[e2] > b1) { b1 = pe[e2]; i1 = e2; }
        float invZ = 1.0f / Z;
        tIdx[t * 2] = i0;
        tIdx[t * 2 + 1] = i1;
        tScore[t * 2] = b0 * invZ;
        tScore[t * 2 + 1] = b1 * invZ;
        atomicAdd(&counts[i0], 1);
        atomicAdd(&counts[i1], 1);
    }
}

__global__ void prefix_kernel(const int* __restrict__ counts, int* __restrict__ offs,
                              int* __restrict__ cursor) {
    if (threadIdx.x == 0) {
        int acc = 0;
        for (int e = 0; e < N_E; ++e) {
            offs[e] = acc;
            acc += counts[e];
            cursor[e] = 0;
        }
    }
}

__global__ __launch_bounds__(256) void fill_kernel(const int* __restrict__ tIdx,
                                                   const int* __restrict__ offs,
                                                   int* __restrict__ cursor,
                                                   int* __restrict__ list,
                                                   int* __restrict__ pairRow) {
    int t = blockIdx.x * 256 + threadIdx.x;
    if (t >= T_TOK) return;
    for (int kk = 0; kk < 2; ++kk) {
        int e = tIdx[t * 2 + kk];
        int pos = atomicAdd(&cursor[e], 1);
        int slot = offs[e] + pos;
        list[slot] = t;
        pairRow[t * 2 + kk] = slot;
    }
}

// ---------------- MoE expert GEMM (expert-batched, optional gather + GELU) ----------------
// GATHER=1: A row = Asrc[list[off+r]] (token gather). GATHER=0: A row = Asrc[off+r] (compact).
template <int GELU, int GATHER>
__global__ __launch_bounds__(256) void moe_gemm_kernel(const float* __restrict__ A,
                                                       const float* __restrict__ B,
                                                       const float* __restrict__ bias,
                                                       float* __restrict__ C,
                                                       const int* __restrict__ list,
                                                       const int* __restrict__ offs,
                                                       const int* __restrict__ counts,
                                                       int K, int N) {
    int e = blockIdx.z;
    int cnt = counts[e];
    int m0 = blockIdx.y * 64;
    if (m0 >= cnt) return;
    int off = offs[e];
    const float* Be = B + (size_t)e * K * N;
    const float* be = bias + (size_t)e * N;
    __shared__ float As[16][64];
    __shared__ float Bs[16][64];
    int tid = threadIdx.x;
    int col0 = blockIdx.x * 64;
    int am = tid >> 2, ak = (tid & 3) << 2;
    int bk = tid >> 4, bn = (tid & 15) << 2;
    int tm = (tid >> 4) << 2, tn = (tid & 15) << 2;
    int rr = m0 + am;
    if (rr > cnt - 1) rr = cnt - 1;
    size_t arow = GATHER ? (size_t)list[off + rr] : (size_t)(off + rr);
    const float* Ap = A + arow * K + ak;
    const float* Bp = Be + (size_t)bk * N + col0 + bn;
    float acc[4][4] = {};
    for (int k0 = 0; k0 < K; k0 += 16) {
        float4 a4 = *(const float4*)(Ap + k0);
        float4 b4 = *(const float4*)(Bp + (size_t)k0 * N);
        As[ak + 0][am] = a4.x;
        As[ak + 1][am] = a4.y;
        As[ak + 2][am] = a4.z;
        As[ak + 3][am] = a4.w;
        *(float4*)&Bs[bk][bn] = b4;
        __syncthreads();
#pragma unroll
        for (int kk = 0; kk < 16; ++kk) {
            float4 a = *(const float4*)&As[kk][tm];
            float4 b = *(const float4*)&Bs[kk][tn];
            acc[0][0] += a.x * b.x; acc[0][1] += a.x * b.y; acc[0][2] += a.x * b.z; acc[0][3] += a.x * b.w;
            acc[1][0] += a.y * b.x; acc[1][1] += a.y * b.y; acc[1][2] += a.y * b.z; acc[1][3] += a.y * b.w;
            acc[2][0] += a.z * b.x; acc[2][1] += a.z * b.y; acc[2][2] += a.z * b.z; acc[2][3] += a.z * b.w;
            acc[3][0] += a.w * b.x; acc[3][1] += a.w * b.y; acc[3][2] += a.w * b.z; acc[3][3] += a.w * b.w;
        }
        __syncthreads();
    }
#pragma unroll
    for (int i = 0; i < 4; ++i) {
        int rl = m0 + tm + i;
        if (rl >= cnt) continue;
#pragma unroll
        for (int j = 0; j < 4; ++j) {
            int c = col0 + tn + j;
            float v = acc[i][j] + be[c];
            if (GELU) v = gelu_exact(v);
            C[(size_t)(off + rl) * N + c] = v;
        }
    }
}

// ---------------- MoE combine: h[t] += s0*ysel[r0] + s1*ysel[r1] ----------------
__global__ __launch_bounds__(256) void combine_kernel(const float* __restrict__ ysel,
                                                      const float* __restrict__ tScore,
                                                      const int* __restrict__ pairRow,
                                                      float* __restrict__ h) {
    int idx = blockIdx.x * 256 + threadIdx.x;
    if (idx >= T_TOK * D_MOD) return;
    int t = idx >> 10;
    int d = idx & (D_MOD - 1);
    float acc = h[idx];
#pragma unroll
    for (int kk = 0; kk < 2; ++kk) {
        int r = pairRow[t * 2 + kk];
        acc += tScore[t * 2 + kk] * ysel[(size_t)r * D_MOD + d];
    }
    h[idx] = acc;
}

extern "C" void kernel_launch(void* const* d_in, const int* in_sizes, int n_in,
                              void* d_out, int out_size, void* d_ws, size_t ws_size,
                              hipStream_t stream) {
    const float* x = (const float*)d_in[0];
    // d_in[1] = mask (all ones) — unused
    const float* w_rms1 = (const float*)d_in[2];
    const float* w_rms2 = (const float*)d_in[3];
    const float* w_rms3 = (const float*)d_in[4];
    const float* w_rms4 = (const float*)d_in[5];
    const float* Wq = (const float*)d_in[6];
    const float* Wk = (const float*)d_in[7];
    const float* Wv = (const float*)d_in[8];
    const float* Wo = (const float*)d_in[9];
    const float* Cq = (const float*)d_in[10];
    const float* Ck = (const float*)d_in[11];
    const float* Cv = (const float*)d_in[12];
    const float* Co = (const float*)d_in[13];
    const float* Wi = (const float*)d_in[14];
    const float* bi = (const float*)d_in[15];
    const float* conv_w = (const float*)d_in[16];
    const float* conv_b = (const float*)d_in[17];
    const float* Wod = (const float*)d_in[18];
    const float* bod = (const float*)d_in[19];
    const float* w_gate = (const float*)d_in[20];
    const float* W1 = (const float*)d_in[21];
    const float* b1 = (const float*)d_in[22];
    const float* W2 = (const float*)d_in[23];
    const float* b2 = (const float*)d_in[24];
    float* out = (float*)d_out;

    char* ws = (char*)d_ws;
    size_t off = 0;
    auto alloc_f = [&](size_t nfl) {
        float* p = (float*)(ws + off);
        off += nfl * sizeof(float);
        return p;
    };
    const size_t TD = (size_t)T_TOK * D_MOD;
    float* h = alloc_f(TD);
    float* nrm = alloc_f(TD);
    float* qb = alloc_f(TD);
    float* kb = alloc_f(TD);
    float* vb = alloc_f(TD);
    float* ab = alloc_f(TD);                       // attn out / gated (reused)
    float* gv = alloc_f((size_t)T_TOK * 2 * D_MOD);
    float* hsel = alloc_f((size_t)2 * T_TOK * FF_DIM);  // 64 MB
    float* ysel = alloc_f((size_t)2 * T_TOK * D_MOD);
    int* counts = (int*)(ws + off); off += N_E * sizeof(int);
    int* offs = (int*)(ws + off); off += N_E * sizeof(int);
    int* cursor = (int*)(ws + off); off += N_E * sizeof(int);
    int* tIdx = (int*)(ws + off); off += 2 * T_TOK * sizeof(int);
    int* list = (int*)(ws + off); off += 2 * T_TOK * sizeof(int);
    int* pairRow = (int*)(ws + off); off += 2 * T_TOK * sizeof(int);
    float* tScore = alloc_f(2 * T_TOK);

    // ---- 1. attn1 (GQA 16h/4kv, hd=64) ----
    rmsnorm_kernel<<<T_TOK, 256, 0, stream>>>(x, w_rms1, nrm);
    gemm_kernel<<<dim3(16, 32), 256, 0, stream>>>(nrm, Wq, nullptr, nullptr, qb, T_TOK, 1024, 1024);
    gemm_kernel<<<dim3(4, 32), 256, 0, stream>>>(nrm, Wk, nullptr, nullptr, kb, T_TOK, 256, 1024);
    gemm_kernel<<<dim3(4, 32), 256, 0, stream>>>(nrm, Wv, nullptr, nullptr, vb, T_TOK, 256, 1024);
    attn_kernel<64><<<dim3(L_SEQ, N_H, B_SZ), 256, 0, stream>>>(qb, kb, vb, ab, N_H, N_KV, 0.125f);
    gemm_kernel<<<dim3(16, 32), 256, 0, stream>>>(ab, Wo, nullptr, x, h, T_TOK, 1024, 1024);

    // ---- 2. ContextManager attention (8h/8kv, hd=128), input = h (no norm) ----
    gemm_kernel<<<dim3(16, 32), 256, 0, stream>>>(h, Cq, nullptr, nullptr, qb, T_TOK, 1024, 1024);
    gemm_kernel<<<dim3(16, 32), 256, 0, stream>>>(h, Ck, nullptr, nullptr, kb, T_TOK, 1024, 1024);
    gemm_kernel<<<dim3(16, 32), 256, 0, stream>>>(h, Cv, nullptr, nullptr, vb, T_TOK, 1024, 1024);
    attn_kernel<128><<<dim3(L_SEQ, N_CH, B_SZ), 256, 0, stream>>>(qb, kb, vb, ab, N_CH, N_CH,
                                                                  0.088388347648318447f);
    gemm_kernel<<<dim3(16, 32), 256, 0, stream>>>(ab, Co, nullptr, h, h, T_TOK, 1024, 1024);

    // ---- 3. deltanet ----
    rmsnorm_kernel<<<T_TOK, 256, 0, stream>>>(h, w_rms2, nrm);
    gemm_kernel<<<dim3(32, 32), 256, 0, stream>>>(nrm, Wi, bi, nullptr, gv, T_TOK, 2048, 1024);
    conv_gate_kernel<<<(T_TOK * D_MOD) / 256, 256, 0, stream>>>(gv, conv_w, conv_b, ab);
    gemm_kernel<<<dim3(16, 32), 256, 0, stream>>>(ab, Wod, bod, h, h, T_TOK, 1024, 1024);

    // ---- 4. MoE (top-2 of 8) ----
    rmsnorm_kernel<<<T_TOK, 256, 0, stream>>>(h, w_rms3, nrm);
    hipMemsetAsync(counts, 0, N_E * sizeof(int), stream);
    route_kernel<<<T_TOK, 256, 0, stream>>>(nrm, w_gate, tIdx, tScore, counts);
    prefix_kernel<<<1, 64, 0, stream>>>(counts, offs, cursor);
    fill_kernel<<<(T_TOK + 255) / 256, 256, 0, stream>>>(tIdx, offs, cursor, list, pairRow);
    moe_gemm_kernel<1, 1><<<dim3(FF_DIM / 64, T_TOK / 64, N_E), 256, 0, stream>>>(
        nrm, W1, b1, hsel, list, offs, counts, 1024, FF_DIM);
    moe_gemm_kernel<0, 0><<<dim3(1024 / 64, T_TOK / 64, N_E), 256, 0, stream>>>(
        hsel, W2, b2, ysel, nullptr, offs, counts, FF_DIM, 1024);
    combine_kernel<<<(T_TOK * D_MOD) / 256, 256, 0, stream>>>(ysel, tScore, pairRow, h);

    // ---- 5. final rmsnorm -> out ----
    rmsnorm_kernel<<<T_TOK, 256, 0, stream>>>(h, w_rms4, out);
}

// Round 2
// 2630.024 us; speedup vs baseline: 2.0823x; 2.0823x over previous
//
#include <hip/hip_runtime.h>
#include <hip/hip_bf16.h>
#include <math.h>

#define T_TOK 2048
#define B_SZ 2
#define L_SEQ 1024
#define D_MOD 1024
#define N_H 16
#define N_KV 4
#define N_CH 8
#define N_E 8
#define FF_DIM 4096
#define DC_K 4
#define EPS_F 1e-6f

__device__ __forceinline__ float gelu_exact(float x) {
    return 0.5f * x * (1.0f + erff(x * 0.70710678118654752f));
}

// ---------------- RMSNorm: one block per row, 256 threads, D=1024 ----------------
__global__ __launch_bounds__(256) void rmsnorm_kernel(const float* __restrict__ x,
                                                      const float* __restrict__ w,
                                                      float* __restrict__ out) {
    int row = blockIdx.x;
    int tid = threadIdx.x;
    const float* xr = x + (size_t)row * D_MOD;
    float4 v = ((const float4*)xr)[tid];
    float ss = v.x * v.x + v.y * v.y + v.z * v.z + v.w * v.w;
    __shared__ float red[256];
    red[tid] = ss;
    __syncthreads();
    for (int s = 128; s > 0; s >>= 1) {
        if (tid < s) red[tid] += red[tid + s];
        __syncthreads();
    }
    float mean = red[0] * (1.0f / D_MOD);
    float inv = 1.0f / sqrtf(mean + EPS_F);
    float4 wv = ((const float4*)w)[tid];
    float4 o;
    o.x = v.x * inv * wv.x;
    o.y = v.y * inv * wv.y;
    o.z = v.z * inv * wv.z;
    o.w = v.w * inv * wv.w;
    ((float4*)(out + (size_t)row * D_MOD))[tid] = o;
}

// ---------------- Tiled GEMM: C[M,N] = A[M,K]@B[K,N] (+bias)(+res) ----------------
__global__ __launch_bounds__(256) void gemm_kernel(const float* __restrict__ A,
                                                   const float* __restrict__ B,
                                                   const float* __restrict__ bias,
                                                   const float* __restrict__ res,
                                                   float* __restrict__ C,
                                                   int M, int N, int K) {
    __shared__ float As[16][64];
    __shared__ float Bs[16][64];
    int tid = threadIdx.x;
    int row0 = blockIdx.y * 64, col0 = blockIdx.x * 64;
    int am = tid >> 2, ak = (tid & 3) << 2;
    int bk = tid >> 4, bn = (tid & 15) << 2;
    int tm = (tid >> 4) << 2, tn = (tid & 15) << 2;
    float acc[4][4] = {};
    const float* Ap = A + (size_t)(row0 + am) * K + ak;
    const float* Bp = B + (size_t)bk * N + col0 + bn;
    for (int k0 = 0; k0 < K; k0 += 16) {
        float4 a4 = *(const float4*)(Ap + k0);
        float4 b4 = *(const float4*)(Bp + (size_t)k0 * N);
        As[ak + 0][am] = a4.x;
        As[ak + 1][am] = a4.y;
        As[ak + 2][am] = a4.z;
        As[ak + 3][am] = a4.w;
        *(float4*)&Bs[bk][bn] = b4;
        __syncthreads();
#pragma unroll
        for (int kk = 0; kk < 16; ++kk) {
            float4 a = *(const float4*)&As[kk][tm];
            float4 b = *(const float4*)&Bs[kk][tn];
            acc[0][0] += a.x * b.x; acc[0][1] += a.x * b.y; acc[0][2] += a.x * b.z; acc[0][3] += a.x * b.w;
            acc[1][0] += a.y * b.x; acc[1][1] += a.y * b.y; acc[1][2] += a.y * b.z; acc[1][3] += a.y * b.w;
            acc[2][0] += a.z * b.x; acc[2][1] += a.z * b.y; acc[2][2] += a.z * b.z; acc[2][3] += a.z * b.w;
            acc[3][0] += a.w * b.x; acc[3][1] += a.w * b.y; acc[3][2] += a.w * b.z; acc[3][3] += a.w * b.w;
        }
        __syncthreads();
    }
#pragma unroll
    for (int i = 0; i < 4; ++i) {
        int r = row0 + tm + i;
#pragma unroll
        for (int j = 0; j < 4; ++j) {
            int c = col0 + tn + j;
            float v = acc[i][j];
            if (bias) v += bias[c];
            if (res) v += res[(size_t)r * N + c];
            C[(size_t)r * N + c] = v;
        }
    }
}

// ---------------- Flash attention (fp32, LDS-tiled) ----------------
// One block per (b, h, 32-q-row tile). 256 threads. QT=KT=32.
// Q:[B,L,nh,HD] K/V:[B,L,nkv,HD] O:[B,L,nh,HD]. Non-causal, full softmax.
template <int HD>
__global__ __launch_bounds__(256) void fattn_kernel(const float* __restrict__ Qm,
                                                    const float* __restrict__ Km,
                                                    const float* __restrict__ Vm,
                                                    float* __restrict__ O,
                                                    int nh, int nkv, float scale) {
    constexpr int QT = 32, KT = 32;
    constexpr int SP = HD + 4;        // padded LDS row stride (floats); 16B-aligned rows
    constexpr int NM = HD / 32;       // float4 col-blocks owned per thread (2 or 4)
    __shared__ float Qs[QT][SP];
    __shared__ float Ks[KT][SP];
    __shared__ float Vs[KT][SP];
    __shared__ float Ps[QT][KT + 1];
    __shared__ float m_s[QT], l_s[QT], msc[QT];

    int tid = threadIdx.x;
    int q0 = blockIdx.x * QT, h = blockIdx.y, b = blockIdx.z;
    int kvh = h / (nh / nkv);
    int Dq = nh * HD, Dk = nkv * HD;

    const float* Qbase = Qm + (size_t)(b * L_SEQ + q0) * Dq + h * HD;
    const float* Kbase = Km + (size_t)b * L_SEQ * Dk + (size_t)kvh * HD;
    const float* Vbase = Vm + (size_t)b * L_SEQ * Dk + (size_t)kvh * HD;

    constexpr int F4 = HD / 4;        // float4 per row
    constexpr int NV = QT * F4;       // float4 per tile
    // stage Q (scaled)
    for (int idx = tid; idx < NV; idx += 256) {
        int r = idx / F4, c4 = (idx % F4) << 2;
        float4 q4 = *(const float4*)(Qbase + (size_t)r * Dq + c4);
        q4.x *= scale; q4.y *= scale; q4.z *= scale; q4.w *= scale;
        *(float4*)&Qs[r][c4] = q4;
    }
    if (tid < QT) { m_s[tid] = -1e30f; l_s[tid] = 0.f; }

    // per-thread output ownership: row ip = tid/8, cols {4c+32m}, c = tid%8
    int ip = tid >> 3, c = tid & 7;
    float4 acc[NM];
#pragma unroll
    for (int m = 0; m < NM; ++m) acc[m] = make_float4(0.f, 0.f, 0.f, 0.f);

    int i0 = (tid >> 4) << 1, j0 = (tid & 15) << 1;

    for (int kt = 0; kt < L_SEQ / KT; ++kt) {
        // stage K/V tile
        for (int idx = tid; idx < NV; idx += 256) {
            int r = idx / F4, c4 = (idx % F4) << 2;
            size_t goff = (size_t)(kt * KT + r) * Dk + c4;
            *(float4*)&Ks[r][c4] = *(const float4*)(Kbase + goff);
            *(float4*)&Vs[r][c4] = *(const float4*)(Vbase + goff);
        }
        __syncthreads();
        // S = Q K^T (2x2 per thread)
        float s00 = 0.f, s01 = 0.f, s10 = 0.f, s11 = 0.f;
#pragma unroll 4
        for (int d = 0; d < HD; d += 4) {
            float4 qa = *(const float4*)&Qs[i0][d];
            float4 qb = *(const float4*)&Qs[i0 + 1][d];
            float4 ka = *(const float4*)&Ks[j0][d];
            float4 kb = *(const float4*)&Ks[j0 + 1][d];
            s00 += qa.x * ka.x + qa.y * ka.y + qa.z * ka.z + qa.w * ka.w;
            s01 += qa.x * kb.x + qa.y * kb.y + qa.z * kb.z + qa.w * kb.w;
            s10 += qb.x * ka.x + qb.y * ka.y + qb.z * ka.z + qb.w * ka.w;
            s11 += qb.x * kb.x + qb.y * kb.y + qb.z * kb.z + qb.w * kb.w;
        }
        Ps[i0][j0] = s00;
        Ps[i0][j0 + 1] = s01;
        Ps[i0 + 1][j0] = s10;
        Ps[i0 + 1][j0 + 1] = s11;
        __syncthreads();
        // row max (8 lanes per row)
        {
            float mx = -1e30f;
#pragma unroll
            for (int k = 0; k < 4; ++k) mx = fmaxf(mx, Ps[ip][c * 4 + k]);
            mx = fmaxf(mx, __shfl_xor(mx, 1));
            mx = fmaxf(mx, __shfl_xor(mx, 2));
            mx = fmaxf(mx, __shfl_xor(mx, 4));
            if (c == 0) {
                float mo = m_s[ip];
                float mn = fmaxf(mo, mx);
                m_s[ip] = mn;
                msc[ip] = __expf(mo - mn);
            }
        }
        __syncthreads();
        // exp + row sum
        {
            float mn = m_s[ip];
            float sm = 0.f;
#pragma unroll
            for (int k = 0; k < 4; ++k) {
                float p = __expf(Ps[ip][c * 4 + k] - mn);
                Ps[ip][c * 4 + k] = p;
                sm += p;
            }
            sm += __shfl_xor(sm, 1);
            sm += __shfl_xor(sm, 2);
            sm += __shfl_xor(sm, 4);
            if (c == 0) l_s[ip] = l_s[ip] * msc[ip] + sm;
        }
        __syncthreads();
        // PV: rescale acc, then acc += P @ V
        {
            float sc = msc[ip];
#pragma unroll
            for (int m = 0; m < NM; ++m) {
                acc[m].x *= sc; acc[m].y *= sc; acc[m].z *= sc; acc[m].w *= sc;
            }
            for (int j = 0; j < KT; ++j) {
                float p = Ps[ip][j];
#pragma unroll
                for (int m = 0; m < NM; ++m) {
                    float4 v = *(const float4*)&Vs[j][c * 4 + m * 32];
                    acc[m].x += p * v.x; acc[m].y += p * v.y;
                    acc[m].z += p * v.z; acc[m].w += p * v.w;
                }
            }
        }
        __syncthreads();
    }
    float invl = 1.0f / l_s[ip];
    float* orow = O + (size_t)(b * L_SEQ + q0 + ip) * Dq + h * HD + c * 4;
#pragma unroll
    for (int m = 0; m < NM; ++m) {
        float4 o4;
        o4.x = acc[m].x * invl; o4.y = acc[m].y * invl;
        o4.z = acc[m].z * invl; o4.w = acc[m].w * invl;
        *(float4*)(orow + m * 32) = o4;
    }
}

// ---------------- DeltaNet conv + gate ----------------
__global__ __launch_bounds__(256) void conv_gate_kernel(const float* __restrict__ gv,
                                                        const float* __restrict__ cw,
                                                        const float* __restrict__ cb,
                                                        float* __restrict__ gated) {
    int idx = blockIdx.x * 256 + threadIdx.x;
    if (idx >= T_TOK * D_MOD) return;
    int d = idx & (D_MOD - 1);
    int t = idx >> 10;
    int l = t & (L_SEQ - 1);
    float conv = cb[d];
#pragma unroll
    for (int i = 0; i < DC_K; ++i) {
        int lp = l - (DC_K - 1) + i;
        if (lp >= 0)
            conv += gv[(size_t)(t - l + lp) * (2 * D_MOD) + D_MOD + d] * cw[d * DC_K + i];
    }
    float gate = gv[(size_t)t * (2 * D_MOD) + d];
    float sig = 1.0f / (1.0f + expf(-gate));
    gated[(size_t)t * D_MOD + d] = conv * (gate * sig);
}

// ---------------- MoE routing ----------------
__global__ __launch_bounds__(256) void route_kernel(const float* __restrict__ g,
                                                    const float* __restrict__ wg,
                                                    int* __restrict__ tIdx,
                                                    float* __restrict__ tScore,
                                                    int* __restrict__ counts) {
    int t = blockIdx.x, tid = threadIdx.x;
    __shared__ float gs[D_MOD];
    __shared__ float logits[N_E];
    ((float4*)gs)[tid] = ((const float4*)(g + (size_t)t * D_MOD))[tid];
    __syncthreads();
    int e = tid >> 5, lane = tid & 31;
    const float* w = wg + (size_t)e * D_MOD;
    float p = 0.f;
    for (int d = lane; d < D_MOD; d += 32) p += gs[d] * w[d];
    for (int o = 16; o > 0; o >>= 1) p += __shfl_down(p, o, 32);
    if (lane == 0) logits[e] = p;
    __syncthreads();
    if (tid == 0) {
        float mx = logits[0];
        for (int e2 = 1; e2 < N_E; ++e2) mx = fmaxf(mx, logits[e2]);
        float pe[N_E];
        float Z = 0.f;
        for (int e2 = 0; e2 < N_E; ++e2) {
            pe[e2] = expf(logits[e2] - mx);
            Z += pe[e2];
        }
        int i0 = 0;
        float b0 = pe[0];
        for (int e2 = 1; e2 < N_E; ++e2)
            if (pe[e2] > b0) { b0 = pe[e2]; i0 = e2; }
        int i1 = -1;
        float b1 = -1.f;
        for (int e2 = 0; e2 < N_E; ++e2)
            if (e2 != i0 && pe[e2] > b1) { b1 = pe[e2]; i1 = e2; }
        float invZ = 1.0f / Z;
        tIdx[t * 2] = i0;
        tIdx[t * 2 + 1] = i1;
        tScore[t * 2] = b0 * invZ;
        tScore[t * 2 + 1] = b1 * invZ;
        atomicAdd(&counts[i0], 1);
        atomicAdd(&counts[i1], 1);
    }
}

__global__ void prefix_kernel(const int* __restrict__ counts, int* __restrict__ offs,
                              int* __restrict__ cursor) {
    if (threadIdx.x == 0) {
        int acc = 0;
        for (int e = 0; e < N_E; ++e) {
            offs[e] = acc;
            acc += counts[e];
            cursor[e] = 0;
        }
    }
}

__global__ __launch_bounds__(256) void fill_kernel(const int* __restrict__ tIdx,
                                                   const int* __restrict__ offs,
                                                   int* __restrict__ cursor,
                                                   int* __restrict__ list,
                                                   int* __restrict__ pairRow) {
    int t = blockIdx.x * 256 + threadIdx.x;
    if (t >= T_TOK) return;
    for (int kk = 0; kk < 2; ++kk) {
        int e = tIdx[t * 2 + kk];
        int pos = atomicAdd(&cursor[e], 1);
        int slot = offs[e] + pos;
        list[slot] = t;
        pairRow[t * 2 + kk] = slot;
    }
}

// ---------------- MoE expert GEMM ----------------
template <int GELU, int GATHER>
__global__ __launch_bounds__(256) void moe_gemm_kernel(const float* __restrict__ A,
                                                       const float* __restrict__ B,
                                                       const float* __restrict__ bias,
                                                       float* __restrict__ C,
                                                       const int* __restrict__ list,
                                                       const int* __restrict__ offs,
                                                       const int* __restrict__ counts,
                                                       int K, int N) {
    int e = blockIdx.z;
    int cnt = counts[e];
    int m0 = blockIdx.y * 64;
    if (m0 >= cnt) return;
    int off = offs[e];
    const float* Be = B + (size_t)e * K * N;
    const float* be = bias + (size_t)e * N;
    __shared__ float As[16][64];
    __shared__ float Bs[16][64];
    int tid = threadIdx.x;
    int col0 = blockIdx.x * 64;
    int am = tid >> 2, ak = (tid & 3) << 2;
    int bk = tid >> 4, bn = (tid & 15) << 2;
    int tm = (tid >> 4) << 2, tn = (tid & 15) << 2;
    int rr = m0 + am;
    if (rr > cnt - 1) rr = cnt - 1;
    size_t arow = GATHER ? (size_t)list[off + rr] : (size_t)(off + rr);
    const float* Ap = A + arow * K + ak;
    const float* Bp = Be + (size_t)bk * N + col0 + bn;
    float acc[4][4] = {};
    for (int k0 = 0; k0 < K; k0 += 16) {
        float4 a4 = *(const float4*)(Ap + k0);
        float4 b4 = *(const float4*)(Bp + (size_t)k0 * N);
        As[ak + 0][am] = a4.x;
        As[ak + 1][am] = a4.y;
        As[ak + 2][am] = a4.z;
        As[ak + 3][am] = a4.w;
        *(float4*)&Bs[bk][bn] = b4;
        __syncthreads();
#pragma unroll
        for (int kk = 0; kk < 16; ++kk) {
            float4 a = *(const float4*)&As[kk][tm];
            float4 b = *(const float4*)&Bs[kk][tn];
            acc[0][0] += a.x * b.x; acc[0][1] += a.x * b.y; acc[0][2] += a.x * b.z; acc[0][3] += a.x * b.w;
            acc[1][0] += a.y * b.x; acc[1][1] += a.y * b.y; acc[1][2] += a.y * b.z; acc[1][3] += a.y * b.w;
            acc[2][0] += a.z * b.x; acc[2][1] += a.z * b.y; acc[2][2] += a.z * b.z; acc[2][3] += a.z * b.w;
            acc[3][0] += a.w * b.x; acc[3][1] += a.w * b.y; acc[3][2] += a.w * b.z; acc[3][3] += a.w * b.w;
        }
        __syncthreads();
    }
#pragma unroll
    for (int i = 0; i < 4; ++i) {
        int rl = m0 + tm + i;
        if (rl >= cnt) continue;
#pragma unroll
        for (int j = 0; j < 4; ++j) {
            int c = col0 + tn + j;
            float v = acc[i][j] + be[c];
            if (GELU) v = gelu_exact(v);
            C[(size_t)(off + rl) * N + c] = v;
        }
    }
}

// ---------------- MoE combine ----------------
__global__ __launch_bounds__(256) void combine_kernel(const float* __restrict__ ysel,
                                                      const float* __restrict__ tScore,
                                                      const int* __restrict__ pairRow,
                                                      float* __restrict__ h) {
    int idx = blockIdx.x * 256 + threadIdx.x;
    if (idx >= T_TOK * D_MOD) return;
    int t = idx >> 10;
    int d = idx & (D_MOD - 1);
    float acc = h[idx];
#pragma unroll
    for (int kk = 0; kk < 2; ++kk) {
        int r = pairRow[t * 2 + kk];
        acc += tScore[t * 2 + kk] * ysel[(size_t)r * D_MOD + d];
    }
    h[idx] = acc;
}

extern "C" void kernel_launch(void* const* d_in, const int* in_sizes, int n_in,
                              void* d_out, int out_size, void* d_ws, size_t ws_size,
                              hipStream_t stream) {
    const float* x = (const float*)d_in[0];
    const float* w_rms1 = (const float*)d_in[2];
    const float* w_rms2 = (const float*)d_in[3];
    const float* w_rms3 = (const float*)d_in[4];
    const float* w_rms4 = (const float*)d_in[5];
    const float* Wq = (const float*)d_in[6];
    const float* Wk = (const float*)d_in[7];
    const float* Wv = (const float*)d_in[8];
    const float* Wo = (const float*)d_in[9];
    const float* Cq = (const float*)d_in[10];
    const float* Ck = (const float*)d_in[11];
    const float* Cv = (const float*)d_in[12];
    const float* Co = (const float*)d_in[13];
    const float* Wi = (const float*)d_in[14];
    const float* bi = (const float*)d_in[15];
    const float* conv_w = (const float*)d_in[16];
    const float* conv_b = (const float*)d_in[17];
    const float* Wod = (const float*)d_in[18];
    const float* bod = (const float*)d_in[19];
    const float* w_gate = (const float*)d_in[20];
    const float* W1 = (const float*)d_in[21];
    const float* b1 = (const float*)d_in[22];
    const float* W2 = (const float*)d_in[23];
    const float* b2 = (const float*)d_in[24];
    float* out = (float*)d_out;

    char* ws = (char*)d_ws;
    size_t off = 0;
    auto alloc_f = [&](size_t nfl) {
        float* p = (float*)(ws + off);
        off += nfl * sizeof(float);
        return p;
    };
    const size_t TD = (size_t)T_TOK * D_MOD;
    float* h = alloc_f(TD);
    float* nrm = alloc_f(TD);
    float* qb = alloc_f(TD);
    float* kb = alloc_f(TD);
    float* vb = alloc_f(TD);
    float* ab = alloc_f(TD);
    float* gv = alloc_f((size_t)T_TOK * 2 * D_MOD);
    float* hsel = alloc_f((size_t)2 * T_TOK * FF_DIM);
    float* ysel = alloc_f((size_t)2 * T_TOK * D_MOD);
    int* counts = (int*)(ws + off); off += N_E * sizeof(int);
    int* offs = (int*)(ws + off); off += N_E * sizeof(int);
    int* cursor = (int*)(ws + off); off += N_E * sizeof(int);
    int* tIdx = (int*)(ws + off); off += 2 * T_TOK * sizeof(int);
    int* list = (int*)(ws + off); off += 2 * T_TOK * sizeof(int);
    int* pairRow = (int*)(ws + off); off += 2 * T_TOK * sizeof(int);
    float* tScore = alloc_f(2 * T_TOK);

    // ---- 1. attn1 (GQA 16h/4kv, hd=64) ----
    rmsnorm_kernel<<<T_TOK, 256, 0, stream>>>(x, w_rms1, nrm);
    gemm_kernel<<<dim3(16, 32), 256, 0, stream>>>(nrm, Wq, nullptr, nullptr, qb, T_TOK, 1024, 1024);
    gemm_kernel<<<dim3(4, 32), 256, 0, stream>>>(nrm, Wk, nullptr, nullptr, kb, T_TOK, 256, 1024);
    gemm_kernel<<<dim3(4, 32), 256, 0, stream>>>(nrm, Wv, nullptr, nullptr, vb, T_TOK, 256, 1024);
    fattn_kernel<64><<<dim3(L_SEQ / 32, N_H, B_SZ), 256, 0, stream>>>(qb, kb, vb, ab, N_H, N_KV, 0.125f);
    gemm_kernel<<<dim3(16, 32), 256, 0, stream>>>(ab, Wo, nullptr, x, h, T_TOK, 1024, 1024);

    // ---- 2. ContextManager attention (8h/8kv, hd=128) ----
    gemm_kernel<<<dim3(16, 32), 256, 0, stream>>>(h, Cq, nullptr, nullptr, qb, T_TOK, 1024, 1024);
    gemm_kernel<<<dim3(16, 32), 256, 0, stream>>>(h, Ck, nullptr, nullptr, kb, T_TOK, 1024, 1024);
    gemm_kernel<<<dim3(16, 32), 256, 0, stream>>>(h, Cv, nullptr, nullptr, vb, T_TOK, 1024, 1024);
    fattn_kernel<128><<<dim3(L_SEQ / 32, N_CH, B_SZ), 256, 0, stream>>>(qb, kb, vb, ab, N_CH, N_CH,
                                                                        0.088388347648318447f);
    gemm_kernel<<<dim3(16, 32), 256, 0, stream>>>(ab, Co, nullptr, h, h, T_TOK, 1024, 1024);

    // ---- 3. deltanet ----
    rmsnorm_kernel<<<T_TOK, 256, 0, stream>>>(h, w_rms2, nrm);
    gemm_kernel<<<dim3(32, 32), 256, 0, stream>>>(nrm, Wi, bi, nullptr, gv, T_TOK, 2048, 1024);
    conv_gate_kernel<<<(T_TOK * D_MOD) / 256, 256, 0, stream>>>(gv, conv_w, conv_b, ab);
    gemm_kernel<<<dim3(16, 32), 256, 0, stream>>>(ab, Wod, bod, h, h, T_TOK, 1024, 1024);

    // ---- 4. MoE (top-2 of 8) ----
    rmsnorm_kernel<<<T_TOK, 256, 0, stream>>>(h, w_rms3, nrm);
    hipMemsetAsync(counts, 0, N_E * sizeof(int), stream);
    route_kernel<<<T_TOK, 256, 0, stream>>>(nrm, w_gate, tIdx, tScore, counts);
    prefix_kernel<<<1, 64, 0, stream>>>(counts, offs, cursor);
    fill_kernel<<<(T_TOK + 255) / 256, 256, 0, stream>>>(tIdx, offs, cursor, list, pairRow);
    moe_gemm_kernel<1, 1><<<dim3(FF_DIM / 64, T_TOK / 64, N_E), 256, 0, stream>>>(
        nrm, W1, b1, hsel, list, offs, counts, 1024, FF_DIM);
    moe_gemm_kernel<0, 0><<<dim3(1024 / 64, T_TOK / 64, N_E), 256, 0, stream>>>(
        hsel, W2, b2, ysel, nullptr, offs, counts, FF_DIM, 1024);
    combine_kernel<<<(T_TOK * D_MOD) / 256, 256, 0, stream>>>(ysel, tScore, pairRow, h);

    // ---- 5. final rmsnorm -> out ----
    rmsnorm_kernel<<<T_TOK, 256, 0, stream>>>(h, w_rms4, out);
}

// Round 3
// 1269.374 us; speedup vs baseline: 4.3144x; 2.0719x over previous
//
#include <hip/hip_runtime.h>
#include <hip/hip_bf16.h>
#include <math.h>

#define T_TOK 2048
#define B_SZ 2
#define L_SEQ 1024
#define D_MOD 1024
#define N_H 16
#define N_KV 4
#define N_CH 8
#define N_E 8
#define FF_DIM 4096
#define DC_K 4
#define EPS_F 1e-6f

typedef unsigned short u16;
typedef unsigned int u32;
typedef short s16x8 __attribute__((ext_vector_type(8)));
typedef u16 u16x8 __attribute__((ext_vector_type(8)));
typedef float f32x4 __attribute__((ext_vector_type(4)));
struct alignas(8) U16x4 { u16 a, b, c, d; };

__device__ __forceinline__ float gelu_exact(float x) {
    return 0.5f * x * (1.0f + erff(x * 0.70710678118654752f));
}
__device__ __forceinline__ u16 f2bf(float f) {  // RNE
    u32 x = __float_as_uint(f);
    return (u16)((x + 0x7fffu + ((x >> 16) & 1u)) >> 16);
}
__device__ __forceinline__ float b2f(u16 u) {
    return __uint_as_float(((u32)u) << 16);
}
__device__ __forceinline__ void gload_lds16(const u16* g, u16* l) {
    __builtin_amdgcn_global_load_lds(
        (const __attribute__((address_space(1))) u32*)g,
        (__attribute__((address_space(3))) u32*)l, 16, 0, 0);
}

// ---------------- transpose + fp32->bf16 convert: dst[c][r] = src[r][c] ----------------
__global__ __launch_bounds__(256) void transpose_cvt(const float* __restrict__ src,
                                                     u16* __restrict__ dst,
                                                     int R, int C, int dstStride, int dstRowOff) {
    __shared__ float t[32][33];
    int e = blockIdx.z;
    src += (size_t)e * R * C;
    dst += (size_t)e * (size_t)C * dstStride;
    int c0 = blockIdx.x * 32, r0 = blockIdx.y * 32;
    int tx = threadIdx.x & 31, ty = threadIdx.x >> 5;
#pragma unroll
    for (int i = 0; i < 4; ++i) {
        int r = r0 + ty + i * 8;
        if (r < R && c0 + tx < C) t[tx][ty + i * 8] = src[(size_t)r * C + c0 + tx];
    }
    __syncthreads();
#pragma unroll
    for (int i = 0; i < 4; ++i) {
        int c = c0 + ty + i * 8, rr = r0 + tx;
        if (c < C && rr < R)
            dst[(size_t)(dstRowOff + c) * dstStride + rr] = f2bf(t[ty + i * 8][tx]);
    }
}

// ---------------- RMSNorm: fp32 in, optional fp32 + bf16 out ----------------
__global__ __launch_bounds__(256) void rmsnorm_kernel(const float* __restrict__ x,
                                                      const float* __restrict__ w,
                                                      float* __restrict__ fo,
                                                      u16* __restrict__ bo) {
    int row = blockIdx.x;
    int tid = threadIdx.x;
    const float* xr = x + (size_t)row * D_MOD;
    float4 v = ((const float4*)xr)[tid];
    float ss = v.x * v.x + v.y * v.y + v.z * v.z + v.w * v.w;
    __shared__ float red[256];
    red[tid] = ss;
    __syncthreads();
    for (int s = 128; s > 0; s >>= 1) {
        if (tid < s) red[tid] += red[tid + s];
        __syncthreads();
    }
    float inv = 1.0f / sqrtf(red[0] * (1.0f / D_MOD) + EPS_F);
    float4 wv = ((const float4*)w)[tid];
    float4 o;
    o.x = v.x * inv * wv.x;
    o.y = v.y * inv * wv.y;
    o.z = v.z * inv * wv.z;
    o.w = v.w * inv * wv.w;
    if (fo) ((float4*)(fo + (size_t)row * D_MOD))[tid] = o;
    if (bo) {
        U16x4 b;
        b.a = f2bf(o.x); b.b = f2bf(o.y); b.c = f2bf(o.z); b.d = f2bf(o.w);
        *(U16x4*)(bo + (size_t)row * D_MOD + tid * 4) = b;
    }
}

// ---------------- MFMA bf16 GEMM: C[M,N](f32/bf16) = A[M,K]bf16 @ BT[N,K]bf16 ----------------
// MODE 0: dense (cnt=M). MODE 1: MoE gather (A row = list[off+r], C row = off+r).
// MODE 2: MoE compact (A row = off+r, C row = off+r).
// 128x128 tile, 4 waves (2x2 of 64x64), BK=32, 16x16x32 MFMA, global_load_lds staging
// with XOR chunk swizzle (linear LDS dest + inverse-swizzled source + swizzled read).
template <int MODE, int GELU, int OUTF, int OUTB>
__global__ __launch_bounds__(256) void mfma_gemm(const u16* __restrict__ A,
                                                 const u16* __restrict__ BT,
                                                 const float* __restrict__ bias,
                                                 const float* __restrict__ res,
                                                 float* __restrict__ C,
                                                 u16* __restrict__ Cb,
                                                 const int* __restrict__ list,
                                                 const int* __restrict__ offs,
                                                 const int* __restrict__ counts,
                                                 int M, int N, int K) {
    __shared__ u16 ldsA[128 * 32];
    __shared__ u16 ldsB[128 * 32];
    int tid = threadIdx.x;
    int lane = tid & 63, w = tid >> 6;
    int wr = w >> 1, wc = w & 1;
    int e = blockIdx.z;
    int cnt, off;
    if (MODE == 0) { cnt = M; off = 0; }
    else { cnt = counts[e]; off = offs[e]; }
    int m0 = blockIdx.y * 128;
    if (m0 >= cnt) return;
    int n0 = blockIdx.x * 128;
    const u16* Bt = BT + (size_t)e * (size_t)N * K;

    // staging source pointers (2 issues each for A and B; 4KB per wave-issue)
    const u16* aSrc[2];
    const u16* bSrc[2];
#pragma unroll
    for (int j = 0; j < 2; ++j) {
        int rowA = w * 16 + (lane >> 2) + j * 64;
        int slot = lane & 3;
        int rl = m0 + rowA;
        if (rl >= cnt) rl = cnt - 1;
        size_t ga;
        if (MODE == 1) ga = (size_t)list[off + rl] * K;
        else if (MODE == 2) ga = (size_t)(off + rl) * K;
        else ga = (size_t)rl * K;
        aSrc[j] = A + ga + ((slot ^ ((rowA >> 1) & 3)) << 3);
        bSrc[j] = Bt + (size_t)(n0 + rowA) * K + ((slot ^ ((rowA >> 1) & 3)) << 3);
    }
    u16* ldsAw0 = ldsA + w * 512;
    u16* ldsBw0 = ldsB + w * 512;

    f32x4 acc[4][4] = {};
    int r16 = lane & 15, cr = lane >> 4;

    for (int k0 = 0; k0 < K; k0 += 32) {
        gload_lds16(aSrc[0] + k0, ldsAw0);
        gload_lds16(aSrc[1] + k0, ldsAw0 + 2048);
        gload_lds16(bSrc[0] + k0, ldsBw0);
        gload_lds16(bSrc[1] + k0, ldsBw0 + 2048);
        __syncthreads();
        s16x8 af[4], bfr[4];
#pragma unroll
        for (int mi = 0; mi < 4; ++mi) {
            int row = wr * 64 + mi * 16 + r16;
            af[mi] = *(const s16x8*)&ldsA[row * 32 + ((cr ^ ((row >> 1) & 3)) << 3)];
        }
#pragma unroll
        for (int ni = 0; ni < 4; ++ni) {
            int row = wc * 64 + ni * 16 + r16;
            bfr[ni] = *(const s16x8*)&ldsB[row * 32 + ((cr ^ ((row >> 1) & 3)) << 3)];
        }
#pragma unroll
        for (int mi = 0; mi < 4; ++mi)
#pragma unroll
            for (int ni = 0; ni < 4; ++ni)
                acc[mi][ni] = __builtin_amdgcn_mfma_f32_16x16x32_bf16(af[mi], bfr[ni],
                                                                      acc[mi][ni], 0, 0, 0);
        __syncthreads();
    }

    const float* bias_e = bias ? (bias + (MODE ? (size_t)e * N : 0)) : nullptr;
#pragma unroll
    for (int mi = 0; mi < 4; ++mi) {
#pragma unroll
        for (int ni = 0; ni < 4; ++ni) {
            int rloc = wr * 64 + mi * 16 + (lane >> 4) * 4;
            int col = n0 + wc * 64 + ni * 16 + (lane & 15);
#pragma unroll
            for (int jj = 0; jj < 4; ++jj) {
                int rl = m0 + rloc + jj;
                if (rl >= cnt) continue;
                float val = acc[mi][ni][jj];
                if (bias_e) val += bias_e[col];
                if (GELU) val = gelu_exact(val);
                size_t crow = (MODE == 0) ? (size_t)rl : (size_t)(off + rl);
                if (res) val += res[crow * N + col];
                if (OUTF) C[crow * N + col] = val;
                if (OUTB) Cb[crow * N + col] = f2bf(val);
            }
        }
    }
}

// ---------------- Flash attention (bf16 in/out, fp32 math, LDS-tiled) ----------------
template <int HD>
__global__ __launch_bounds__(256) void fattn_kernel(const u16* __restrict__ Qb,
                                                    const u16* __restrict__ Kb,
                                                    const u16* __restrict__ Vb,
                                                    u16* __restrict__ O,
                                                    int stride, int nh, int nkv, float scale) {
    constexpr int QT = 32, KT = 32;
    constexpr int SP = HD + 4;
    constexpr int NM = HD / 32;
    __shared__ float Qs[QT][SP];
    __shared__ float Ks[KT][SP];
    __shared__ float Vs[KT][SP];
    __shared__ float Ps[QT][KT + 1];
    __shared__ float m_s[QT], l_s[QT], msc[QT];

    int tid = threadIdx.x;
    int q0 = blockIdx.x * QT, h = blockIdx.y, b = blockIdx.z;
    int kvh = h / (nh / nkv);

    const u16* Qbase = Qb + (size_t)(b * L_SEQ + q0) * stride + h * HD;
    const u16* Kbase = Kb + (size_t)b * L_SEQ * stride + (size_t)kvh * HD;
    const u16* Vbase = Vb + (size_t)b * L_SEQ * stride + (size_t)kvh * HD;

    constexpr int C8 = HD / 8;
    constexpr int NCH = QT * C8;
    for (int idx = tid; idx < NCH; idx += 256) {
        int r = idx / C8, c8 = idx % C8;
        u16x8 q8 = *(const u16x8*)(Qbase + (size_t)r * stride + c8 * 8);
#pragma unroll
        for (int j = 0; j < 8; ++j) Qs[r][c8 * 8 + j] = b2f(q8[j]) * scale;
    }
    if (tid < QT) { m_s[tid] = -1e30f; l_s[tid] = 0.f; }

    int ip = tid >> 3, c = tid & 7;
    float4 acc[NM];
#pragma unroll
    for (int m = 0; m < NM; ++m) acc[m] = make_float4(0.f, 0.f, 0.f, 0.f);

    int i0 = (tid >> 4) << 1, j0 = (tid & 15) << 1;

    for (int kt = 0; kt < L_SEQ / KT; ++kt) {
        for (int idx = tid; idx < NCH; idx += 256) {
            int r = idx / C8, c8 = idx % C8;
            size_t goff = (size_t)(kt * KT + r) * stride + c8 * 8;
            u16x8 k8 = *(const u16x8*)(Kbase + goff);
            u16x8 v8 = *(const u16x8*)(Vbase + goff);
#pragma unroll
            for (int j = 0; j < 8; ++j) {
                Ks[r][c8 * 8 + j] = b2f(k8[j]);
                Vs[r][c8 * 8 + j] = b2f(v8[j]);
            }
        }
        __syncthreads();
        float s00 = 0.f, s01 = 0.f, s10 = 0.f, s11 = 0.f;
#pragma unroll 4
        for (int d = 0; d < HD; d += 4) {
            float4 qa = *(const float4*)&Qs[i0][d];
            float4 qb4 = *(const float4*)&Qs[i0 + 1][d];
            float4 ka = *(const float4*)&Ks[j0][d];
            float4 kb4 = *(const float4*)&Ks[j0 + 1][d];
            s00 += qa.x * ka.x + qa.y * ka.y + qa.z * ka.z + qa.w * ka.w;
            s01 += qa.x * kb4.x + qa.y * kb4.y + qa.z * kb4.z + qa.w * kb4.w;
            s10 += qb4.x * ka.x + qb4.y * ka.y + qb4.z * ka.z + qb4.w * ka.w;
            s11 += qb4.x * kb4.x + qb4.y * kb4.y + qb4.z * kb4.z + qb4.w * kb4.w;
        }
        Ps[i0][j0] = s00;
        Ps[i0][j0 + 1] = s01;
        Ps[i0 + 1][j0] = s10;
        Ps[i0 + 1][j0 + 1] = s11;
        __syncthreads();
        {
            float mx = -1e30f;
#pragma unroll
            for (int k = 0; k < 4; ++k) mx = fmaxf(mx, Ps[ip][c * 4 + k]);
            mx = fmaxf(mx, __shfl_xor(mx, 1));
            mx = fmaxf(mx, __shfl_xor(mx, 2));
            mx = fmaxf(mx, __shfl_xor(mx, 4));
            if (c == 0) {
                float mo = m_s[ip];
                float mn = fmaxf(mo, mx);
                m_s[ip] = mn;
                msc[ip] = __expf(mo - mn);
            }
        }
        __syncthreads();
        {
            float mn = m_s[ip];
            float sm = 0.f;
#pragma unroll
            for (int k = 0; k < 4; ++k) {
                float p = __expf(Ps[ip][c * 4 + k] - mn);
                Ps[ip][c * 4 + k] = p;
                sm += p;
            }
            sm += __shfl_xor(sm, 1);
            sm += __shfl_xor(sm, 2);
            sm += __shfl_xor(sm, 4);
            if (c == 0) l_s[ip] = l_s[ip] * msc[ip] + sm;
        }
        __syncthreads();
        {
            float sc = msc[ip];
#pragma unroll
            for (int m = 0; m < NM; ++m) {
                acc[m].x *= sc; acc[m].y *= sc; acc[m].z *= sc; acc[m].w *= sc;
            }
            for (int j = 0; j < KT; ++j) {
                float p = Ps[ip][j];
#pragma unroll
                for (int m = 0; m < NM; ++m) {
                    float4 v = *(const float4*)&Vs[j][c * 4 + m * 32];
                    acc[m].x += p * v.x; acc[m].y += p * v.y;
                    acc[m].z += p * v.z; acc[m].w += p * v.w;
                }
            }
        }
        __syncthreads();
    }
    float invl = 1.0f / l_s[ip];
    u16* orow = O + (size_t)(b * L_SEQ + q0 + ip) * (nh * HD) + h * HD + c * 4;
#pragma unroll
    for (int m = 0; m < NM; ++m) {
        U16x4 o4;
        o4.a = f2bf(acc[m].x * invl);
        o4.b = f2bf(acc[m].y * invl);
        o4.c = f2bf(acc[m].z * invl);
        o4.d = f2bf(acc[m].w * invl);
        *(U16x4*)(orow + m * 32) = o4;
    }
}

// ---------------- DeltaNet conv + gate (bf16 in/out, fp32 math) ----------------
__global__ __launch_bounds__(256) void conv_gate_kernel(const u16* __restrict__ gv,
                                                        const float* __restrict__ cw,
                                                        const float* __restrict__ cb,
                                                        u16* __restrict__ gated) {
    int idx = blockIdx.x * 256 + threadIdx.x;
    if (idx >= T_TOK * D_MOD) return;
    int d = idx & (D_MOD - 1);
    int t = idx >> 10;
    int l = t & (L_SEQ - 1);
    float conv = cb[d];
#pragma unroll
    for (int i = 0; i < DC_K; ++i) {
        int lp = l - (DC_K - 1) + i;
        if (lp >= 0)
            conv += b2f(gv[(size_t)(t - l + lp) * (2 * D_MOD) + D_MOD + d]) * cw[d * DC_K + i];
    }
    float gate = b2f(gv[(size_t)t * (2 * D_MOD) + d]);
    float sig = 1.0f / (1.0f + expf(-gate));
    gated[(size_t)t * D_MOD + d] = f2bf(conv * (gate * sig));
}

// ---------------- MoE routing (fp32 input) ----------------
__global__ __launch_bounds__(256) void route_kernel(const float* __restrict__ g,
                                                    const float* __restrict__ wg,
                                                    int* __restrict__ tIdx,
                                                    float* __restrict__ tScore,
                                                    int* __restrict__ counts) {
    int t = blockIdx.x, tid = threadIdx.x;
    __shared__ float gs[D_MOD];
    __shared__ float logits[N_E];
    ((float4*)gs)[tid] = ((const float4*)(g + (size_t)t * D_MOD))[tid];
    __syncthreads();
    int e = tid >> 5, lane = tid & 31;
    const float* w = wg + (size_t)e * D_MOD;
    float p = 0.f;
    for (int d = lane; d < D_MOD; d += 32) p += gs[d] * w[d];
    for (int o = 16; o > 0; o >>= 1) p += __shfl_down(p, o, 32);
    if (lane == 0) logits[e] = p;
    __syncthreads();
    if (tid == 0) {
        float mx = logits[0];
        for (int e2 = 1; e2 < N_E; ++e2) mx = fmaxf(mx, logits[e2]);
        float pe[N_E];
        float Z = 0.f;
        for (int e2 = 0; e2 < N_E; ++e2) {
            pe[e2] = expf(logits[e2] - mx);
            Z += pe[e2];
        }
        int i0 = 0;
        float b0 = pe[0];
        for (int e2 = 1; e2 < N_E; ++e2)
            if (pe[e2] > b0) { b0 = pe[e2]; i0 = e2; }
        int i1 = -1;
        float b1 = -1.f;
        for (int e2 = 0; e2 < N_E; ++e2)
            if (e2 != i0 && pe[e2] > b1) { b1 = pe[e2]; i1 = e2; }
        float invZ = 1.0f / Z;
        tIdx[t * 2] = i0;
        tIdx[t * 2 + 1] = i1;
        tScore[t * 2] = b0 * invZ;
        tScore[t * 2 + 1] = b1 * invZ;
        atomicAdd(&counts[i0], 1);
        atomicAdd(&counts[i1], 1);
    }
}

__global__ void prefix_kernel(const int* __restrict__ counts, int* __restrict__ offs,
                              int* __restrict__ cursor) {
    if (threadIdx.x == 0) {
        int acc = 0;
        for (int e = 0; e < N_E; ++e) {
            offs[e] = acc;
            acc += counts[e];
            cursor[e] = 0;
        }
    }
}

__global__ __launch_bounds__(256) void fill_kernel(const int* __restrict__ tIdx,
                                                   const int* __restrict__ offs,
                                                   int* __restrict__ cursor,
                                                   int* __restrict__ list,
                                                   int* __restrict__ pairRow) {
    int t = blockIdx.x * 256 + threadIdx.x;
    if (t >= T_TOK) return;
    for (int kk = 0; kk < 2; ++kk) {
        int e = tIdx[t * 2 + kk];
        int pos = atomicAdd(&cursor[e], 1);
        int slot = offs[e] + pos;
        list[slot] = t;
        pairRow[t * 2 + kk] = slot;
    }
}

// ---------------- MoE combine (bf16 ysel) ----------------
__global__ __launch_bounds__(256) void combine_kernel(const u16* __restrict__ ysel,
                                                      const float* __restrict__ tScore,
                                                      const int* __restrict__ pairRow,
                                                      float* __restrict__ h) {
    int idx = blockIdx.x * 256 + threadIdx.x;
    if (idx >= T_TOK * D_MOD) return;
    int t = idx >> 10;
    int d = idx & (D_MOD - 1);
    float acc = h[idx];
#pragma unroll
    for (int kk = 0; kk < 2; ++kk) {
        int r = pairRow[t * 2 + kk];
        acc += tScore[t * 2 + kk] * b2f(ysel[(size_t)r * D_MOD + d]);
    }
    h[idx] = acc;
}

extern "C" void kernel_launch(void* const* d_in, const int* in_sizes, int n_in,
                              void* d_out, int out_size, void* d_ws, size_t ws_size,
                              hipStream_t stream) {
    const float* x = (const float*)d_in[0];
    const float* w_rms1 = (const float*)d_in[2];
    const float* w_rms2 = (const float*)d_in[3];
    const float* w_rms3 = (const float*)d_in[4];
    const float* w_rms4 = (const float*)d_in[5];
    const float* Wq = (const float*)d_in[6];
    const float* Wk = (const float*)d_in[7];
    const float* Wv = (const float*)d_in[8];
    const float* Wo = (const float*)d_in[9];
    const float* Cq = (const float*)d_in[10];
    const float* Ck = (const float*)d_in[11];
    const float* Cv = (const float*)d_in[12];
    const float* Co = (const float*)d_in[13];
    const float* Wi = (const float*)d_in[14];
    const float* bi = (const float*)d_in[15];
    const float* conv_w = (const float*)d_in[16];
    const float* conv_b = (const float*)d_in[17];
    const float* Wod = (const float*)d_in[18];
    const float* bod = (const float*)d_in[19];
    const float* w_gate = (const float*)d_in[20];
    const float* W1 = (const float*)d_in[21];
    const float* b1 = (const float*)d_in[22];
    const float* W2 = (const float*)d_in[23];
    const float* b2 = (const float*)d_in[24];
    float* out = (float*)d_out;

    char* ws = (char*)d_ws;
    size_t off = 0;
    auto alloc_f = [&](size_t n) { float* p = (float*)(ws + off); off += n * 4; return p; };
    auto alloc_b = [&](size_t n) { u16* p = (u16*)(ws + off); off += n * 2; return p; };

    // bf16 transposed weights (persistent through the call)
    u16* qkvT = alloc_b((size_t)1536 * 1024);
    u16* cqkvT = alloc_b((size_t)3072 * 1024);
    u16* WoT = alloc_b((size_t)1024 * 1024);
    u16* CoT = alloc_b((size_t)1024 * 1024);
    u16* WiT = alloc_b((size_t)2048 * 1024);
    u16* WodT = alloc_b((size_t)1024 * 1024);
    u16* W1T = alloc_b((size_t)N_E * FF_DIM * 1024);
    u16* W2T = alloc_b((size_t)N_E * 1024 * FF_DIM);
    // activations
    const size_t TD = (size_t)T_TOK * D_MOD;
    float* h = alloc_f(TD);
    float* nrm = alloc_f(TD);
    u16* nrm_bf = alloc_b(TD);
    u16* h_bf = alloc_b(TD);
    u16* ab_bf = alloc_b(TD);
    u16* qkv_bf = alloc_b((size_t)T_TOK * 3072);
    u16* gv_bf = alloc_b((size_t)T_TOK * 2048);
    u16* hsel = alloc_b((size_t)2 * T_TOK * FF_DIM);
    u16* ysel = alloc_b((size_t)2 * T_TOK * D_MOD);
    int* counts = (int*)(ws + off); off += N_E * 4;
    int* offs = (int*)(ws + off); off += N_E * 4;
    int* cursor = (int*)(ws + off); off += N_E * 4;
    int* tIdx = (int*)(ws + off); off += 2 * T_TOK * 4;
    int* list = (int*)(ws + off); off += 2 * T_TOK * 4;
    int* pairRow = (int*)(ws + off); off += 2 * T_TOK * 4;
    float* tScore = alloc_f(2 * T_TOK);

    // ---- 0. weight transpose+convert (each weight read exactly once) ----
    transpose_cvt<<<dim3(32, 32, 1), 256, 0, stream>>>(Wq, qkvT, 1024, 1024, 1024, 0);
    transpose_cvt<<<dim3(8, 32, 1), 256, 0, stream>>>(Wk, qkvT, 1024, 256, 1024, 1024);
    transpose_cvt<<<dim3(8, 32, 1), 256, 0, stream>>>(Wv, qkvT, 1024, 256, 1024, 1280);
    transpose_cvt<<<dim3(32, 32, 1), 256, 0, stream>>>(Cq, cqkvT, 1024, 1024, 1024, 0);
    transpose_cvt<<<dim3(32, 32, 1), 256, 0, stream>>>(Ck, cqkvT, 1024, 1024, 1024, 1024);
    transpose_cvt<<<dim3(32, 32, 1), 256, 0, stream>>>(Cv, cqkvT, 1024, 1024, 1024, 2048);
    transpose_cvt<<<dim3(32, 32, 1), 256, 0, stream>>>(Wo, WoT, 1024, 1024, 1024, 0);
    transpose_cvt<<<dim3(32, 32, 1), 256, 0, stream>>>(Co, CoT, 1024, 1024, 1024, 0);
    transpose_cvt<<<dim3(64, 32, 1), 256, 0, stream>>>(Wi, WiT, 1024, 2048, 1024, 0);
    transpose_cvt<<<dim3(32, 32, 1), 256, 0, stream>>>(Wod, WodT, 1024, 1024, 1024, 0);
    transpose_cvt<<<dim3(128, 32, N_E), 256, 0, stream>>>(W1, W1T, 1024, FF_DIM, 1024, 0);
    transpose_cvt<<<dim3(32, 128, N_E), 256, 0, stream>>>(W2, W2T, FF_DIM, 1024, FF_DIM, 0);

    // ---- 1. attn1 (GQA 16h/4kv, hd=64) ----
    rmsnorm_kernel<<<T_TOK, 256, 0, stream>>>(x, w_rms1, nullptr, nrm_bf);
    mfma_gemm<0, 0, 0, 1><<<dim3(12, 16, 1), 256, 0, stream>>>(
        nrm_bf, qkvT, nullptr, nullptr, nullptr, qkv_bf, nullptr, nullptr, nullptr,
        T_TOK, 1536, 1024);
    fattn_kernel<64><<<dim3(32, N_H, B_SZ), 256, 0, stream>>>(
        qkv_bf, qkv_bf + 1024, qkv_bf + 1280, ab_bf, 1536, N_H, N_KV, 0.125f);
    mfma_gemm<0, 0, 1, 1><<<dim3(8, 16, 1), 256, 0, stream>>>(
        ab_bf, WoT, nullptr, x, h, h_bf, nullptr, nullptr, nullptr, T_TOK, 1024, 1024);

    // ---- 2. ContextManager attention (8h/8kv, hd=128) ----
    mfma_gemm<0, 0, 0, 1><<<dim3(24, 16, 1), 256, 0, stream>>>(
        h_bf, cqkvT, nullptr, nullptr, nullptr, qkv_bf, nullptr, nullptr, nullptr,
        T_TOK, 3072, 1024);
    fattn_kernel<128><<<dim3(32, N_CH, B_SZ), 256, 0, stream>>>(
        qkv_bf, qkv_bf + 1024, qkv_bf + 2048, ab_bf, 3072, N_CH, N_CH, 0.088388347648318447f);
    mfma_gemm<0, 0, 1, 0><<<dim3(8, 16, 1), 256, 0, stream>>>(
        ab_bf, CoT, nullptr, h, h, nullptr, nullptr, nullptr, nullptr, T_TOK, 1024, 1024);

    // ---- 3. deltanet ----
    rmsnorm_kernel<<<T_TOK, 256, 0, stream>>>(h, w_rms2, nullptr, nrm_bf);
    mfma_gemm<0, 0, 0, 1><<<dim3(16, 16, 1), 256, 0, stream>>>(
        nrm_bf, WiT, bi, nullptr, nullptr, gv_bf, nullptr, nullptr, nullptr, T_TOK, 2048, 1024);
    conv_gate_kernel<<<(T_TOK * D_MOD) / 256, 256, 0, stream>>>(gv_bf, conv_w, conv_b, ab_bf);
    mfma_gemm<0, 0, 1, 0><<<dim3(8, 16, 1), 256, 0, stream>>>(
        ab_bf, WodT, bod, h, h, nullptr, nullptr, nullptr, nullptr, T_TOK, 1024, 1024);

    // ---- 4. MoE (top-2 of 8) ----
    rmsnorm_kernel<<<T_TOK, 256, 0, stream>>>(h, w_rms3, nrm, nrm_bf);
    hipMemsetAsync(counts, 0, N_E * sizeof(int), stream);
    route_kernel<<<T_TOK, 256, 0, stream>>>(nrm, w_gate, tIdx, tScore, counts);
    prefix_kernel<<<1, 64, 0, stream>>>(counts, offs, cursor);
    fill_kernel<<<(T_TOK + 255) / 256, 256, 0, stream>>>(tIdx, offs, cursor, list, pairRow);
    mfma_gemm<1, 1, 0, 1><<<dim3(FF_DIM / 128, 32, N_E), 256, 0, stream>>>(
        nrm_bf, W1T, b1, nullptr, nullptr, hsel, list, offs, counts, T_TOK, FF_DIM, 1024);
    mfma_gemm<2, 0, 0, 1><<<dim3(1024 / 128, 32, N_E), 256, 0, stream>>>(
        hsel, W2T, b2, nullptr, nullptr, ysel, list, offs, counts, T_TOK, 1024, FF_DIM);
    combine_kernel<<<(T_TOK * D_MOD) / 256, 256, 0, stream>>>(ysel, tScore, pairRow, h);

    // ---- 5. final rmsnorm -> out ----
    rmsnorm_kernel<<<T_TOK, 256, 0, stream>>>(h, w_rms4, out, nullptr);
}

// Round 4
// 896.383 us; speedup vs baseline: 6.1096x; 1.4161x over previous
//
#include <hip/hip_runtime.h>
#include <hip/hip_bf16.h>
#include <math.h>

#define T_TOK 2048
#define B_SZ 2
#define L_SEQ 1024
#define D_MOD 1024
#define N_H 16
#define N_KV 4
#define N_CH 8
#define N_E 8
#define FF_DIM 4096
#define DC_K 4
#define EPS_F 1e-6f

typedef unsigned short u16;
typedef unsigned int u32;
typedef short s16x8 __attribute__((ext_vector_type(8)));
typedef u16 u16x8 __attribute__((ext_vector_type(8)));
typedef float f32x4 __attribute__((ext_vector_type(4)));
struct alignas(8) U16x4 { u16 a, b, c, d; };

__device__ __forceinline__ float gelu_exact(float x) {
    return 0.5f * x * (1.0f + erff(x * 0.70710678118654752f));
}
__device__ __forceinline__ u16 f2bf(float f) {  // RNE
    u32 x = __float_as_uint(f);
    return (u16)((x + 0x7fffu + ((x >> 16) & 1u)) >> 16);
}
__device__ __forceinline__ float b2f(u16 u) {
    return __uint_as_float(((u32)u) << 16);
}
__device__ __forceinline__ void gload_lds16(const u16* g, u16* l) {
    __builtin_amdgcn_global_load_lds(
        (const __attribute__((address_space(1))) u32*)g,
        (__attribute__((address_space(3))) u32*)l, 16, 0, 0);
}

// ---------------- transpose + fp32->bf16 convert: dst[c][r] = src[r][c] ----------------
__global__ __launch_bounds__(256) void transpose_cvt(const float* __restrict__ src,
                                                     u16* __restrict__ dst,
                                                     int R, int C, int dstStride, int dstRowOff) {
    __shared__ float t[32][33];
    int e = blockIdx.z;
    src += (size_t)e * R * C;
    dst += (size_t)e * (size_t)C * dstStride;
    int c0 = blockIdx.x * 32, r0 = blockIdx.y * 32;
    int tx = threadIdx.x & 31, ty = threadIdx.x >> 5;
#pragma unroll
    for (int i = 0; i < 4; ++i) {
        int r = r0 + ty + i * 8;
        if (r < R && c0 + tx < C) t[tx][ty + i * 8] = src[(size_t)r * C + c0 + tx];
    }
    __syncthreads();
#pragma unroll
    for (int i = 0; i < 4; ++i) {
        int c = c0 + ty + i * 8, rr = r0 + tx;
        if (c < C && rr < R)
            dst[(size_t)(dstRowOff + c) * dstStride + rr] = f2bf(t[ty + i * 8][tx]);
    }
}

// ---------------- RMSNorm: fp32 in, optional fp32 + bf16 out ----------------
__global__ __launch_bounds__(256) void rmsnorm_kernel(const float* __restrict__ x,
                                                      const float* __restrict__ w,
                                                      float* __restrict__ fo,
                                                      u16* __restrict__ bo) {
    int row = blockIdx.x;
    int tid = threadIdx.x;
    const float* xr = x + (size_t)row * D_MOD;
    float4 v = ((const float4*)xr)[tid];
    float ss = v.x * v.x + v.y * v.y + v.z * v.z + v.w * v.w;
    __shared__ float red[256];
    red[tid] = ss;
    __syncthreads();
    for (int s = 128; s > 0; s >>= 1) {
        if (tid < s) red[tid] += red[tid + s];
        __syncthreads();
    }
    float inv = 1.0f / sqrtf(red[0] * (1.0f / D_MOD) + EPS_F);
    float4 wv = ((const float4*)w)[tid];
    float4 o;
    o.x = v.x * inv * wv.x;
    o.y = v.y * inv * wv.y;
    o.z = v.z * inv * wv.z;
    o.w = v.w * inv * wv.w;
    if (fo) ((float4*)(fo + (size_t)row * D_MOD))[tid] = o;
    if (bo) {
        U16x4 b;
        b.a = f2bf(o.x); b.b = f2bf(o.y); b.c = f2bf(o.z); b.d = f2bf(o.w);
        *(U16x4*)(bo + (size_t)row * D_MOD + tid * 4) = b;
    }
}

// ---------------- MFMA bf16 GEMM (unchanged from round 3) ----------------
template <int MODE, int GELU, int OUTF, int OUTB>
__global__ __launch_bounds__(256) void mfma_gemm(const u16* __restrict__ A,
                                                 const u16* __restrict__ BT,
                                                 const float* __restrict__ bias,
                                                 const float* __restrict__ res,
                                                 float* __restrict__ C,
                                                 u16* __restrict__ Cb,
                                                 const int* __restrict__ list,
                                                 const int* __restrict__ offs,
                                                 const int* __restrict__ counts,
                                                 int M, int N, int K) {
    __shared__ u16 ldsA[128 * 32];
    __shared__ u16 ldsB[128 * 32];
    int tid = threadIdx.x;
    int lane = tid & 63, w = tid >> 6;
    int wr = w >> 1, wc = w & 1;
    int e = blockIdx.z;
    int cnt, off;
    if (MODE == 0) { cnt = M; off = 0; }
    else { cnt = counts[e]; off = offs[e]; }
    int m0 = blockIdx.y * 128;
    if (m0 >= cnt) return;
    int n0 = blockIdx.x * 128;
    const u16* Bt = BT + (size_t)e * (size_t)N * K;

    const u16* aSrc[2];
    const u16* bSrc[2];
#pragma unroll
    for (int j = 0; j < 2; ++j) {
        int rowA = w * 16 + (lane >> 2) + j * 64;
        int slot = lane & 3;
        int rl = m0 + rowA;
        if (rl >= cnt) rl = cnt - 1;
        size_t ga;
        if (MODE == 1) ga = (size_t)list[off + rl] * K;
        else if (MODE == 2) ga = (size_t)(off + rl) * K;
        else ga = (size_t)rl * K;
        aSrc[j] = A + ga + ((slot ^ ((rowA >> 1) & 3)) << 3);
        bSrc[j] = Bt + (size_t)(n0 + rowA) * K + ((slot ^ ((rowA >> 1) & 3)) << 3);
    }
    u16* ldsAw0 = ldsA + w * 512;
    u16* ldsBw0 = ldsB + w * 512;

    f32x4 acc[4][4] = {};
    int r16 = lane & 15, cr = lane >> 4;

    for (int k0 = 0; k0 < K; k0 += 32) {
        gload_lds16(aSrc[0] + k0, ldsAw0);
        gload_lds16(aSrc[1] + k0, ldsAw0 + 2048);
        gload_lds16(bSrc[0] + k0, ldsBw0);
        gload_lds16(bSrc[1] + k0, ldsBw0 + 2048);
        __syncthreads();
        s16x8 af[4], bfr[4];
#pragma unroll
        for (int mi = 0; mi < 4; ++mi) {
            int row = wr * 64 + mi * 16 + r16;
            af[mi] = *(const s16x8*)&ldsA[row * 32 + ((cr ^ ((row >> 1) & 3)) << 3)];
        }
#pragma unroll
        for (int ni = 0; ni < 4; ++ni) {
            int row = wc * 64 + ni * 16 + r16;
            bfr[ni] = *(const s16x8*)&ldsB[row * 32 + ((cr ^ ((row >> 1) & 3)) << 3)];
        }
#pragma unroll
        for (int mi = 0; mi < 4; ++mi)
#pragma unroll
            for (int ni = 0; ni < 4; ++ni)
                acc[mi][ni] = __builtin_amdgcn_mfma_f32_16x16x32_bf16(af[mi], bfr[ni],
                                                                      acc[mi][ni], 0, 0, 0);
        __syncthreads();
    }

    const float* bias_e = bias ? (bias + (MODE ? (size_t)e * N : 0)) : nullptr;
#pragma unroll
    for (int mi = 0; mi < 4; ++mi) {
#pragma unroll
        for (int ni = 0; ni < 4; ++ni) {
            int rloc = wr * 64 + mi * 16 + (lane >> 4) * 4;
            int col = n0 + wc * 64 + ni * 16 + (lane & 15);
#pragma unroll
            for (int jj = 0; jj < 4; ++jj) {
                int rl = m0 + rloc + jj;
                if (rl >= cnt) continue;
                float val = acc[mi][ni][jj];
                if (bias_e) val += bias_e[col];
                if (GELU) val = gelu_exact(val);
                size_t crow = (MODE == 0) ? (size_t)rl : (size_t)(off + rl);
                if (res) val += res[crow * N + col];
                if (OUTF) C[crow * N + col] = val;
                if (OUTB) Cb[crow * N + col] = f2bf(val);
            }
        }
    }
}

// ---------------- MFMA flash attention ----------------
// Block: 64 q-rows (4 waves x 16). KV tiles of 64. QK^T and PV on matrix cores.
// K staged via global_load_lds with XOR chunk swizzle; V staged transposed Vt[HD][72];
// P converted C-layout -> A-layout via per-wave XOR-swizzled LDS tile.
template <int HD>
__global__ __launch_bounds__(256) void mfma_attn(const u16* __restrict__ Qb,
                                                 const u16* __restrict__ Kb,
                                                 const u16* __restrict__ Vb,
                                                 u16* __restrict__ O,
                                                 int stride, int ostride,
                                                 int nh, int nkv, float scale) {
    constexpr int KT = 64;
    constexpr int CH = HD / 8;          // 16B chunks per K row
    constexpr int NF = HD / 32;         // K-frags along HD for QK
    constexpr int ND = HD / 16;         // d-subtiles for PV
    constexpr int VSTR = 72;            // Vt row stride (u16), 16B-aligned, conflict-spread
    constexpr int NISS = (64 * CH) / (64 * 4);  // global_load_lds issues per wave (2 or 4)

    __shared__ u16 Kl[64 * HD];
    __shared__ u16 Vt[HD * VSTR];
    __shared__ u16 Pl[4][16 * 72];

    int tid = threadIdx.x, lane = tid & 63, w = tid >> 6;
    int g = lane >> 4, r16 = lane & 15;
    int q0 = blockIdx.x * 64, h = blockIdx.y, b = blockIdx.z;
    int kvh = h / (nh / nkv);

    // Q fragments (A-layout): lane holds Q[q0+w*16+r16][f*32 + g*8 + j]
    const u16* Qp = Qb + (size_t)(b * L_SEQ + q0 + w * 16 + r16) * stride + h * HD + g * 8;
    s16x8 qf[NF];
#pragma unroll
    for (int f = 0; f < NF; ++f) qf[f] = *(const s16x8*)(Qp + f * 32);

    const u16* Kbase = Kb + (size_t)(b * L_SEQ) * stride + (size_t)kvh * HD;
    const u16* Vbase = Vb + (size_t)(b * L_SEQ) * stride + (size_t)kvh * HD;

    // K staging source offsets (pre-swizzled global source, linear LDS dest)
    int srcOffK[NISS];
#pragma unroll
    for (int i = 0; i < NISS; ++i) {
        int ci = (w * NISS + i) * 64 + lane;
        int row = ci / CH;
        int ch = ci % CH;
        srcOffK[i] = row * stride + ((ch ^ (row & 7)) << 3);
    }

    f32x4 ofr[ND] = {};
    float m_r[4], l_r[4];
#pragma unroll
    for (int r = 0; r < 4; ++r) { m_r[r] = -1e30f; l_r[r] = 0.f; }

    for (int kt = 0; kt < L_SEQ / KT; ++kt) {
        const u16* Ksrc = Kbase + (size_t)(kt * KT) * stride;
        const u16* Vsrc = Vbase + (size_t)(kt * KT) * stride;
        __syncthreads();  // previous tile's LDS reads complete
#pragma unroll
        for (int i = 0; i < NISS; ++i)
            gload_lds16(Ksrc + srcOffK[i], Kl + (size_t)(w * NISS + i) * 512);
        // V transposed staging: lane owns k-row `lane`, wave owns 16-d block
#pragma unroll
        for (int half = 0; half < HD / 64; ++half) {
            int dbase = w * 16 + half * 64;
            u16x8 v0 = *(const u16x8*)(Vsrc + (size_t)lane * stride + dbase);
            u16x8 v1 = *(const u16x8*)(Vsrc + (size_t)lane * stride + dbase + 8);
#pragma unroll
            for (int j = 0; j < 8; ++j) {
                Vt[(dbase + j) * VSTR + lane] = v0[j];
                Vt[(dbase + 8 + j) * VSTR + lane] = v1[j];
            }
        }
        __syncthreads();

        // S = Q K^T : 4 k-subtiles of 16 cols
        f32x4 s[4];
#pragma unroll
        for (int sub = 0; sub < 4; ++sub) {
            f32x4 acc = {};
#pragma unroll
            for (int f = 0; f < NF; ++f) {
                int row = sub * 16 + r16;
                int chunk = (f * 4 + g) ^ (row & 7);
                s16x8 kf = *(const s16x8*)&Kl[(row * CH + chunk) * 8];
                acc = __builtin_amdgcn_mfma_f32_16x16x32_bf16(qf[f], kf, acc, 0, 0, 0);
            }
            s[sub] = acc;
        }

        // online softmax (rows live in 16-lane groups; reg r picks q-row)
#pragma unroll
        for (int sub = 0; sub < 4; ++sub)
#pragma unroll
            for (int r = 0; r < 4; ++r) s[sub][r] *= scale;
#pragma unroll
        for (int r = 0; r < 4; ++r) {
            float mx = fmaxf(fmaxf(s[0][r], s[1][r]), fmaxf(s[2][r], s[3][r]));
            mx = fmaxf(mx, __shfl_xor(mx, 1));
            mx = fmaxf(mx, __shfl_xor(mx, 2));
            mx = fmaxf(mx, __shfl_xor(mx, 4));
            mx = fmaxf(mx, __shfl_xor(mx, 8));
            float mo = m_r[r];
            float mn = fmaxf(mo, mx);
            float sc = __expf(mo - mn);
            m_r[r] = mn;
            float sum = 0.f;
#pragma unroll
            for (int sub = 0; sub < 4; ++sub) {
                float e = __expf(s[sub][r] - mn);
                s[sub][r] = e;
                sum += e;
            }
            sum += __shfl_xor(sum, 1);
            sum += __shfl_xor(sum, 2);
            sum += __shfl_xor(sum, 4);
            sum += __shfl_xor(sum, 8);
            l_r[r] = l_r[r] * sc + sum;
#pragma unroll
            for (int dsub = 0; dsub < ND; ++dsub) ofr[dsub][r] *= sc;
        }

        // P: C-layout regs -> per-wave LDS tile (XOR chunk swizzle), bf16
        u16* Pw = Pl[w];
#pragma unroll
        for (int sub = 0; sub < 4; ++sub)
#pragma unroll
            for (int r = 0; r < 4; ++r) {
                int q = g * 4 + r;
                int k = sub * 16 + r16;
                Pw[q * 72 + (((k >> 3) ^ (q & 7)) << 3) + (k & 7)] = f2bf(s[sub][r]);
            }
        __syncthreads();

        // PV: A = P (A-layout read), B = V via Vt rows
        s16x8 pf[2];
#pragma unroll
        for (int ks = 0; ks < 2; ++ks) {
            int chunk = (ks * 4 + g) ^ (r16 & 7);
            pf[ks] = *(const s16x8*)&Pw[r16 * 72 + chunk * 8];
        }
#pragma unroll
        for (int dsub = 0; dsub < ND; ++dsub)
#pragma unroll
            for (int ks = 0; ks < 2; ++ks) {
                s16x8 vf = *(const s16x8*)&Vt[(dsub * 16 + r16) * VSTR + ks * 32 + g * 8];
                ofr[dsub] = __builtin_amdgcn_mfma_f32_16x16x32_bf16(pf[ks], vf, ofr[dsub], 0, 0, 0);
            }
    }

    float inv[4];
#pragma unroll
    for (int r = 0; r < 4; ++r) inv[r] = 1.0f / l_r[r];
#pragma unroll
    for (int dsub = 0; dsub < ND; ++dsub)
#pragma unroll
        for (int r = 0; r < 4; ++r) {
            int q = q0 + w * 16 + g * 4 + r;
            O[(size_t)(b * L_SEQ + q) * ostride + h * HD + dsub * 16 + r16] =
                f2bf(ofr[dsub][r] * inv[r]);
        }
}

// ---------------- DeltaNet conv + gate (bf16 in/out, fp32 math) ----------------
__global__ __launch_bounds__(256) void conv_gate_kernel(const u16* __restrict__ gv,
                                                        const float* __restrict__ cw,
                                                        const float* __restrict__ cb,
                                                        u16* __restrict__ gated) {
    int idx = blockIdx.x * 256 + threadIdx.x;
    if (idx >= T_TOK * D_MOD) return;
    int d = idx & (D_MOD - 1);
    int t = idx >> 10;
    int l = t & (L_SEQ - 1);
    float conv = cb[d];
#pragma unroll
    for (int i = 0; i < DC_K; ++i) {
        int lp = l - (DC_K - 1) + i;
        if (lp >= 0)
            conv += b2f(gv[(size_t)(t - l + lp) * (2 * D_MOD) + D_MOD + d]) * cw[d * DC_K + i];
    }
    float gate = b2f(gv[(size_t)t * (2 * D_MOD) + d]);
    float sig = 1.0f / (1.0f + expf(-gate));
    gated[(size_t)t * D_MOD + d] = f2bf(conv * (gate * sig));
}

// ---------------- MoE routing (fp32 input) ----------------
__global__ __launch_bounds__(256) void route_kernel(const float* __restrict__ g,
                                                    const float* __restrict__ wg,
                                                    int* __restrict__ tIdx,
                                                    float* __restrict__ tScore,
                                                    int* __restrict__ counts) {
    int t = blockIdx.x, tid = threadIdx.x;
    __shared__ float gs[D_MOD];
    __shared__ float logits[N_E];
    ((float4*)gs)[tid] = ((const float4*)(g + (size_t)t * D_MOD))[tid];
    __syncthreads();
    int e = tid >> 5, lane = tid & 31;
    const float* w = wg + (size_t)e * D_MOD;
    float p = 0.f;
    for (int d = lane; d < D_MOD; d += 32) p += gs[d] * w[d];
    for (int o = 16; o > 0; o >>= 1) p += __shfl_down(p, o, 32);
    if (lane == 0) logits[e] = p;
    __syncthreads();
    if (tid == 0) {
        float mx = logits[0];
        for (int e2 = 1; e2 < N_E; ++e2) mx = fmaxf(mx, logits[e2]);
        float pe[N_E];
        float Z = 0.f;
        for (int e2 = 0; e2 < N_E; ++e2) {
            pe[e2] = expf(logits[e2] - mx);
            Z += pe[e2];
        }
        int i0 = 0;
        float b0 = pe[0];
        for (int e2 = 1; e2 < N_E; ++e2)
            if (pe[e2] > b0) { b0 = pe[e2]; i0 = e2; }
        int i1 = -1;
        float b1 = -1.f;
        for (int e2 = 0; e2 < N_E; ++e2)
            if (e2 != i0 && pe[e2] > b1) { b1 = pe[e2]; i1 = e2; }
        float invZ = 1.0f / Z;
        tIdx[t * 2] = i0;
        tIdx[t * 2 + 1] = i1;
        tScore[t * 2] = b0 * invZ;
        tScore[t * 2 + 1] = b1 * invZ;
        atomicAdd(&counts[i0], 1);
        atomicAdd(&counts[i1], 1);
    }
}

__global__ void prefix_kernel(const int* __restrict__ counts, int* __restrict__ offs,
                              int* __restrict__ cursor) {
    if (threadIdx.x == 0) {
        int acc = 0;
        for (int e = 0; e < N_E; ++e) {
            offs[e] = acc;
            acc += counts[e];
            cursor[e] = 0;
        }
    }
}

__global__ __launch_bounds__(256) void fill_kernel(const int* __restrict__ tIdx,
                                                   const int* __restrict__ offs,
                                                   int* __restrict__ cursor,
                                                   int* __restrict__ list,
                                                   int* __restrict__ pairRow) {
    int t = blockIdx.x * 256 + threadIdx.x;
    if (t >= T_TOK) return;
    for (int kk = 0; kk < 2; ++kk) {
        int e = tIdx[t * 2 + kk];
        int pos = atomicAdd(&cursor[e], 1);
        int slot = offs[e] + pos;
        list[slot] = t;
        pairRow[t * 2 + kk] = slot;
    }
}

// ---------------- MoE combine (bf16 ysel) ----------------
__global__ __launch_bounds__(256) void combine_kernel(const u16* __restrict__ ysel,
                                                      const float* __restrict__ tScore,
                                                      const int* __restrict__ pairRow,
                                                      float* __restrict__ h) {
    int idx = blockIdx.x * 256 + threadIdx.x;
    if (idx >= T_TOK * D_MOD) return;
    int t = idx >> 10;
    int d = idx & (D_MOD - 1);
    float acc = h[idx];
#pragma unroll
    for (int kk = 0; kk < 2; ++kk) {
        int r = pairRow[t * 2 + kk];
        acc += tScore[t * 2 + kk] * b2f(ysel[(size_t)r * D_MOD + d]);
    }
    h[idx] = acc;
}

extern "C" void kernel_launch(void* const* d_in, const int* in_sizes, int n_in,
                              void* d_out, int out_size, void* d_ws, size_t ws_size,
                              hipStream_t stream) {
    const float* x = (const float*)d_in[0];
    const float* w_rms1 = (const float*)d_in[2];
    const float* w_rms2 = (const float*)d_in[3];
    const float* w_rms3 = (const float*)d_in[4];
    const float* w_rms4 = (const float*)d_in[5];
    const float* Wq = (const float*)d_in[6];
    const float* Wk = (const float*)d_in[7];
    const float* Wv = (const float*)d_in[8];
    const float* Wo = (const float*)d_in[9];
    const float* Cq = (const float*)d_in[10];
    const float* Ck = (const float*)d_in[11];
    const float* Cv = (const float*)d_in[12];
    const float* Co = (const float*)d_in[13];
    const float* Wi = (const float*)d_in[14];
    const float* bi = (const float*)d_in[15];
    const float* conv_w = (const float*)d_in[16];
    const float* conv_b = (const float*)d_in[17];
    const float* Wod = (const float*)d_in[18];
    const float* bod = (const float*)d_in[19];
    const float* w_gate = (const float*)d_in[20];
    const float* W1 = (const float*)d_in[21];
    const float* b1 = (const float*)d_in[22];
    const float* W2 = (const float*)d_in[23];
    const float* b2 = (const float*)d_in[24];
    float* out = (float*)d_out;

    char* ws = (char*)d_ws;
    size_t off = 0;
    auto alloc_f = [&](size_t n) { float* p = (float*)(ws + off); off += n * 4; return p; };
    auto alloc_b = [&](size_t n) { u16* p = (u16*)(ws + off); off += n * 2; return p; };

    u16* qkvT = alloc_b((size_t)1536 * 1024);
    u16* cqkvT = alloc_b((size_t)3072 * 1024);
    u16* WoT = alloc_b((size_t)1024 * 1024);
    u16* CoT = alloc_b((size_t)1024 * 1024);
    u16* WiT = alloc_b((size_t)2048 * 1024);
    u16* WodT = alloc_b((size_t)1024 * 1024);
    u16* W1T = alloc_b((size_t)N_E * FF_DIM * 1024);
    u16* W2T = alloc_b((size_t)N_E * 1024 * FF_DIM);
    const size_t TD = (size_t)T_TOK * D_MOD;
    float* h = alloc_f(TD);
    float* nrm = alloc_f(TD);
    u16* nrm_bf = alloc_b(TD);
    u16* h_bf = alloc_b(TD);
    u16* ab_bf = alloc_b(TD);
    u16* qkv_bf = alloc_b((size_t)T_TOK * 3072);
    u16* gv_bf = alloc_b((size_t)T_TOK * 2048);
    u16* hsel = alloc_b((size_t)2 * T_TOK * FF_DIM);
    u16* ysel = alloc_b((size_t)2 * T_TOK * D_MOD);
    int* counts = (int*)(ws + off); off += N_E * 4;
    int* offs = (int*)(ws + off); off += N_E * 4;
    int* cursor = (int*)(ws + off); off += N_E * 4;
    int* tIdx = (int*)(ws + off); off += 2 * T_TOK * 4;
    int* list = (int*)(ws + off); off += 2 * T_TOK * 4;
    int* pairRow = (int*)(ws + off); off += 2 * T_TOK * 4;
    float* tScore = alloc_f(2 * T_TOK);

    // ---- 0. weight transpose+convert ----
    transpose_cvt<<<dim3(32, 32, 1), 256, 0, stream>>>(Wq, qkvT, 1024, 1024, 1024, 0);
    transpose_cvt<<<dim3(8, 32, 1), 256, 0, stream>>>(Wk, qkvT, 1024, 256, 1024, 1024);
    transpose_cvt<<<dim3(8, 32, 1), 256, 0, stream>>>(Wv, qkvT, 1024, 256, 1024, 1280);
    transpose_cvt<<<dim3(32, 32, 1), 256, 0, stream>>>(Cq, cqkvT, 1024, 1024, 1024, 0);
    transpose_cvt<<<dim3(32, 32, 1), 256, 0, stream>>>(Ck, cqkvT, 1024, 1024, 1024, 1024);
    transpose_cvt<<<dim3(32, 32, 1), 256, 0, stream>>>(Cv, cqkvT, 1024, 1024, 1024, 2048);
    transpose_cvt<<<dim3(32, 32, 1), 256, 0, stream>>>(Wo, WoT, 1024, 1024, 1024, 0);
    transpose_cvt<<<dim3(32, 32, 1), 256, 0, stream>>>(Co, CoT, 1024, 1024, 1024, 0);
    transpose_cvt<<<dim3(64, 32, 1), 256, 0, stream>>>(Wi, WiT, 1024, 2048, 1024, 0);
    transpose_cvt<<<dim3(32, 32, 1), 256, 0, stream>>>(Wod, WodT, 1024, 1024, 1024, 0);
    transpose_cvt<<<dim3(128, 32, N_E), 256, 0, stream>>>(W1, W1T, 1024, FF_DIM, 1024, 0);
    transpose_cvt<<<dim3(32, 128, N_E), 256, 0, stream>>>(W2, W2T, FF_DIM, 1024, FF_DIM, 0);

    // ---- 1. attn1 (GQA 16h/4kv, hd=64) ----
    rmsnorm_kernel<<<T_TOK, 256, 0, stream>>>(x, w_rms1, nullptr, nrm_bf);
    mfma_gemm<0, 0, 0, 1><<<dim3(12, 16, 1), 256, 0, stream>>>(
        nrm_bf, qkvT, nullptr, nullptr, nullptr, qkv_bf, nullptr, nullptr, nullptr,
        T_TOK, 1536, 1024);
    mfma_attn<64><<<dim3(16, N_H, B_SZ), 256, 0, stream>>>(
        qkv_bf, qkv_bf + 1024, qkv_bf + 1280, ab_bf, 1536, 1024, N_H, N_KV, 0.125f);
    mfma_gemm<0, 0, 1, 1><<<dim3(8, 16, 1), 256, 0, stream>>>(
        ab_bf, WoT, nullptr, x, h, h_bf, nullptr, nullptr, nullptr, T_TOK, 1024, 1024);

    // ---- 2. ContextManager attention (8h/8kv, hd=128) ----
    mfma_gemm<0, 0, 0, 1><<<dim3(24, 16, 1), 256, 0, stream>>>(
        h_bf, cqkvT, nullptr, nullptr, nullptr, qkv_bf, nullptr, nullptr, nullptr,
        T_TOK, 3072, 1024);
    mfma_attn<128><<<dim3(16, N_CH, B_SZ), 256, 0, stream>>>(
        qkv_bf, qkv_bf + 1024, qkv_bf + 2048, ab_bf, 3072, 1024, N_CH, N_CH,
        0.088388347648318447f);
    mfma_gemm<0, 0, 1, 0><<<dim3(8, 16, 1), 256, 0, stream>>>(
        ab_bf, CoT, nullptr, h, h, nullptr, nullptr, nullptr, nullptr, T_TOK, 1024, 1024);

    // ---- 3. deltanet ----
    rmsnorm_kernel<<<T_TOK, 256, 0, stream>>>(h, w_rms2, nullptr, nrm_bf);
    mfma_gemm<0, 0, 0, 1><<<dim3(16, 16, 1), 256, 0, stream>>>(
        nrm_bf, WiT, bi, nullptr, nullptr, gv_bf, nullptr, nullptr, nullptr, T_TOK, 2048, 1024);
    conv_gate_kernel<<<(T_TOK * D_MOD) / 256, 256, 0, stream>>>(gv_bf, conv_w, conv_b, ab_bf);
    mfma_gemm<0, 0, 1, 0><<<dim3(8, 16, 1), 256, 0, stream>>>(
        ab_bf, WodT, bod, h, h, nullptr, nullptr, nullptr, nullptr, T_TOK, 1024, 1024);

    // ---- 4. MoE (top-2 of 8) ----
    rmsnorm_kernel<<<T_TOK, 256, 0, stream>>>(h, w_rms3, nrm, nrm_bf);
    hipMemsetAsync(counts, 0, N_E * sizeof(int), stream);
    route_kernel<<<T_TOK, 256, 0, stream>>>(nrm, w_gate, tIdx, tScore, counts);
    prefix_kernel<<<1, 64, 0, stream>>>(counts, offs, cursor);
    fill_kernel<<<(T_TOK + 255) / 256, 256, 0, stream>>>(tIdx, offs, cursor, list, pairRow);
    mfma_gemm<1, 1, 0, 1><<<dim3(FF_DIM / 128, 32, N_E), 256, 0, stream>>>(
        nrm_bf, W1T, b1, nullptr, nullptr, hsel, list, offs, counts, T_TOK, FF_DIM, 1024);
    mfma_gemm<2, 0, 0, 1><<<dim3(1024 / 128, 32, N_E), 256, 0, stream>>>(
        hsel, W2T, b2, nullptr, nullptr, ysel, list, offs, counts, T_TOK, 1024, FF_DIM);
    combine_kernel<<<(T_TOK * D_MOD) / 256, 256, 0, stream>>>(ysel, tScore, pairRow, h);

    // ---- 5. final rmsnorm -> out ----
    rmsnorm_kernel<<<T_TOK, 256, 0, stream>>>(h, w_rms4, out, nullptr);
}

// Round 5
// 779.533 us; speedup vs baseline: 7.0254x; 1.1499x over previous
//
#include <hip/hip_runtime.h>
#include <hip/hip_bf16.h>
#include <math.h>

#define T_TOK 2048
#define B_SZ 2
#define L_SEQ 1024
#define D_MOD 1024
#define N_H 16
#define N_KV 4
#define N_CH 8
#define N_E 8
#define FF_DIM 4096
#define DC_K 4
#define EPS_F 1e-6f

typedef unsigned short u16;
typedef unsigned int u32;
typedef short s16x8 __attribute__((ext_vector_type(8)));
typedef u16 u16x8 __attribute__((ext_vector_type(8)));
typedef float f32x4 __attribute__((ext_vector_type(4)));
struct alignas(8) U16x4 { u16 a, b, c, d; };

__device__ __forceinline__ float gelu_exact(float x) {
    return 0.5f * x * (1.0f + erff(x * 0.70710678118654752f));
}
__device__ __forceinline__ u16 f2bf(float f) {  // RNE
    u32 x = __float_as_uint(f);
    return (u16)((x + 0x7fffu + ((x >> 16) & 1u)) >> 16);
}
__device__ __forceinline__ float b2f(u16 u) {
    return __uint_as_float(((u32)u) << 16);
}
__device__ __forceinline__ void gload_lds16(const u16* g, u16* l) {
    __builtin_amdgcn_global_load_lds(
        (const __attribute__((address_space(1))) u32*)g,
        (__attribute__((address_space(3))) u32*)l, 16, 0, 0);
}

// ---------------- transpose + fp32->bf16 convert: dst[c][r] = src[r][c] ----------------
__global__ __launch_bounds__(256) void transpose_cvt(const float* __restrict__ src,
                                                     u16* __restrict__ dst,
                                                     int R, int C, int dstStride, int dstRowOff) {
    __shared__ float t[32][33];
    int e = blockIdx.z;
    src += (size_t)e * R * C;
    dst += (size_t)e * (size_t)C * dstStride;
    int c0 = blockIdx.x * 32, r0 = blockIdx.y * 32;
    int tx = threadIdx.x & 31, ty = threadIdx.x >> 5;
#pragma unroll
    for (int i = 0; i < 4; ++i) {
        int r = r0 + ty + i * 8;
        if (r < R && c0 + tx < C) t[tx][ty + i * 8] = src[(size_t)r * C + c0 + tx];
    }
    __syncthreads();
#pragma unroll
    for (int i = 0; i < 4; ++i) {
        int c = c0 + ty + i * 8, rr = r0 + tx;
        if (c < C && rr < R)
            dst[(size_t)(dstRowOff + c) * dstStride + rr] = f2bf(t[ty + i * 8][tx]);
    }
}

// ---------------- RMSNorm: fp32 in, optional fp32 + bf16 out ----------------
__global__ __launch_bounds__(256) void rmsnorm_kernel(const float* __restrict__ x,
                                                      const float* __restrict__ w,
                                                      float* __restrict__ fo,
                                                      u16* __restrict__ bo) {
    int row = blockIdx.x;
    int tid = threadIdx.x;
    const float* xr = x + (size_t)row * D_MOD;
    float4 v = ((const float4*)xr)[tid];
    float ss = v.x * v.x + v.y * v.y + v.z * v.z + v.w * v.w;
    __shared__ float red[256];
    red[tid] = ss;
    __syncthreads();
    for (int s = 128; s > 0; s >>= 1) {
        if (tid < s) red[tid] += red[tid + s];
        __syncthreads();
    }
    float inv = 1.0f / sqrtf(red[0] * (1.0f / D_MOD) + EPS_F);
    float4 wv = ((const float4*)w)[tid];
    float4 o;
    o.x = v.x * inv * wv.x;
    o.y = v.y * inv * wv.y;
    o.z = v.z * inv * wv.z;
    o.w = v.w * inv * wv.w;
    if (fo) ((float4*)(fo + (size_t)row * D_MOD))[tid] = o;
    if (bo) {
        U16x4 b;
        b.a = f2bf(o.x); b.b = f2bf(o.y); b.c = f2bf(o.z); b.d = f2bf(o.w);
        *(U16x4*)(bo + (size_t)row * D_MOD + tid * 4) = b;
    }
}

// ---------------- MFMA bf16 GEMM, 2-phase double-buffered ----------------
// C[M,N](f32/bf16) = A[M,K]bf16 @ BT[N,K]bf16. Tile BM x 128, BK=32, 4 waves.
// MODE 0: dense. MODE 1: MoE gather (A row = list[off+r], C row = off+r).
// MODE 2: MoE compact. Prefetch next K-tile is issued BEFORE compute; the
// single __syncthreads (implicit vmcnt(0) drain) lands after the MFMAs, so
// staging latency hides under compute even at 1 block/CU.
template <int MODE, int GELU, int OUTF, int OUTB, int BM>
__global__ __launch_bounds__(256) void mfma_gemm(const u16* __restrict__ A,
                                                 const u16* __restrict__ BT,
                                                 const float* __restrict__ bias,
                                                 const float* __restrict__ res,
                                                 float* __restrict__ C,
                                                 u16* __restrict__ Cb,
                                                 const int* __restrict__ list,
                                                 const int* __restrict__ offs,
                                                 const int* __restrict__ counts,
                                                 int M, int N, int K) {
    constexpr int MI = BM / 32;   // acc-rows per wave (2 or 4)
    constexpr int NAI = BM / 64;  // A staging issues per wave (1 or 2)
    __shared__ u16 ldsA[2][BM * 32];
    __shared__ u16 ldsB[2][128 * 32];
    int tid = threadIdx.x;
    int lane = tid & 63, w = tid >> 6;
    int wr = w >> 1, wc = w & 1;
    int e = blockIdx.z;
    int cnt, off;
    if (MODE == 0) { cnt = M; off = 0; }
    else { cnt = counts[e]; off = offs[e]; }
    int m0 = blockIdx.y * BM;
    if (m0 >= cnt) return;
    int n0 = blockIdx.x * 128;
    const u16* Bt = BT + (size_t)e * (size_t)N * K;

    const u16* aSrc[NAI];
    const u16* bSrc[2];
#pragma unroll
    for (int j = 0; j < NAI; ++j) {
        int rowA = w * 16 + (lane >> 2) + j * 64;
        int slot = lane & 3;
        int rl = m0 + rowA;
        if (rl >= cnt) rl = cnt - 1;
        size_t ga;
        if (MODE == 1) ga = (size_t)list[off + rl] * K;
        else if (MODE == 2) ga = (size_t)(off + rl) * K;
        else ga = (size_t)rl * K;
        aSrc[j] = A + ga + ((slot ^ ((rowA >> 1) & 3)) << 3);
    }
#pragma unroll
    for (int j = 0; j < 2; ++j) {
        int rowB = w * 16 + (lane >> 2) + j * 64;
        int slot = lane & 3;
        bSrc[j] = Bt + (size_t)(n0 + rowB) * K + ((slot ^ ((rowB >> 1) & 3)) << 3);
    }

    auto stage = [&](int buf, int k0) {
        u16* la = &ldsA[buf][w * 512];
        u16* lb = &ldsB[buf][w * 512];
#pragma unroll
        for (int j = 0; j < NAI; ++j) gload_lds16(aSrc[j] + k0, la + j * 2048);
        gload_lds16(bSrc[0] + k0, lb);
        gload_lds16(bSrc[1] + k0, lb + 2048);
    };

    f32x4 acc[MI][4] = {};
    int r16 = lane & 15, cr = lane >> 4;

    stage(0, 0);
    __syncthreads();
    int cur = 0;
    for (int k0 = 0; k0 < K; k0 += 32) {
        if (k0 + 32 < K) stage(cur ^ 1, k0 + 32);
        s16x8 af[MI], bfr[4];
#pragma unroll
        for (int mi = 0; mi < MI; ++mi) {
            int row = wr * (BM / 2) + mi * 16 + r16;
            af[mi] = *(const s16x8*)&ldsA[cur][row * 32 + ((cr ^ ((row >> 1) & 3)) << 3)];
        }
#pragma unroll
        for (int ni = 0; ni < 4; ++ni) {
            int row = wc * 64 + ni * 16 + r16;
            bfr[ni] = *(const s16x8*)&ldsB[cur][row * 32 + ((cr ^ ((row >> 1) & 3)) << 3)];
        }
#pragma unroll
        for (int mi = 0; mi < MI; ++mi)
#pragma unroll
            for (int ni = 0; ni < 4; ++ni)
                acc[mi][ni] = __builtin_amdgcn_mfma_f32_16x16x32_bf16(af[mi], bfr[ni],
                                                                      acc[mi][ni], 0, 0, 0);
        __syncthreads();
        cur ^= 1;
    }

    const float* bias_e = bias ? (bias + (MODE ? (size_t)e * N : 0)) : nullptr;
#pragma unroll
    for (int mi = 0; mi < MI; ++mi) {
#pragma unroll
        for (int ni = 0; ni < 4; ++ni) {
            int rloc = wr * (BM / 2) + mi * 16 + (lane >> 4) * 4;
            int col = n0 + wc * 64 + ni * 16 + (lane & 15);
#pragma unroll
            for (int jj = 0; jj < 4; ++jj) {
                int rl = m0 + rloc + jj;
                if (rl >= cnt) continue;
                float val = acc[mi][ni][jj];
                if (bias_e) val += bias_e[col];
                if (GELU) val = gelu_exact(val);
                size_t crow = (MODE == 0) ? (size_t)rl : (size_t)(off + rl);
                if (res) val += res[crow * N + col];
                if (OUTF) C[crow * N + col] = val;
                if (OUTB) Cb[crow * N + col] = f2bf(val);
            }
        }
    }
}

// ---------------- MFMA flash attention (unchanged from round 4) ----------------
template <int HD>
__global__ __launch_bounds__(256) void mfma_attn(const u16* __restrict__ Qb,
                                                 const u16* __restrict__ Kb,
                                                 const u16* __restrict__ Vb,
                                                 u16* __restrict__ O,
                                                 int stride, int ostride,
                                                 int nh, int nkv, float scale) {
    constexpr int KT = 64;
    constexpr int CH = HD / 8;
    constexpr int NF = HD / 32;
    constexpr int ND = HD / 16;
    constexpr int VSTR = 72;
    constexpr int NISS = (64 * CH) / (64 * 4);

    __shared__ u16 Kl[64 * HD];
    __shared__ u16 Vt[HD * VSTR];
    __shared__ u16 Pl[4][16 * 72];

    int tid = threadIdx.x, lane = tid & 63, w = tid >> 6;
    int g = lane >> 4, r16 = lane & 15;
    int q0 = blockIdx.x * 64, h = blockIdx.y, b = blockIdx.z;
    int kvh = h / (nh / nkv);

    const u16* Qp = Qb + (size_t)(b * L_SEQ + q0 + w * 16 + r16) * stride + h * HD + g * 8;
    s16x8 qf[NF];
#pragma unroll
    for (int f = 0; f < NF; ++f) qf[f] = *(const s16x8*)(Qp + f * 32);

    const u16* Kbase = Kb + (size_t)(b * L_SEQ) * stride + (size_t)kvh * HD;
    const u16* Vbase = Vb + (size_t)(b * L_SEQ) * stride + (size_t)kvh * HD;

    int srcOffK[NISS];
#pragma unroll
    for (int i = 0; i < NISS; ++i) {
        int ci = (w * NISS + i) * 64 + lane;
        int row = ci / CH;
        int ch = ci % CH;
        srcOffK[i] = row * stride + ((ch ^ (row & 7)) << 3);
    }

    f32x4 ofr[ND] = {};
    float m_r[4], l_r[4];
#pragma unroll
    for (int r = 0; r < 4; ++r) { m_r[r] = -1e30f; l_r[r] = 0.f; }

    for (int kt = 0; kt < L_SEQ / KT; ++kt) {
        const u16* Ksrc = Kbase + (size_t)(kt * KT) * stride;
        const u16* Vsrc = Vbase + (size_t)(kt * KT) * stride;
        __syncthreads();
#pragma unroll
        for (int i = 0; i < NISS; ++i)
            gload_lds16(Ksrc + srcOffK[i], Kl + (size_t)(w * NISS + i) * 512);
#pragma unroll
        for (int half = 0; half < HD / 64; ++half) {
            int dbase = w * 16 + half * 64;
            u16x8 v0 = *(const u16x8*)(Vsrc + (size_t)lane * stride + dbase);
            u16x8 v1 = *(const u16x8*)(Vsrc + (size_t)lane * stride + dbase + 8);
#pragma unroll
            for (int j = 0; j < 8; ++j) {
                Vt[(dbase + j) * VSTR + lane] = v0[j];
                Vt[(dbase + 8 + j) * VSTR + lane] = v1[j];
            }
        }
        __syncthreads();

        f32x4 s[4];
#pragma unroll
        for (int sub = 0; sub < 4; ++sub) {
            f32x4 acc = {};
#pragma unroll
            for (int f = 0; f < NF; ++f) {
                int row = sub * 16 + r16;
                int chunk = (f * 4 + g) ^ (row & 7);
                s16x8 kf = *(const s16x8*)&Kl[(row * CH + chunk) * 8];
                acc = __builtin_amdgcn_mfma_f32_16x16x32_bf16(qf[f], kf, acc, 0, 0, 0);
            }
            s[sub] = acc;
        }

#pragma unroll
        for (int sub = 0; sub < 4; ++sub)
#pragma unroll
            for (int r = 0; r < 4; ++r) s[sub][r] *= scale;
#pragma unroll
        for (int r = 0; r < 4; ++r) {
            float mx = fmaxf(fmaxf(s[0][r], s[1][r]), fmaxf(s[2][r], s[3][r]));
            mx = fmaxf(mx, __shfl_xor(mx, 1));
            mx = fmaxf(mx, __shfl_xor(mx, 2));
            mx = fmaxf(mx, __shfl_xor(mx, 4));
            mx = fmaxf(mx, __shfl_xor(mx, 8));
            float mo = m_r[r];
            float mn = fmaxf(mo, mx);
            float sc = __expf(mo - mn);
            m_r[r] = mn;
            float sum = 0.f;
#pragma unroll
            for (int sub = 0; sub < 4; ++sub) {
                float e = __expf(s[sub][r] - mn);
                s[sub][r] = e;
                sum += e;
            }
            sum += __shfl_xor(sum, 1);
            sum += __shfl_xor(sum, 2);
            sum += __shfl_xor(sum, 4);
            sum += __shfl_xor(sum, 8);
            l_r[r] = l_r[r] * sc + sum;
#pragma unroll
            for (int dsub = 0; dsub < ND; ++dsub) ofr[dsub][r] *= sc;
        }

        u16* Pw = Pl[w];
#pragma unroll
        for (int sub = 0; sub < 4; ++sub)
#pragma unroll
            for (int r = 0; r < 4; ++r) {
                int q = g * 4 + r;
                int k = sub * 16 + r16;
                Pw[q * 72 + (((k >> 3) ^ (q & 7)) << 3) + (k & 7)] = f2bf(s[sub][r]);
            }
        __syncthreads();

        s16x8 pf[2];
#pragma unroll
        for (int ks = 0; ks < 2; ++ks) {
            int chunk = (ks * 4 + g) ^ (r16 & 7);
            pf[ks] = *(const s16x8*)&Pw[r16 * 72 + chunk * 8];
        }
#pragma unroll
        for (int dsub = 0; dsub < ND; ++dsub)
#pragma unroll
            for (int ks = 0; ks < 2; ++ks) {
                s16x8 vf = *(const s16x8*)&Vt[(dsub * 16 + r16) * VSTR + ks * 32 + g * 8];
                ofr[dsub] = __builtin_amdgcn_mfma_f32_16x16x32_bf16(pf[ks], vf, ofr[dsub], 0, 0, 0);
            }
    }

    float inv[4];
#pragma unroll
    for (int r = 0; r < 4; ++r) inv[r] = 1.0f / l_r[r];
#pragma unroll
    for (int dsub = 0; dsub < ND; ++dsub)
#pragma unroll
        for (int r = 0; r < 4; ++r) {
            int q = q0 + w * 16 + g * 4 + r;
            O[(size_t)(b * L_SEQ + q) * ostride + h * HD + dsub * 16 + r16] =
                f2bf(ofr[dsub][r] * inv[r]);
        }
}

// ---------------- DeltaNet conv + gate (bf16 in/out, fp32 math) ----------------
__global__ __launch_bounds__(256) void conv_gate_kernel(const u16* __restrict__ gv,
                                                        const float* __restrict__ cw,
                                                        const float* __restrict__ cb,
                                                        u16* __restrict__ gated) {
    int idx = blockIdx.x * 256 + threadIdx.x;
    if (idx >= T_TOK * D_MOD) return;
    int d = idx & (D_MOD - 1);
    int t = idx >> 10;
    int l = t & (L_SEQ - 1);
    float conv = cb[d];
#pragma unroll
    for (int i = 0; i < DC_K; ++i) {
        int lp = l - (DC_K - 1) + i;
        if (lp >= 0)
            conv += b2f(gv[(size_t)(t - l + lp) * (2 * D_MOD) + D_MOD + d]) * cw[d * DC_K + i];
    }
    float gate = b2f(gv[(size_t)t * (2 * D_MOD) + d]);
    float sig = 1.0f / (1.0f + expf(-gate));
    gated[(size_t)t * D_MOD + d] = f2bf(conv * (gate * sig));
}

// ---------------- MoE routing (fp32 input) ----------------
__global__ __launch_bounds__(256) void route_kernel(const float* __restrict__ g,
                                                    const float* __restrict__ wg,
                                                    int* __restrict__ tIdx,
                                                    float* __restrict__ tScore,
                                                    int* __restrict__ counts) {
    int t = blockIdx.x, tid = threadIdx.x;
    __shared__ float gs[D_MOD];
    __shared__ float logits[N_E];
    ((float4*)gs)[tid] = ((const float4*)(g + (size_t)t * D_MOD))[tid];
    __syncthreads();
    int e = tid >> 5, lane = tid & 31;
    const float* w = wg + (size_t)e * D_MOD;
    float p = 0.f;
    for (int d = lane; d < D_MOD; d += 32) p += gs[d] * w[d];
    for (int o = 16; o > 0; o >>= 1) p += __shfl_down(p, o, 32);
    if (lane == 0) logits[e] = p;
    __syncthreads();
    if (tid == 0) {
        float mx = logits[0];
        for (int e2 = 1; e2 < N_E; ++e2) mx = fmaxf(mx, logits[e2]);
        float pe[N_E];
        float Z = 0.f;
        for (int e2 = 0; e2 < N_E; ++e2) {
            pe[e2] = expf(logits[e2] - mx);
            Z += pe[e2];
        }
        int i0 = 0;
        float b0 = pe[0];
        for (int e2 = 1; e2 < N_E; ++e2)
            if (pe[e2] > b0) { b0 = pe[e2]; i0 = e2; }
        int i1 = -1;
        float b1 = -1.f;
        for (int e2 = 0; e2 < N_E; ++e2)
            if (e2 != i0 && pe[e2] > b1) { b1 = pe[e2]; i1 = e2; }
        float invZ = 1.0f / Z;
        tIdx[t * 2] = i0;
        tIdx[t * 2 + 1] = i1;
        tScore[t * 2] = b0 * invZ;
        tScore[t * 2 + 1] = b1 * invZ;
        atomicAdd(&counts[i0], 1);
        atomicAdd(&counts[i1], 1);
    }
}

__global__ void prefix_kernel(const int* __restrict__ counts, int* __restrict__ offs,
                              int* __restrict__ cursor) {
    if (threadIdx.x == 0) {
        int acc = 0;
        for (int e = 0; e < N_E; ++e) {
            offs[e] = acc;
            acc += counts[e];
            cursor[e] = 0;
        }
    }
}

__global__ __launch_bounds__(256) void fill_kernel(const int* __restrict__ tIdx,
                                                   const int* __restrict__ offs,
                                                   int* __restrict__ cursor,
                                                   int* __restrict__ list,
                                                   int* __restrict__ pairRow) {
    int t = blockIdx.x * 256 + threadIdx.x;
    if (t >= T_TOK) return;
    for (int kk = 0; kk < 2; ++kk) {
        int e = tIdx[t * 2 + kk];
        int pos = atomicAdd(&cursor[e], 1);
        int slot = offs[e] + pos;
        list[slot] = t;
        pairRow[t * 2 + kk] = slot;
    }
}

// ---------------- MoE combine (bf16 ysel) ----------------
__global__ __launch_bounds__(256) void combine_kernel(const u16* __restrict__ ysel,
                                                      const float* __restrict__ tScore,
                                                      const int* __restrict__ pairRow,
                                                      float* __restrict__ h) {
    int idx = blockIdx.x * 256 + threadIdx.x;
    if (idx >= T_TOK * D_MOD) return;
    int t = idx >> 10;
    int d = idx & (D_MOD - 1);
    float acc = h[idx];
#pragma unroll
    for (int kk = 0; kk < 2; ++kk) {
        int r = pairRow[t * 2 + kk];
        acc += tScore[t * 2 + kk] * b2f(ysel[(size_t)r * D_MOD + d]);
    }
    h[idx] = acc;
}

extern "C" void kernel_launch(void* const* d_in, const int* in_sizes, int n_in,
                              void* d_out, int out_size, void* d_ws, size_t ws_size,
                              hipStream_t stream) {
    const float* x = (const float*)d_in[0];
    const float* w_rms1 = (const float*)d_in[2];
    const float* w_rms2 = (const float*)d_in[3];
    const float* w_rms3 = (const float*)d_in[4];
    const float* w_rms4 = (const float*)d_in[5];
    const float* Wq = (const float*)d_in[6];
    const float* Wk = (const float*)d_in[7];
    const float* Wv = (const float*)d_in[8];
    const float* Wo = (const float*)d_in[9];
    const float* Cq = (const float*)d_in[10];
    const float* Ck = (const float*)d_in[11];
    const float* Cv = (const float*)d_in[12];
    const float* Co = (const float*)d_in[13];
    const float* Wi = (const float*)d_in[14];
    const float* bi = (const float*)d_in[15];
    const float* conv_w = (const float*)d_in[16];
    const float* conv_b = (const float*)d_in[17];
    const float* Wod = (const float*)d_in[18];
    const float* bod = (const float*)d_in[19];
    const float* w_gate = (const float*)d_in[20];
    const float* W1 = (const float*)d_in[21];
    const float* b1 = (const float*)d_in[22];
    const float* W2 = (const float*)d_in[23];
    const float* b2 = (const float*)d_in[24];
    float* out = (float*)d_out;

    char* ws = (char*)d_ws;
    size_t off = 0;
    auto alloc_f = [&](size_t n) { float* p = (float*)(ws + off); off += n * 4; return p; };
    auto alloc_b = [&](size_t n) { u16* p = (u16*)(ws + off); off += n * 2; return p; };

    u16* qkvT = alloc_b((size_t)1536 * 1024);
    u16* cqkvT = alloc_b((size_t)3072 * 1024);
    u16* WoT = alloc_b((size_t)1024 * 1024);
    u16* CoT = alloc_b((size_t)1024 * 1024);
    u16* WiT = alloc_b((size_t)2048 * 1024);
    u16* WodT = alloc_b((size_t)1024 * 1024);
    u16* W1T = alloc_b((size_t)N_E * FF_DIM * 1024);
    u16* W2T = alloc_b((size_t)N_E * 1024 * FF_DIM);
    const size_t TD = (size_t)T_TOK * D_MOD;
    float* h = alloc_f(TD);
    float* nrm = alloc_f(TD);
    u16* nrm_bf = alloc_b(TD);
    u16* h_bf = alloc_b(TD);
    u16* ab_bf = alloc_b(TD);
    u16* qkv_bf = alloc_b((size_t)T_TOK * 3072);
    u16* gv_bf = alloc_b((size_t)T_TOK * 2048);
    u16* hsel = alloc_b((size_t)2 * T_TOK * FF_DIM);
    u16* ysel = alloc_b((size_t)2 * T_TOK * D_MOD);
    int* counts = (int*)(ws + off); off += N_E * 4;
    int* offs = (int*)(ws + off); off += N_E * 4;
    int* cursor = (int*)(ws + off); off += N_E * 4;
    int* tIdx = (int*)(ws + off); off += 2 * T_TOK * 4;
    int* list = (int*)(ws + off); off += 2 * T_TOK * 4;
    int* pairRow = (int*)(ws + off); off += 2 * T_TOK * 4;
    float* tScore = alloc_f(2 * T_TOK);

    // ---- 0. weight transpose+convert ----
    transpose_cvt<<<dim3(32, 32, 1), 256, 0, stream>>>(Wq, qkvT, 1024, 1024, 1024, 0);
    transpose_cvt<<<dim3(8, 32, 1), 256, 0, stream>>>(Wk, qkvT, 1024, 256, 1024, 1024);
    transpose_cvt<<<dim3(8, 32, 1), 256, 0, stream>>>(Wv, qkvT, 1024, 256, 1024, 1280);
    transpose_cvt<<<dim3(32, 32, 1), 256, 0, stream>>>(Cq, cqkvT, 1024, 1024, 1024, 0);
    transpose_cvt<<<dim3(32, 32, 1), 256, 0, stream>>>(Ck, cqkvT, 1024, 1024, 1024, 1024);
    transpose_cvt<<<dim3(32, 32, 1), 256, 0, stream>>>(Cv, cqkvT, 1024, 1024, 1024, 2048);
    transpose_cvt<<<dim3(32, 32, 1), 256, 0, stream>>>(Wo, WoT, 1024, 1024, 1024, 0);
    transpose_cvt<<<dim3(32, 32, 1), 256, 0, stream>>>(Co, CoT, 1024, 1024, 1024, 0);
    transpose_cvt<<<dim3(64, 32, 1), 256, 0, stream>>>(Wi, WiT, 1024, 2048, 1024, 0);
    transpose_cvt<<<dim3(32, 32, 1), 256, 0, stream>>>(Wod, WodT, 1024, 1024, 1024, 0);
    transpose_cvt<<<dim3(128, 32, N_E), 256, 0, stream>>>(W1, W1T, 1024, FF_DIM, 1024, 0);
    transpose_cvt<<<dim3(32, 128, N_E), 256, 0, stream>>>(W2, W2T, FF_DIM, 1024, FF_DIM, 0);

    // ---- 1. attn1 (GQA 16h/4kv, hd=64) ----
    rmsnorm_kernel<<<T_TOK, 256, 0, stream>>>(x, w_rms1, nullptr, nrm_bf);
    mfma_gemm<0, 0, 0, 1, 64><<<dim3(12, 32, 1), 256, 0, stream>>>(
        nrm_bf, qkvT, nullptr, nullptr, nullptr, qkv_bf, nullptr, nullptr, nullptr,
        T_TOK, 1536, 1024);
    mfma_attn<64><<<dim3(16, N_H, B_SZ), 256, 0, stream>>>(
        qkv_bf, qkv_bf + 1024, qkv_bf + 1280, ab_bf, 1536, 1024, N_H, N_KV, 0.125f);
    mfma_gemm<0, 0, 1, 1, 64><<<dim3(8, 32, 1), 256, 0, stream>>>(
        ab_bf, WoT, nullptr, x, h, h_bf, nullptr, nullptr, nullptr, T_TOK, 1024, 1024);

    // ---- 2. ContextManager attention (8h/8kv, hd=128) ----
    mfma_gemm<0, 0, 0, 1, 64><<<dim3(24, 32, 1), 256, 0, stream>>>(
        h_bf, cqkvT, nullptr, nullptr, nullptr, qkv_bf, nullptr, nullptr, nullptr,
        T_TOK, 3072, 1024);
    mfma_attn<128><<<dim3(16, N_CH, B_SZ), 256, 0, stream>>>(
        qkv_bf, qkv_bf + 1024, qkv_bf + 2048, ab_bf, 3072, 1024, N_CH, N_CH,
        0.088388347648318447f);
    mfma_gemm<0, 0, 1, 0, 64><<<dim3(8, 32, 1), 256, 0, stream>>>(
        ab_bf, CoT, nullptr, h, h, nullptr, nullptr, nullptr, nullptr, T_TOK, 1024, 1024);

    // ---- 3. deltanet ----
    rmsnorm_kernel<<<T_TOK, 256, 0, stream>>>(h, w_rms2, nullptr, nrm_bf);
    mfma_gemm<0, 0, 0, 1, 64><<<dim3(16, 32, 1), 256, 0, stream>>>(
        nrm_bf, WiT, bi, nullptr, nullptr, gv_bf, nullptr, nullptr, nullptr, T_TOK, 2048, 1024);
    conv_gate_kernel<<<(T_TOK * D_MOD) / 256, 256, 0, stream>>>(gv_bf, conv_w, conv_b, ab_bf);
    mfma_gemm<0, 0, 1, 0, 64><<<dim3(8, 32, 1), 256, 0, stream>>>(
        ab_bf, WodT, bod, h, h, nullptr, nullptr, nullptr, nullptr, T_TOK, 1024, 1024);

    // ---- 4. MoE (top-2 of 8) ----
    rmsnorm_kernel<<<T_TOK, 256, 0, stream>>>(h, w_rms3, nrm, nrm_bf);
    hipMemsetAsync(counts, 0, N_E * sizeof(int), stream);
    route_kernel<<<T_TOK, 256, 0, stream>>>(nrm, w_gate, tIdx, tScore, counts);
    prefix_kernel<<<1, 64, 0, stream>>>(counts, offs, cursor);
    fill_kernel<<<(T_TOK + 255) / 256, 256, 0, stream>>>(tIdx, offs, cursor, list, pairRow);
    mfma_gemm<1, 1, 0, 1, 128><<<dim3(FF_DIM / 128, 16, N_E), 256, 0, stream>>>(
        nrm_bf, W1T, b1, nullptr, nullptr, hsel, list, offs, counts, T_TOK, FF_DIM, 1024);
    mfma_gemm<2, 0, 0, 1, 128><<<dim3(1024 / 128, 16, N_E), 256, 0, stream>>>(
        hsel, W2T, b2, nullptr, nullptr, ysel, list, offs, counts, T_TOK, 1024, FF_DIM);
    combine_kernel<<<(T_TOK * D_MOD) / 256, 256, 0, stream>>>(ysel, tScore, pairRow, h);

    // ---- 5. final rmsnorm -> out ----
    rmsnorm_kernel<<<T_TOK, 256, 0, stream>>>(h, w_rms4, out, nullptr);
}

// Round 6
// 734.203 us; speedup vs baseline: 7.4592x; 1.0617x over previous
//
#include <hip/hip_runtime.h>
#include <hip/hip_bf16.h>
#include <math.h>

#define T_TOK 2048
#define B_SZ 2
#define L_SEQ 1024
#define D_MOD 1024
#define N_H 16
#define N_KV 4
#define N_CH 8
#define N_E 8
#define FF_DIM 4096
#define DC_K 4
#define EPS_F 1e-6f

typedef unsigned short u16;
typedef unsigned int u32;
typedef short s16x8 __attribute__((ext_vector_type(8)));
typedef u16 u16x8 __attribute__((ext_vector_type(8)));
typedef float f32x4 __attribute__((ext_vector_type(4)));
struct alignas(8) U16x4 { u16 a, b, c, d; };

__device__ __forceinline__ float gelu_exact(float x) {
    return 0.5f * x * (1.0f + erff(x * 0.70710678118654752f));
}
__device__ __forceinline__ u16 f2bf(float f) {  // RNE
    u32 x = __float_as_uint(f);
    return (u16)((x + 0x7fffu + ((x >> 16) & 1u)) >> 16);
}
__device__ __forceinline__ float b2f(u16 u) {
    return __uint_as_float(((u32)u) << 16);
}
__device__ __forceinline__ void gload_lds16(const u16* g, u16* l) {
    __builtin_amdgcn_global_load_lds(
        (const __attribute__((address_space(1))) u32*)g,
        (__attribute__((address_space(3))) u32*)l, 16, 0, 0);
}

// ---------------- transpose + fp32->bf16 convert: dst[c][r] = src[r][c] ----------------
// 64x64 tiles, float4 reads, U16x4 writes. R, C multiples of 64.
__global__ __launch_bounds__(256) void transpose_cvt(const float* __restrict__ src,
                                                     u16* __restrict__ dst,
                                                     int R, int C, int dstStride, int dstRowOff) {
    __shared__ float ts[64][65];
    int e = blockIdx.z;
    src += (size_t)e * R * C;
    dst += (size_t)e * (size_t)C * dstStride;
    int c0 = blockIdx.x * 64, r0 = blockIdx.y * 64;
    int t = threadIdx.x;
#pragma unroll
    for (int k = 0; k < 4; ++k) {
        int fidx = k * 256 + t;
        int r = fidx >> 4, c4 = (fidx & 15) << 2;
        float4 v = *(const float4*)(src + (size_t)(r0 + r) * C + c0 + c4);
        ts[r][c4] = v.x; ts[r][c4 + 1] = v.y; ts[r][c4 + 2] = v.z; ts[r][c4 + 3] = v.w;
    }
    __syncthreads();
#pragma unroll
    for (int k = 0; k < 4; ++k) {
        int idx = k * 256 + t;
        int c = idx >> 4, r4 = (idx & 15) << 2;
        U16x4 o;
        o.a = f2bf(ts[r4][c]);
        o.b = f2bf(ts[r4 + 1][c]);
        o.c = f2bf(ts[r4 + 2][c]);
        o.d = f2bf(ts[r4 + 3][c]);
        *(U16x4*)(dst + (size_t)(dstRowOff + c0 + c) * dstStride + r0 + r4) = o;
    }
}

// ---------------- RMSNorm: fp32 in, optional fp32 + bf16 out ----------------
__global__ __launch_bounds__(256) void rmsnorm_kernel(const float* __restrict__ x,
                                                      const float* __restrict__ w,
                                                      float* __restrict__ fo,
                                                      u16* __restrict__ bo) {
    int row = blockIdx.x;
    int tid = threadIdx.x;
    const float* xr = x + (size_t)row * D_MOD;
    float4 v = ((const float4*)xr)[tid];
    float ss = v.x * v.x + v.y * v.y + v.z * v.z + v.w * v.w;
    __shared__ float red[256];
    red[tid] = ss;
    __syncthreads();
    for (int s = 128; s > 0; s >>= 1) {
        if (tid < s) red[tid] += red[tid + s];
        __syncthreads();
    }
    float inv = 1.0f / sqrtf(red[0] * (1.0f / D_MOD) + EPS_F);
    float4 wv = ((const float4*)w)[tid];
    float4 o;
    o.x = v.x * inv * wv.x;
    o.y = v.y * inv * wv.y;
    o.z = v.z * inv * wv.z;
    o.w = v.w * inv * wv.w;
    if (fo) ((float4*)(fo + (size_t)row * D_MOD))[tid] = o;
    if (bo) {
        U16x4 b;
        b.a = f2bf(o.x); b.b = f2bf(o.y); b.c = f2bf(o.z); b.d = f2bf(o.w);
        *(U16x4*)(bo + (size_t)row * D_MOD + tid * 4) = b;
    }
}

// ---------------- MFMA bf16 GEMM, 2-phase double-buffered, parametric tile ----------------
// C[M,N](f32/bf16) = A[M,K]bf16 @ BT[N,K]bf16. BM x BN tile, BK=32, NT threads.
// NT=256: 4 waves (2x2). NT=512: 8 waves (2x4).
// MODE 0: dense, 3-D grid. MODE 1/2 (MoE gather/compact): 1-D grid with
// expert->XCD affinity: e = id%8 (round-robin dispatch pins expert e's blocks,
// hence W[e]'s panels, to XCD e's L2), bx = (id/8)%nx, by = (id/8)/nx.
template <int MODE, int GELU, int OUTF, int OUTB, int BM, int BN, int NT>
__global__ __launch_bounds__(NT) void mfma_gemm(const u16* __restrict__ A,
                                                const u16* __restrict__ BT,
                                                const float* __restrict__ bias,
                                                const float* __restrict__ res,
                                                float* __restrict__ C,
                                                u16* __restrict__ Cb,
                                                const int* __restrict__ list,
                                                const int* __restrict__ offs,
                                                const int* __restrict__ counts,
                                                int M, int N, int K, int nx) {
    constexpr int WN = (NT == 512) ? 4 : 2;
    constexpr int PWR = BM / 2;        // per-wave rows
    constexpr int PWC = BN / WN;       // per-wave cols
    constexpr int MI = PWR / 16;
    constexpr int NI = PWC / 16;
    constexpr int NAI = (BM * 4) / NT;  // A staging issues per wave
    constexpr int NBI = (BN * 4) / NT;  // B staging issues per wave
    __shared__ u16 ldsA[2][BM * 32];
    __shared__ u16 ldsB[2][BN * 32];
    int tid = threadIdx.x;
    int lane = tid & 63, w = tid >> 6;
    int wr = w / WN, wc = w % WN;
    int bx, by, e;
    if (MODE == 0) {
        bx = blockIdx.x; by = blockIdx.y; e = 0;
    } else {
        int id = blockIdx.x;
        e = id & 7;
        int r = id >> 3;
        bx = r % nx;
        by = r / nx;
    }
    int cnt, off;
    if (MODE == 0) { cnt = M; off = 0; }
    else { cnt = counts[e]; off = offs[e]; }
    int m0 = by * BM;
    if (m0 >= cnt) return;
    int n0 = bx * BN;
    const u16* Bt = BT + (size_t)e * (size_t)N * K;

    const u16* aSrc[NAI];
    const u16* bSrc[NBI];
#pragma unroll
    for (int j = 0; j < NAI; ++j) {
        int rowA = j * (NT / 4) + w * 16 + (lane >> 2);
        int slot = lane & 3;
        int rl = m0 + rowA;
        if (rl >= cnt) rl = cnt - 1;
        size_t ga;
        if (MODE == 1) ga = (size_t)list[off + rl] * K;
        else if (MODE == 2) ga = (size_t)(off + rl) * K;
        else ga = (size_t)rl * K;
        aSrc[j] = A + ga + ((slot ^ ((rowA >> 1) & 3)) << 3);
    }
#pragma unroll
    for (int j = 0; j < NBI; ++j) {
        int rowB = j * (NT / 4) + w * 16 + (lane >> 2);
        int slot = lane & 3;
        bSrc[j] = Bt + (size_t)(n0 + rowB) * K + ((slot ^ ((rowB >> 1) & 3)) << 3);
    }

    auto stage = [&](int buf, int k0) {
#pragma unroll
        for (int j = 0; j < NAI; ++j)
            gload_lds16(aSrc[j] + k0, &ldsA[buf][(j * NT + w * 64) * 8]);
#pragma unroll
        for (int j = 0; j < NBI; ++j)
            gload_lds16(bSrc[j] + k0, &ldsB[buf][(j * NT + w * 64) * 8]);
    };

    f32x4 acc[MI][NI] = {};
    int r16 = lane & 15, cr = lane >> 4;

    stage(0, 0);
    __syncthreads();
    int cur = 0;
    for (int k0 = 0; k0 < K; k0 += 32) {
        if (k0 + 32 < K) stage(cur ^ 1, k0 + 32);
        s16x8 af[MI], bfr[NI];
#pragma unroll
        for (int mi = 0; mi < MI; ++mi) {
            int row = wr * PWR + mi * 16 + r16;
            af[mi] = *(const s16x8*)&ldsA[cur][row * 32 + ((cr ^ ((row >> 1) & 3)) << 3)];
        }
#pragma unroll
        for (int ni = 0; ni < NI; ++ni) {
            int row = wc * PWC + ni * 16 + r16;
            bfr[ni] = *(const s16x8*)&ldsB[cur][row * 32 + ((cr ^ ((row >> 1) & 3)) << 3)];
        }
#pragma unroll
        for (int mi = 0; mi < MI; ++mi)
#pragma unroll
            for (int ni = 0; ni < NI; ++ni)
                acc[mi][ni] = __builtin_amdgcn_mfma_f32_16x16x32_bf16(af[mi], bfr[ni],
                                                                      acc[mi][ni], 0, 0, 0);
        __syncthreads();
        cur ^= 1;
    }

    const float* bias_e = bias ? (bias + (MODE ? (size_t)e * N : 0)) : nullptr;
#pragma unroll
    for (int mi = 0; mi < MI; ++mi) {
#pragma unroll
        for (int ni = 0; ni < NI; ++ni) {
            int rloc = wr * PWR + mi * 16 + (lane >> 4) * 4;
            int col = n0 + wc * PWC + ni * 16 + (lane & 15);
#pragma unroll
            for (int jj = 0; jj < 4; ++jj) {
                int rl = m0 + rloc + jj;
                if (rl >= cnt) continue;
                float val = acc[mi][ni][jj];
                if (bias_e) val += bias_e[col];
                if (GELU) val = gelu_exact(val);
                size_t crow = (MODE == 0) ? (size_t)rl : (size_t)(off + rl);
                if (res) val += res[crow * N + col];
                if (OUTF) C[crow * N + col] = val;
                if (OUTB) Cb[crow * N + col] = f2bf(val);
            }
        }
    }
}

// ---------------- MFMA flash attention (unchanged) ----------------
template <int HD>
__global__ __launch_bounds__(256) void mfma_attn(const u16* __restrict__ Qb,
                                                 const u16* __restrict__ Kb,
                                                 const u16* __restrict__ Vb,
                                                 u16* __restrict__ O,
                                                 int stride, int ostride,
                                                 int nh, int nkv, float scale) {
    constexpr int KT = 64;
    constexpr int CH = HD / 8;
    constexpr int NF = HD / 32;
    constexpr int ND = HD / 16;
    constexpr int VSTR = 72;
    constexpr int NISS = (64 * CH) / (64 * 4);

    __shared__ u16 Kl[64 * HD];
    __shared__ u16 Vt[HD * VSTR];
    __shared__ u16 Pl[4][16 * 72];

    int tid = threadIdx.x, lane = tid & 63, w = tid >> 6;
    int g = lane >> 4, r16 = lane & 15;
    int q0 = blockIdx.x * 64, h = blockIdx.y, b = blockIdx.z;
    int kvh = h / (nh / nkv);

    const u16* Qp = Qb + (size_t)(b * L_SEQ + q0 + w * 16 + r16) * stride + h * HD + g * 8;
    s16x8 qf[NF];
#pragma unroll
    for (int f = 0; f < NF; ++f) qf[f] = *(const s16x8*)(Qp + f * 32);

    const u16* Kbase = Kb + (size_t)(b * L_SEQ) * stride + (size_t)kvh * HD;
    const u16* Vbase = Vb + (size_t)(b * L_SEQ) * stride + (size_t)kvh * HD;

    int srcOffK[NISS];
#pragma unroll
    for (int i = 0; i < NISS; ++i) {
        int ci = (w * NISS + i) * 64 + lane;
        int row = ci / CH;
        int ch = ci % CH;
        srcOffK[i] = row * stride + ((ch ^ (row & 7)) << 3);
    }

    f32x4 ofr[ND] = {};
    float m_r[4], l_r[4];
#pragma unroll
    for (int r = 0; r < 4; ++r) { m_r[r] = -1e30f; l_r[r] = 0.f; }

    for (int kt = 0; kt < L_SEQ / KT; ++kt) {
        const u16* Ksrc = Kbase + (size_t)(kt * KT) * stride;
        const u16* Vsrc = Vbase + (size_t)(kt * KT) * stride;
        __syncthreads();
#pragma unroll
        for (int i = 0; i < NISS; ++i)
            gload_lds16(Ksrc + srcOffK[i], Kl + (size_t)(w * NISS + i) * 512);
#pragma unroll
        for (int half = 0; half < HD / 64; ++half) {
            int dbase = w * 16 + half * 64;
            u16x8 v0 = *(const u16x8*)(Vsrc + (size_t)lane * stride + dbase);
            u16x8 v1 = *(const u16x8*)(Vsrc + (size_t)lane * stride + dbase + 8);
#pragma unroll
            for (int j = 0; j < 8; ++j) {
                Vt[(dbase + j) * VSTR + lane] = v0[j];
                Vt[(dbase + 8 + j) * VSTR + lane] = v1[j];
            }
        }
        __syncthreads();

        f32x4 s[4];
#pragma unroll
        for (int sub = 0; sub < 4; ++sub) {
            f32x4 acc = {};
#pragma unroll
            for (int f = 0; f < NF; ++f) {
                int row = sub * 16 + r16;
                int chunk = (f * 4 + g) ^ (row & 7);
                s16x8 kf = *(const s16x8*)&Kl[(row * CH + chunk) * 8];
                acc = __builtin_amdgcn_mfma_f32_16x16x32_bf16(qf[f], kf, acc, 0, 0, 0);
            }
            s[sub] = acc;
        }

#pragma unroll
        for (int sub = 0; sub < 4; ++sub)
#pragma unroll
            for (int r = 0; r < 4; ++r) s[sub][r] *= scale;
#pragma unroll
        for (int r = 0; r < 4; ++r) {
            float mx = fmaxf(fmaxf(s[0][r], s[1][r]), fmaxf(s[2][r], s[3][r]));
            mx = fmaxf(mx, __shfl_xor(mx, 1));
            mx = fmaxf(mx, __shfl_xor(mx, 2));
            mx = fmaxf(mx, __shfl_xor(mx, 4));
            mx = fmaxf(mx, __shfl_xor(mx, 8));
            float mo = m_r[r];
            float mn = fmaxf(mo, mx);
            float sc = __expf(mo - mn);
            m_r[r] = mn;
            float sum = 0.f;
#pragma unroll
            for (int sub = 0; sub < 4; ++sub) {
                float e = __expf(s[sub][r] - mn);
                s[sub][r] = e;
                sum += e;
            }
            sum += __shfl_xor(sum, 1);
            sum += __shfl_xor(sum, 2);
            sum += __shfl_xor(sum, 4);
            sum += __shfl_xor(sum, 8);
            l_r[r] = l_r[r] * sc + sum;
#pragma unroll
            for (int dsub = 0; dsub < ND; ++dsub) ofr[dsub][r] *= sc;
        }

        u16* Pw = Pl[w];
#pragma unroll
        for (int sub = 0; sub < 4; ++sub)
#pragma unroll
            for (int r = 0; r < 4; ++r) {
                int q = g * 4 + r;
                int k = sub * 16 + r16;
                Pw[q * 72 + (((k >> 3) ^ (q & 7)) << 3) + (k & 7)] = f2bf(s[sub][r]);
            }
        __syncthreads();

        s16x8 pf[2];
#pragma unroll
        for (int ks = 0; ks < 2; ++ks) {
            int chunk = (ks * 4 + g) ^ (r16 & 7);
            pf[ks] = *(const s16x8*)&Pw[r16 * 72 + chunk * 8];
        }
#pragma unroll
        for (int dsub = 0; dsub < ND; ++dsub)
#pragma unroll
            for (int ks = 0; ks < 2; ++ks) {
                s16x8 vf = *(const s16x8*)&Vt[(dsub * 16 + r16) * VSTR + ks * 32 + g * 8];
                ofr[dsub] = __builtin_amdgcn_mfma_f32_16x16x32_bf16(pf[ks], vf, ofr[dsub], 0, 0, 0);
            }
    }

    float inv[4];
#pragma unroll
    for (int r = 0; r < 4; ++r) inv[r] = 1.0f / l_r[r];
#pragma unroll
    for (int dsub = 0; dsub < ND; ++dsub)
#pragma unroll
        for (int r = 0; r < 4; ++r) {
            int q = q0 + w * 16 + g * 4 + r;
            O[(size_t)(b * L_SEQ + q) * ostride + h * HD + dsub * 16 + r16] =
                f2bf(ofr[dsub][r] * inv[r]);
        }
}

// ---------------- DeltaNet conv + gate (bf16 in/out, fp32 math) ----------------
__global__ __launch_bounds__(256) void conv_gate_kernel(const u16* __restrict__ gv,
                                                        const float* __restrict__ cw,
                                                        const float* __restrict__ cb,
                                                        u16* __restrict__ gated) {
    int idx = blockIdx.x * 256 + threadIdx.x;
    if (idx >= T_TOK * D_MOD) return;
    int d = idx & (D_MOD - 1);
    int t = idx >> 10;
    int l = t & (L_SEQ - 1);
    float conv = cb[d];
#pragma unroll
    for (int i = 0; i < DC_K; ++i) {
        int lp = l - (DC_K - 1) + i;
        if (lp >= 0)
            conv += b2f(gv[(size_t)(t - l + lp) * (2 * D_MOD) + D_MOD + d]) * cw[d * DC_K + i];
    }
    float gate = b2f(gv[(size_t)t * (2 * D_MOD) + d]);
    float sig = 1.0f / (1.0f + expf(-gate));
    gated[(size_t)t * D_MOD + d] = f2bf(conv * (gate * sig));
}

// ---------------- MoE routing (fp32 input) ----------------
__global__ __launch_bounds__(256) void route_kernel(const float* __restrict__ g,
                                                    const float* __restrict__ wg,
                                                    int* __restrict__ tIdx,
                                                    float* __restrict__ tScore,
                                                    int* __restrict__ counts) {
    int t = blockIdx.x, tid = threadIdx.x;
    __shared__ float gs[D_MOD];
    __shared__ float logits[N_E];
    ((float4*)gs)[tid] = ((const float4*)(g + (size_t)t * D_MOD))[tid];
    __syncthreads();
    int e = tid >> 5, lane = tid & 31;
    const float* w = wg + (size_t)e * D_MOD;
    float p = 0.f;
    for (int d = lane; d < D_MOD; d += 32) p += gs[d] * w[d];
    for (int o = 16; o > 0; o >>= 1) p += __shfl_down(p, o, 32);
    if (lane == 0) logits[e] = p;
    __syncthreads();
    if (tid == 0) {
        float mx = logits[0];
        for (int e2 = 1; e2 < N_E; ++e2) mx = fmaxf(mx, logits[e2]);
        float pe[N_E];
        float Z = 0.f;
        for (int e2 = 0; e2 < N_E; ++e2) {
            pe[e2] = expf(logits[e2] - mx);
            Z += pe[e2];
        }
        int i0 = 0;
        float b0 = pe[0];
        for (int e2 = 1; e2 < N_E; ++e2)
            if (pe[e2] > b0) { b0 = pe[e2]; i0 = e2; }
        int i1 = -1;
        float b1 = -1.f;
        for (int e2 = 0; e2 < N_E; ++e2)
            if (e2 != i0 && pe[e2] > b1) { b1 = pe[e2]; i1 = e2; }
        float invZ = 1.0f / Z;
        tIdx[t * 2] = i0;
        tIdx[t * 2 + 1] = i1;
        tScore[t * 2] = b0 * invZ;
        tScore[t * 2 + 1] = b1 * invZ;
        atomicAdd(&counts[i0], 1);
        atomicAdd(&counts[i1], 1);
    }
}

__global__ void prefix_kernel(const int* __restrict__ counts, int* __restrict__ offs,
                              int* __restrict__ cursor) {
    if (threadIdx.x == 0) {
        int acc = 0;
        for (int e = 0; e < N_E; ++e) {
            offs[e] = acc;
            acc += counts[e];
            cursor[e] = 0;
        }
    }
}

__global__ __launch_bounds__(256) void fill_kernel(const int* __restrict__ tIdx,
                                                   const int* __restrict__ offs,
                                                   int* __restrict__ cursor,
                                                   int* __restrict__ list,
                                                   int* __restrict__ pairRow) {
    int t = blockIdx.x * 256 + threadIdx.x;
    if (t >= T_TOK) return;
    for (int kk = 0; kk < 2; ++kk) {
        int e = tIdx[t * 2 + kk];
        int pos = atomicAdd(&cursor[e], 1);
        int slot = offs[e] + pos;
        list[slot] = t;
        pairRow[t * 2 + kk] = slot;
    }
}

// ---------------- MoE combine (bf16 ysel) ----------------
__global__ __launch_bounds__(256) void combine_kernel(const u16* __restrict__ ysel,
                                                      const float* __restrict__ tScore,
                                                      const int* __restrict__ pairRow,
                                                      float* __restrict__ h) {
    int idx = blockIdx.x * 256 + threadIdx.x;
    if (idx >= T_TOK * D_MOD) return;
    int t = idx >> 10;
    int d = idx & (D_MOD - 1);
    float acc = h[idx];
#pragma unroll
    for (int kk = 0; kk < 2; ++kk) {
        int r = pairRow[t * 2 + kk];
        acc += tScore[t * 2 + kk] * b2f(ysel[(size_t)r * D_MOD + d]);
    }
    h[idx] = acc;
}

extern "C" void kernel_launch(void* const* d_in, const int* in_sizes, int n_in,
                              void* d_out, int out_size, void* d_ws, size_t ws_size,
                              hipStream_t stream) {
    const float* x = (const float*)d_in[0];
    const float* w_rms1 = (const float*)d_in[2];
    const float* w_rms2 = (const float*)d_in[3];
    const float* w_rms3 = (const float*)d_in[4];
    const float* w_rms4 = (const float*)d_in[5];
    const float* Wq = (const float*)d_in[6];
    const float* Wk = (const float*)d_in[7];
    const float* Wv = (const float*)d_in[8];
    const float* Wo = (const float*)d_in[9];
    const float* Cq = (const float*)d_in[10];
    const float* Ck = (const float*)d_in[11];
    const float* Cv = (const float*)d_in[12];
    const float* Co = (const float*)d_in[13];
    const float* Wi = (const float*)d_in[14];
    const float* bi = (const float*)d_in[15];
    const float* conv_w = (const float*)d_in[16];
    const float* conv_b = (const float*)d_in[17];
    const float* Wod = (const float*)d_in[18];
    const float* bod = (const float*)d_in[19];
    const float* w_gate = (const float*)d_in[20];
    const float* W1 = (const float*)d_in[21];
    const float* b1 = (const float*)d_in[22];
    const float* W2 = (const float*)d_in[23];
    const float* b2 = (const float*)d_in[24];
    float* out = (float*)d_out;

    char* ws = (char*)d_ws;
    size_t off = 0;
    auto alloc_f = [&](size_t n) { float* p = (float*)(ws + off); off += n * 4; return p; };
    auto alloc_b = [&](size_t n) { u16* p = (u16*)(ws + off); off += n * 2; return p; };

    u16* qkvT = alloc_b((size_t)1536 * 1024);
    u16* cqkvT = alloc_b((size_t)3072 * 1024);
    u16* WoT = alloc_b((size_t)1024 * 1024);
    u16* CoT = alloc_b((size_t)1024 * 1024);
    u16* WiT = alloc_b((size_t)2048 * 1024);
    u16* WodT = alloc_b((size_t)1024 * 1024);
    u16* W1T = alloc_b((size_t)N_E * FF_DIM * 1024);
    u16* W2T = alloc_b((size_t)N_E * 1024 * FF_DIM);
    const size_t TD = (size_t)T_TOK * D_MOD;
    float* h = alloc_f(TD);
    float* nrm = alloc_f(TD);
    u16* nrm_bf = alloc_b(TD);
    u16* h_bf = alloc_b(TD);
    u16* ab_bf = alloc_b(TD);
    u16* qkv_bf = alloc_b((size_t)T_TOK * 3072);
    u16* gv_bf = alloc_b((size_t)T_TOK * 2048);
    u16* hsel = alloc_b((size_t)2 * T_TOK * FF_DIM);
    u16* ysel = alloc_b((size_t)2 * T_TOK * D_MOD);
    int* counts = (int*)(ws + off); off += N_E * 4;
    int* offs = (int*)(ws + off); off += N_E * 4;
    int* cursor = (int*)(ws + off); off += N_E * 4;
    int* tIdx = (int*)(ws + off); off += 2 * T_TOK * 4;
    int* list = (int*)(ws + off); off += 2 * T_TOK * 4;
    int* pairRow = (int*)(ws + off); off += 2 * T_TOK * 4;
    float* tScore = alloc_f(2 * T_TOK);

    // ---- 0. weight transpose+convert (64x64 tiles) ----
    transpose_cvt<<<dim3(16, 16, 1), 256, 0, stream>>>(Wq, qkvT, 1024, 1024, 1024, 0);
    transpose_cvt<<<dim3(4, 16, 1), 256, 0, stream>>>(Wk, qkvT, 1024, 256, 1024, 1024);
    transpose_cvt<<<dim3(4, 16, 1), 256, 0, stream>>>(Wv, qkvT, 1024, 256, 1024, 1280);
    transpose_cvt<<<dim3(16, 16, 1), 256, 0, stream>>>(Cq, cqkvT, 1024, 1024, 1024, 0);
    transpose_cvt<<<dim3(16, 16, 1), 256, 0, stream>>>(Ck, cqkvT, 1024, 1024, 1024, 1024);
    transpose_cvt<<<dim3(16, 16, 1), 256, 0, stream>>>(Cv, cqkvT, 1024, 1024, 1024, 2048);
    transpose_cvt<<<dim3(16, 16, 1), 256, 0, stream>>>(Wo, WoT, 1024, 1024, 1024, 0);
    transpose_cvt<<<dim3(16, 16, 1), 256, 0, stream>>>(Co, CoT, 1024, 1024, 1024, 0);
    transpose_cvt<<<dim3(32, 16, 1), 256, 0, stream>>>(Wi, WiT, 1024, 2048, 1024, 0);
    transpose_cvt<<<dim3(16, 16, 1), 256, 0, stream>>>(Wod, WodT, 1024, 1024, 1024, 0);
    transpose_cvt<<<dim3(64, 16, N_E), 256, 0, stream>>>(W1, W1T, 1024, FF_DIM, 1024, 0);
    transpose_cvt<<<dim3(16, 64, N_E), 256, 0, stream>>>(W2, W2T, FF_DIM, 1024, FF_DIM, 0);

    // ---- 1. attn1 (GQA 16h/4kv, hd=64) ----
    rmsnorm_kernel<<<T_TOK, 256, 0, stream>>>(x, w_rms1, nullptr, nrm_bf);
    mfma_gemm<0, 0, 0, 1, 64, 128, 256><<<dim3(12, 32, 1), 256, 0, stream>>>(
        nrm_bf, qkvT, nullptr, nullptr, nullptr, qkv_bf, nullptr, nullptr, nullptr,
        T_TOK, 1536, 1024, 0);
    mfma_attn<64><<<dim3(16, N_H, B_SZ), 256, 0, stream>>>(
        qkv_bf, qkv_bf + 1024, qkv_bf + 1280, ab_bf, 1536, 1024, N_H, N_KV, 0.125f);
    mfma_gemm<0, 0, 1, 1, 64, 128, 256><<<dim3(8, 32, 1), 256, 0, stream>>>(
        ab_bf, WoT, nullptr, x, h, h_bf, nullptr, nullptr, nullptr, T_TOK, 1024, 1024, 0);

    // ---- 2. ContextManager attention (8h/8kv, hd=128) ----
    mfma_gemm<0, 0, 0, 1, 64, 128, 256><<<dim3(24, 32, 1), 256, 0, stream>>>(
        h_bf, cqkvT, nullptr, nullptr, nullptr, qkv_bf, nullptr, nullptr, nullptr,
        T_TOK, 3072, 1024, 0);
    mfma_attn<128><<<dim3(16, N_CH, B_SZ), 256, 0, stream>>>(
        qkv_bf, qkv_bf + 1024, qkv_bf + 2048, ab_bf, 3072, 1024, N_CH, N_CH,
        0.088388347648318447f);
    mfma_gemm<0, 0, 1, 0, 64, 128, 256><<<dim3(8, 32, 1), 256, 0, stream>>>(
        ab_bf, CoT, nullptr, h, h, nullptr, nullptr, nullptr, nullptr, T_TOK, 1024, 1024, 0);

    // ---- 3. deltanet ----
    rmsnorm_kernel<<<T_TOK, 256, 0, stream>>>(h, w_rms2, nullptr, nrm_bf);
    mfma_gemm<0, 0, 0, 1, 64, 128, 256><<<dim3(16, 32, 1), 256, 0, stream>>>(
        nrm_bf, WiT, bi, nullptr, nullptr, gv_bf, nullptr, nullptr, nullptr, T_TOK, 2048, 1024, 0);
    conv_gate_kernel<<<(T_TOK * D_MOD) / 256, 256, 0, stream>>>(gv_bf, conv_w, conv_b, ab_bf);
    mfma_gemm<0, 0, 1, 0, 64, 128, 256><<<dim3(8, 32, 1), 256, 0, stream>>>(
        ab_bf, WodT, bod, h, h, nullptr, nullptr, nullptr, nullptr, T_TOK, 1024, 1024, 0);

    // ---- 4. MoE (top-2 of 8), expert->XCD affinity grids ----
    rmsnorm_kernel<<<T_TOK, 256, 0, stream>>>(h, w_rms3, nrm, nrm_bf);
    hipMemsetAsync(counts, 0, N_E * sizeof(int), stream);
    route_kernel<<<T_TOK, 256, 0, stream>>>(nrm, w_gate, tIdx, tScore, counts);
    prefix_kernel<<<1, 64, 0, stream>>>(counts, offs, cursor);
    fill_kernel<<<(T_TOK + 255) / 256, 256, 0, stream>>>(tIdx, offs, cursor, list, pairRow);
    // MoE1: 256x256 tile, 8 waves; grid = nx(16) * ny(16) * 8 experts, 1-D
    mfma_gemm<1, 1, 0, 1, 256, 256, 512><<<16 * 16 * 8, 512, 0, stream>>>(
        nrm_bf, W1T, b1, nullptr, nullptr, hsel, list, offs, counts, T_TOK, FF_DIM, 1024, 16);
    // MoE2: 128x128 tile, 4 waves; grid = nx(8) * ny(32) * 8 experts, 1-D
    mfma_gemm<2, 0, 0, 1, 128, 128, 256><<<8 * 32 * 8, 256, 0, stream>>>(
        hsel, W2T, b2, nullptr, nullptr, ysel, list, offs, counts, T_TOK, 1024, FF_DIM, 8);
    combine_kernel<<<(T_TOK * D_MOD) / 256, 256, 0, stream>>>(ysel, tScore, pairRow, h);

    // ---- 5. final rmsnorm -> out ----
    rmsnorm_kernel<<<T_TOK, 256, 0, stream>>>(h, w_rms4, out, nullptr);
}

// Round 7
// 719.535 us; speedup vs baseline: 7.6112x; 1.0204x over previous
//
#include <hip/hip_runtime.h>
#include <hip/hip_bf16.h>
#include <math.h>

#define T_TOK 2048
#define B_SZ 2
#define L_SEQ 1024
#define D_MOD 1024
#define N_H 16
#define N_KV 4
#define N_CH 8
#define N_E 8
#define FF_DIM 4096
#define DC_K 4
#define EPS_F 1e-6f

typedef unsigned short u16;
typedef unsigned int u32;
typedef short s16x8 __attribute__((ext_vector_type(8)));
typedef u16 u16x8 __attribute__((ext_vector_type(8)));
typedef float f32x4 __attribute__((ext_vector_type(4)));
struct alignas(8) U16x4 { u16 a, b, c, d; };

__device__ __forceinline__ float gelu_exact(float x) {
    return 0.5f * x * (1.0f + erff(x * 0.70710678118654752f));
}
__device__ __forceinline__ u16 f2bf(float f) {  // RNE
    u32 x = __float_as_uint(f);
    return (u16)((x + 0x7fffu + ((x >> 16) & 1u)) >> 16);
}
__device__ __forceinline__ float b2f(u16 u) {
    return __uint_as_float(((u32)u) << 16);
}
__device__ __forceinline__ void gload_lds16(const u16* g, u16* l) {
    __builtin_amdgcn_global_load_lds(
        (const __attribute__((address_space(1))) u32*)g,
        (__attribute__((address_space(3))) u32*)l, 16, 0, 0);
}

// counted vmcnt + raw barrier, single asm block so nothing can interleave
#define WVB(N) asm volatile("s_waitcnt vmcnt(" #N ")\n\ts_barrier" ::: "memory")
template <int N>
__device__ __forceinline__ void waitv_bar() {
    if constexpr (N == 0) WVB(0);
    else if constexpr (N == 3) WVB(3);
    else if constexpr (N == 4) WVB(4);
    else if constexpr (N == 6) WVB(6);
    else if constexpr (N == 8) WVB(8);
    else if constexpr (N == 9) WVB(9);
    else if constexpr (N == 12) WVB(12);
}

// ---------------- transpose + fp32->bf16 convert: dst[c][r] = src[r][c] ----------------
__global__ __launch_bounds__(256) void transpose_cvt(const float* __restrict__ src,
                                                     u16* __restrict__ dst,
                                                     int R, int C, int dstStride, int dstRowOff) {
    __shared__ float ts[64][65];
    int e = blockIdx.z;
    src += (size_t)e * R * C;
    dst += (size_t)e * (size_t)C * dstStride;
    int c0 = blockIdx.x * 64, r0 = blockIdx.y * 64;
    int t = threadIdx.x;
#pragma unroll
    for (int k = 0; k < 4; ++k) {
        int fidx = k * 256 + t;
        int r = fidx >> 4, c4 = (fidx & 15) << 2;
        float4 v = *(const float4*)(src + (size_t)(r0 + r) * C + c0 + c4);
        ts[r][c4] = v.x; ts[r][c4 + 1] = v.y; ts[r][c4 + 2] = v.z; ts[r][c4 + 3] = v.w;
    }
    __syncthreads();
#pragma unroll
    for (int k = 0; k < 4; ++k) {
        int idx = k * 256 + t;
        int c = idx >> 4, r4 = (idx & 15) << 2;
        U16x4 o;
        o.a = f2bf(ts[r4][c]);
        o.b = f2bf(ts[r4 + 1][c]);
        o.c = f2bf(ts[r4 + 2][c]);
        o.d = f2bf(ts[r4 + 3][c]);
        *(U16x4*)(dst + (size_t)(dstRowOff + c0 + c) * dstStride + r0 + r4) = o;
    }
}

// ---------------- RMSNorm: fp32 in, optional fp32 + bf16 out ----------------
__global__ __launch_bounds__(256) void rmsnorm_kernel(const float* __restrict__ x,
                                                      const float* __restrict__ w,
                                                      float* __restrict__ fo,
                                                      u16* __restrict__ bo) {
    int row = blockIdx.x;
    int tid = threadIdx.x;
    const float* xr = x + (size_t)row * D_MOD;
    float4 v = ((const float4*)xr)[tid];
    float ss = v.x * v.x + v.y * v.y + v.z * v.z + v.w * v.w;
    __shared__ float red[256];
    red[tid] = ss;
    __syncthreads();
    for (int s = 128; s > 0; s >>= 1) {
        if (tid < s) red[tid] += red[tid + s];
        __syncthreads();
    }
    float inv = 1.0f / sqrtf(red[0] * (1.0f / D_MOD) + EPS_F);
    float4 wv = ((const float4*)w)[tid];
    float4 o;
    o.x = v.x * inv * wv.x;
    o.y = v.y * inv * wv.y;
    o.z = v.z * inv * wv.z;
    o.w = v.w * inv * wv.w;
    if (fo) ((float4*)(fo + (size_t)row * D_MOD))[tid] = o;
    if (bo) {
        U16x4 b;
        b.a = f2bf(o.x); b.b = f2bf(o.y); b.c = f2bf(o.z); b.d = f2bf(o.w);
        *(U16x4*)(bo + (size_t)row * D_MOD + tid * 4) = b;
    }
}

// ---------------- MFMA bf16 GEMM, 4-deep counted-vmcnt pipeline ----------------
// C[M,N](f32/bf16) = A[M,K]bf16 @ BT[N,K]bf16. BM x BN tile, BK=32.
// NT=256: 4 waves (2x2). NT=512: 8 waves (2x4).
// MODE 0: dense, 3-D grid. MODE 1/2 (MoE gather/compact): 1-D grid with
// expert->XCD affinity (e = id%8). Pipeline: 4 LDS buffers; stage s+4 issued
// only after the post-compute barrier; buffer readiness via counted
// s_waitcnt vmcnt(3*ISS) (in-order retirement => oldest stage complete).
template <int MODE, int GELU, int OUTF, int OUTB, int BM, int BN, int NT>
__global__ __launch_bounds__(NT) void mfma_gemm(const u16* __restrict__ A,
                                                const u16* __restrict__ BT,
                                                const float* __restrict__ bias,
                                                const float* __restrict__ res,
                                                float* __restrict__ C,
                                                u16* __restrict__ Cb,
                                                const int* __restrict__ list,
                                                const int* __restrict__ offs,
                                                const int* __restrict__ counts,
                                                int M, int N, int K, int nx) {
    constexpr int WN = (NT == 512) ? 4 : 2;
    constexpr int PWR = BM / 2;
    constexpr int PWC = BN / WN;
    constexpr int MI = PWR / 16;
    constexpr int NI = PWC / 16;
    constexpr int NAI = (BM * 4) / NT;
    constexpr int NBI = (BN * 4) / NT;
    constexpr int ISS = NAI + NBI;
    __shared__ u16 ldsA[4][BM * 32];
    __shared__ u16 ldsB[4][BN * 32];
    int tid = threadIdx.x;
    int lane = tid & 63, w = tid >> 6;
    int wr = w / WN, wc = w % WN;
    int bx, by, e;
    if (MODE == 0) {
        bx = blockIdx.x; by = blockIdx.y; e = 0;
    } else {
        int id = blockIdx.x;
        e = id & 7;
        int r = id >> 3;
        bx = r % nx;
        by = r / nx;
    }
    int cnt, off;
    if (MODE == 0) { cnt = M; off = 0; }
    else { cnt = counts[e]; off = offs[e]; }
    int m0 = by * BM;
    if (m0 >= cnt) return;
    int n0 = bx * BN;
    const u16* Bt = BT + (size_t)e * (size_t)N * K;

    const u16* aSrc[NAI];
    const u16* bSrc[NBI];
#pragma unroll
    for (int j = 0; j < NAI; ++j) {
        int rowA = j * (NT / 4) + w * 16 + (lane >> 2);
        int slot = lane & 3;
        int rl = m0 + rowA;
        if (rl >= cnt) rl = cnt - 1;
        size_t ga;
        if (MODE == 1) ga = (size_t)list[off + rl] * K;
        else if (MODE == 2) ga = (size_t)(off + rl) * K;
        else ga = (size_t)rl * K;
        aSrc[j] = A + ga + ((slot ^ ((rowA >> 1) & 3)) << 3);
    }
#pragma unroll
    for (int j = 0; j < NBI; ++j) {
        int rowB = j * (NT / 4) + w * 16 + (lane >> 2);
        int slot = lane & 3;
        bSrc[j] = Bt + (size_t)(n0 + rowB) * K + ((slot ^ ((rowB >> 1) & 3)) << 3);
    }

    auto stage = [&](int buf, int k0) {
#pragma unroll
        for (int j = 0; j < NAI; ++j)
            gload_lds16(aSrc[j] + k0, &ldsA[buf][(j * NT + w * 64) * 8]);
#pragma unroll
        for (int j = 0; j < NBI; ++j)
            gload_lds16(bSrc[j] + k0, &ldsB[buf][(j * NT + w * 64) * 8]);
    };

    f32x4 acc[MI][NI] = {};
    int r16 = lane & 15, cr = lane >> 4;

    stage(0, 0); stage(1, 32); stage(2, 64); stage(3, 96);
    const int nsteps = K >> 5;
    for (int s = 0; s < nsteps; ++s) {
        int ahead = nsteps - 1 - s;
        if (ahead >= 3) waitv_bar<3 * ISS>();
        else if (ahead == 2) waitv_bar<2 * ISS>();
        else if (ahead == 1) waitv_bar<ISS>();
        else waitv_bar<0>();
        int buf = s & 3;
        s16x8 af[MI], bfr[NI];
#pragma unroll
        for (int mi = 0; mi < MI; ++mi) {
            int row = wr * PWR + mi * 16 + r16;
            af[mi] = *(const s16x8*)&ldsA[buf][row * 32 + ((cr ^ ((row >> 1) & 3)) << 3)];
        }
#pragma unroll
        for (int ni = 0; ni < NI; ++ni) {
            int row = wc * PWC + ni * 16 + r16;
            bfr[ni] = *(const s16x8*)&ldsB[buf][row * 32 + ((cr ^ ((row >> 1) & 3)) << 3)];
        }
#pragma unroll
        for (int mi = 0; mi < MI; ++mi)
#pragma unroll
            for (int ni = 0; ni < NI; ++ni)
                acc[mi][ni] = __builtin_amdgcn_mfma_f32_16x16x32_bf16(af[mi], bfr[ni],
                                                                      acc[mi][ni], 0, 0, 0);
        asm volatile("s_waitcnt lgkmcnt(0)\n\ts_barrier" ::: "memory");
        if (s + 4 < nsteps) stage(buf, (s + 4) << 5);
    }

    const float* bias_e = bias ? (bias + (MODE ? (size_t)e * N : 0)) : nullptr;
#pragma unroll
    for (int mi = 0; mi < MI; ++mi) {
#pragma unroll
        for (int ni = 0; ni < NI; ++ni) {
            int rloc = wr * PWR + mi * 16 + (lane >> 4) * 4;
            int col = n0 + wc * PWC + ni * 16 + (lane & 15);
#pragma unroll
            for (int jj = 0; jj < 4; ++jj) {
                int rl = m0 + rloc + jj;
                if (rl >= cnt) continue;
                float val = acc[mi][ni][jj];
                if (bias_e) val += bias_e[col];
                if (GELU) val = gelu_exact(val);
                size_t crow = (MODE == 0) ? (size_t)rl : (size_t)(off + rl);
                if (res) val += res[crow * N + col];
                if (OUTF) C[crow * N + col] = val;
                if (OUTB) Cb[crow * N + col] = f2bf(val);
            }
        }
    }
}

// ---------------- MFMA flash attention (unchanged) ----------------
template <int HD>
__global__ __launch_bounds__(256) void mfma_attn(const u16* __restrict__ Qb,
                                                 const u16* __restrict__ Kb,
                                                 const u16* __restrict__ Vb,
                                                 u16* __restrict__ O,
                                                 int stride, int ostride,
                                                 int nh, int nkv, float scale) {
    constexpr int KT = 64;
    constexpr int CH = HD / 8;
    constexpr int NF = HD / 32;
    constexpr int ND = HD / 16;
    constexpr int VSTR = 72;
    constexpr int NISS = (64 * CH) / (64 * 4);

    __shared__ u16 Kl[64 * HD];
    __shared__ u16 Vt[HD * VSTR];
    __shared__ u16 Pl[4][16 * 72];

    int tid = threadIdx.x, lane = tid & 63, w = tid >> 6;
    int g = lane >> 4, r16 = lane & 15;
    int q0 = blockIdx.x * 64, h = blockIdx.y, b = blockIdx.z;
    int kvh = h / (nh / nkv);

    const u16* Qp = Qb + (size_t)(b * L_SEQ + q0 + w * 16 + r16) * stride + h * HD + g * 8;
    s16x8 qf[NF];
#pragma unroll
    for (int f = 0; f < NF; ++f) qf[f] = *(const s16x8*)(Qp + f * 32);

    const u16* Kbase = Kb + (size_t)(b * L_SEQ) * stride + (size_t)kvh * HD;
    const u16* Vbase = Vb + (size_t)(b * L_SEQ) * stride + (size_t)kvh * HD;

    int srcOffK[NISS];
#pragma unroll
    for (int i = 0; i < NISS; ++i) {
        int ci = (w * NISS + i) * 64 + lane;
        int row = ci / CH;
        int ch = ci % CH;
        srcOffK[i] = row * stride + ((ch ^ (row & 7)) << 3);
    }

    f32x4 ofr[ND] = {};
    float m_r[4], l_r[4];
#pragma unroll
    for (int r = 0; r < 4; ++r) { m_r[r] = -1e30f; l_r[r] = 0.f; }

    for (int kt = 0; kt < L_SEQ / KT; ++kt) {
        const u16* Ksrc = Kbase + (size_t)(kt * KT) * stride;
        const u16* Vsrc = Vbase + (size_t)(kt * KT) * stride;
        __syncthreads();
#pragma unroll
        for (int i = 0; i < NISS; ++i)
            gload_lds16(Ksrc + srcOffK[i], Kl + (size_t)(w * NISS + i) * 512);
#pragma unroll
        for (int half = 0; half < HD / 64; ++half) {
            int dbase = w * 16 + half * 64;
            u16x8 v0 = *(const u16x8*)(Vsrc + (size_t)lane * stride + dbase);
            u16x8 v1 = *(const u16x8*)(Vsrc + (size_t)lane * stride + dbase + 8);
#pragma unroll
            for (int j = 0; j < 8; ++j) {
                Vt[(dbase + j) * VSTR + lane] = v0[j];
                Vt[(dbase + 8 + j) * VSTR + lane] = v1[j];
            }
        }
        __syncthreads();

        f32x4 s[4];
#pragma unroll
        for (int sub = 0; sub < 4; ++sub) {
            f32x4 acc = {};
#pragma unroll
            for (int f = 0; f < NF; ++f) {
                int row = sub * 16 + r16;
                int chunk = (f * 4 + g) ^ (row & 7);
                s16x8 kf = *(const s16x8*)&Kl[(row * CH + chunk) * 8];
                acc = __builtin_amdgcn_mfma_f32_16x16x32_bf16(qf[f], kf, acc, 0, 0, 0);
            }
            s[sub] = acc;
        }

#pragma unroll
        for (int sub = 0; sub < 4; ++sub)
#pragma unroll
            for (int r = 0; r < 4; ++r) s[sub][r] *= scale;
#pragma unroll
        for (int r = 0; r < 4; ++r) {
            float mx = fmaxf(fmaxf(s[0][r], s[1][r]), fmaxf(s[2][r], s[3][r]));
            mx = fmaxf(mx, __shfl_xor(mx, 1));
            mx = fmaxf(mx, __shfl_xor(mx, 2));
            mx = fmaxf(mx, __shfl_xor(mx, 4));
            mx = fmaxf(mx, __shfl_xor(mx, 8));
            float mo = m_r[r];
            float mn = fmaxf(mo, mx);
            float sc = __expf(mo - mn);
            m_r[r] = mn;
            float sum = 0.f;
#pragma unroll
            for (int sub = 0; sub < 4; ++sub) {
                float e = __expf(s[sub][r] - mn);
                s[sub][r] = e;
                sum += e;
            }
            sum += __shfl_xor(sum, 1);
            sum += __shfl_xor(sum, 2);
            sum += __shfl_xor(sum, 4);
            sum += __shfl_xor(sum, 8);
            l_r[r] = l_r[r] * sc + sum;
#pragma unroll
            for (int dsub = 0; dsub < ND; ++dsub) ofr[dsub][r] *= sc;
        }

        u16* Pw = Pl[w];
#pragma unroll
        for (int sub = 0; sub < 4; ++sub)
#pragma unroll
            for (int r = 0; r < 4; ++r) {
                int q = g * 4 + r;
                int k = sub * 16 + r16;
                Pw[q * 72 + (((k >> 3) ^ (q & 7)) << 3) + (k & 7)] = f2bf(s[sub][r]);
            }
        __syncthreads();

        s16x8 pf[2];
#pragma unroll
        for (int ks = 0; ks < 2; ++ks) {
            int chunk = (ks * 4 + g) ^ (r16 & 7);
            pf[ks] = *(const s16x8*)&Pw[r16 * 72 + chunk * 8];
        }
#pragma unroll
        for (int dsub = 0; dsub < ND; ++dsub)
#pragma unroll
            for (int ks = 0; ks < 2; ++ks) {
                s16x8 vf = *(const s16x8*)&Vt[(dsub * 16 + r16) * VSTR + ks * 32 + g * 8];
                ofr[dsub] = __builtin_amdgcn_mfma_f32_16x16x32_bf16(pf[ks], vf, ofr[dsub], 0, 0, 0);
            }
    }

    float inv[4];
#pragma unroll
    for (int r = 0; r < 4; ++r) inv[r] = 1.0f / l_r[r];
#pragma unroll
    for (int dsub = 0; dsub < ND; ++dsub)
#pragma unroll
        for (int r = 0; r < 4; ++r) {
            int q = q0 + w * 16 + g * 4 + r;
            O[(size_t)(b * L_SEQ + q) * ostride + h * HD + dsub * 16 + r16] =
                f2bf(ofr[dsub][r] * inv[r]);
        }
}

// ---------------- DeltaNet conv + gate (bf16 in/out, fp32 math) ----------------
__global__ __launch_bounds__(256) void conv_gate_kernel(const u16* __restrict__ gv,
                                                        const float* __restrict__ cw,
                                                        const float* __restrict__ cb,
                                                        u16* __restrict__ gated) {
    int idx = blockIdx.x * 256 + threadIdx.x;
    if (idx >= T_TOK * D_MOD) return;
    int d = idx & (D_MOD - 1);
    int t = idx >> 10;
    int l = t & (L_SEQ - 1);
    float conv = cb[d];
#pragma unroll
    for (int i = 0; i < DC_K; ++i) {
        int lp = l - (DC_K - 1) + i;
        if (lp >= 0)
            conv += b2f(gv[(size_t)(t - l + lp) * (2 * D_MOD) + D_MOD + d]) * cw[d * DC_K + i];
    }
    float gate = b2f(gv[(size_t)t * (2 * D_MOD) + d]);
    float sig = 1.0f / (1.0f + expf(-gate));
    gated[(size_t)t * D_MOD + d] = f2bf(conv * (gate * sig));
}

// ---------------- MoE routing (fp32 input) ----------------
__global__ __launch_bounds__(256) void route_kernel(const float* __restrict__ g,
                                                    const float* __restrict__ wg,
                                                    int* __restrict__ tIdx,
                                                    float* __restrict__ tScore,
                                                    int* __restrict__ counts) {
    int t = blockIdx.x, tid = threadIdx.x;
    __shared__ float gs[D_MOD];
    __shared__ float logits[N_E];
    ((float4*)gs)[tid] = ((const float4*)(g + (size_t)t * D_MOD))[tid];
    __syncthreads();
    int e = tid >> 5, lane = tid & 31;
    const float* w = wg + (size_t)e * D_MOD;
    float p = 0.f;
    for (int d = lane; d < D_MOD; d += 32) p += gs[d] * w[d];
    for (int o = 16; o > 0; o >>= 1) p += __shfl_down(p, o, 32);
    if (lane == 0) logits[e] = p;
    __syncthreads();
    if (tid == 0) {
        float mx = logits[0];
        for (int e2 = 1; e2 < N_E; ++e2) mx = fmaxf(mx, logits[e2]);
        float pe[N_E];
        float Z = 0.f;
        for (int e2 = 0; e2 < N_E; ++e2) {
            pe[e2] = expf(logits[e2] - mx);
            Z += pe[e2];
        }
        int i0 = 0;
        float b0 = pe[0];
        for (int e2 = 1; e2 < N_E; ++e2)
            if (pe[e2] > b0) { b0 = pe[e2]; i0 = e2; }
        int i1 = -1;
        float b1 = -1.f;
        for (int e2 = 0; e2 < N_E; ++e2)
            if (e2 != i0 && pe[e2] > b1) { b1 = pe[e2]; i1 = e2; }
        float invZ = 1.0f / Z;
        tIdx[t * 2] = i0;
        tIdx[t * 2 + 1] = i1;
        tScore[t * 2] = b0 * invZ;
        tScore[t * 2 + 1] = b1 * invZ;
        atomicAdd(&counts[i0], 1);
        atomicAdd(&counts[i1], 1);
    }
}

__global__ void prefix_kernel(const int* __restrict__ counts, int* __restrict__ offs,
                              int* __restrict__ cursor) {
    if (threadIdx.x == 0) {
        int acc = 0;
        for (int e = 0; e < N_E; ++e) {
            offs[e] = acc;
            acc += counts[e];
            cursor[e] = 0;
        }
    }
}

__global__ __launch_bounds__(256) void fill_kernel(const int* __restrict__ tIdx,
                                                   const int* __restrict__ offs,
                                                   int* __restrict__ cursor,
                                                   int* __restrict__ list,
                                                   int* __restrict__ pairRow) {
    int t = blockIdx.x * 256 + threadIdx.x;
    if (t >= T_TOK) return;
    for (int kk = 0; kk < 2; ++kk) {
        int e = tIdx[t * 2 + kk];
        int pos = atomicAdd(&cursor[e], 1);
        int slot = offs[e] + pos;
        list[slot] = t;
        pairRow[t * 2 + kk] = slot;
    }
}

// ---------------- MoE combine (bf16 ysel) ----------------
__global__ __launch_bounds__(256) void combine_kernel(const u16* __restrict__ ysel,
                                                      const float* __restrict__ tScore,
                                                      const int* __restrict__ pairRow,
                                                      float* __restrict__ h) {
    int idx = blockIdx.x * 256 + threadIdx.x;
    if (idx >= T_TOK * D_MOD) return;
    int t = idx >> 10;
    int d = idx & (D_MOD - 1);
    float acc = h[idx];
#pragma unroll
    for (int kk = 0; kk < 2; ++kk) {
        int r = pairRow[t * 2 + kk];
        acc += tScore[t * 2 + kk] * b2f(ysel[(size_t)r * D_MOD + d]);
    }
    h[idx] = acc;
}

extern "C" void kernel_launch(void* const* d_in, const int* in_sizes, int n_in,
                              void* d_out, int out_size, void* d_ws, size_t ws_size,
                              hipStream_t stream) {
    const float* x = (const float*)d_in[0];
    const float* w_rms1 = (const float*)d_in[2];
    const float* w_rms2 = (const float*)d_in[3];
    const float* w_rms3 = (const float*)d_in[4];
    const float* w_rms4 = (const float*)d_in[5];
    const float* Wq = (const float*)d_in[6];
    const float* Wk = (const float*)d_in[7];
    const float* Wv = (const float*)d_in[8];
    const float* Wo = (const float*)d_in[9];
    const float* Cq = (const float*)d_in[10];
    const float* Ck = (const float*)d_in[11];
    const float* Cv = (const float*)d_in[12];
    const float* Co = (const float*)d_in[13];
    const float* Wi = (const float*)d_in[14];
    const float* bi = (const float*)d_in[15];
    const float* conv_w = (const float*)d_in[16];
    const float* conv_b = (const float*)d_in[17];
    const float* Wod = (const float*)d_in[18];
    const float* bod = (const float*)d_in[19];
    const float* w_gate = (const float*)d_in[20];
    const float* W1 = (const float*)d_in[21];
    const float* b1 = (const float*)d_in[22];
    const float* W2 = (const float*)d_in[23];
    const float* b2 = (const float*)d_in[24];
    float* out = (float*)d_out;

    char* ws = (char*)d_ws;
    size_t off = 0;
    auto alloc_f = [&](size_t n) { float* p = (float*)(ws + off); off += n * 4; return p; };
    auto alloc_b = [&](size_t n) { u16* p = (u16*)(ws + off); off += n * 2; return p; };

    u16* qkvT = alloc_b((size_t)1536 * 1024);
    u16* cqkvT = alloc_b((size_t)3072 * 1024);
    u16* WoT = alloc_b((size_t)1024 * 1024);
    u16* CoT = alloc_b((size_t)1024 * 1024);
    u16* WiT = alloc_b((size_t)2048 * 1024);
    u16* WodT = alloc_b((size_t)1024 * 1024);
    u16* W1T = alloc_b((size_t)N_E * FF_DIM * 1024);
    u16* W2T = alloc_b((size_t)N_E * 1024 * FF_DIM);
    const size_t TD = (size_t)T_TOK * D_MOD;
    float* h = alloc_f(TD);
    float* nrm = alloc_f(TD);
    u16* nrm_bf = alloc_b(TD);
    u16* h_bf = alloc_b(TD);
    u16* ab_bf = alloc_b(TD);
    u16* qkv_bf = alloc_b((size_t)T_TOK * 3072);
    u16* gv_bf = alloc_b((size_t)T_TOK * 2048);
    u16* hsel = alloc_b((size_t)2 * T_TOK * FF_DIM);
    u16* ysel = alloc_b((size_t)2 * T_TOK * D_MOD);
    int* counts = (int*)(ws + off); off += N_E * 4;
    int* offs = (int*)(ws + off); off += N_E * 4;
    int* cursor = (int*)(ws + off); off += N_E * 4;
    int* tIdx = (int*)(ws + off); off += 2 * T_TOK * 4;
    int* list = (int*)(ws + off); off += 2 * T_TOK * 4;
    int* pairRow = (int*)(ws + off); off += 2 * T_TOK * 4;
    float* tScore = alloc_f(2 * T_TOK);

    // ---- 0. weight transpose+convert (64x64 tiles) ----
    transpose_cvt<<<dim3(16, 16, 1), 256, 0, stream>>>(Wq, qkvT, 1024, 1024, 1024, 0);
    transpose_cvt<<<dim3(4, 16, 1), 256, 0, stream>>>(Wk, qkvT, 1024, 256, 1024, 1024);
    transpose_cvt<<<dim3(4, 16, 1), 256, 0, stream>>>(Wv, qkvT, 1024, 256, 1024, 1280);
    transpose_cvt<<<dim3(16, 16, 1), 256, 0, stream>>>(Cq, cqkvT, 1024, 1024, 1024, 0);
    transpose_cvt<<<dim3(16, 16, 1), 256, 0, stream>>>(Ck, cqkvT, 1024, 1024, 1024, 1024);
    transpose_cvt<<<dim3(16, 16, 1), 256, 0, stream>>>(Cv, cqkvT, 1024, 1024, 1024, 2048);
    transpose_cvt<<<dim3(16, 16, 1), 256, 0, stream>>>(Wo, WoT, 1024, 1024, 1024, 0);
    transpose_cvt<<<dim3(16, 16, 1), 256, 0, stream>>>(Co, CoT, 1024, 1024, 1024, 0);
    transpose_cvt<<<dim3(32, 16, 1), 256, 0, stream>>>(Wi, WiT, 1024, 2048, 1024, 0);
    transpose_cvt<<<dim3(16, 16, 1), 256, 0, stream>>>(Wod, WodT, 1024, 1024, 1024, 0);
    transpose_cvt<<<dim3(64, 16, N_E), 256, 0, stream>>>(W1, W1T, 1024, FF_DIM, 1024, 0);
    transpose_cvt<<<dim3(16, 64, N_E), 256, 0, stream>>>(W2, W2T, FF_DIM, 1024, FF_DIM, 0);

    // ---- 1. attn1 (GQA 16h/4kv, hd=64) ----
    rmsnorm_kernel<<<T_TOK, 256, 0, stream>>>(x, w_rms1, nullptr, nrm_bf);
    mfma_gemm<0, 0, 0, 1, 64, 128, 256><<<dim3(12, 32, 1), 256, 0, stream>>>(
        nrm_bf, qkvT, nullptr, nullptr, nullptr, qkv_bf, nullptr, nullptr, nullptr,
        T_TOK, 1536, 1024, 0);
    mfma_attn<64><<<dim3(16, N_H, B_SZ), 256, 0, stream>>>(
        qkv_bf, qkv_bf + 1024, qkv_bf + 1280, ab_bf, 1536, 1024, N_H, N_KV, 0.125f);
    mfma_gemm<0, 0, 1, 1, 64, 128, 256><<<dim3(8, 32, 1), 256, 0, stream>>>(
        ab_bf, WoT, nullptr, x, h, h_bf, nullptr, nullptr, nullptr, T_TOK, 1024, 1024, 0);

    // ---- 2. ContextManager attention (8h/8kv, hd=128) ----
    mfma_gemm<0, 0, 0, 1, 64, 128, 256><<<dim3(24, 32, 1), 256, 0, stream>>>(
        h_bf, cqkvT, nullptr, nullptr, nullptr, qkv_bf, nullptr, nullptr, nullptr,
        T_TOK, 3072, 1024, 0);
    mfma_attn<128><<<dim3(16, N_CH, B_SZ), 256, 0, stream>>>(
        qkv_bf, qkv_bf + 1024, qkv_bf + 2048, ab_bf, 3072, 1024, N_CH, N_CH,
        0.088388347648318447f);
    mfma_gemm<0, 0, 1, 0, 64, 128, 256><<<dim3(8, 32, 1), 256, 0, stream>>>(
        ab_bf, CoT, nullptr, h, h, nullptr, nullptr, nullptr, nullptr, T_TOK, 1024, 1024, 0);

    // ---- 3. deltanet ----
    rmsnorm_kernel<<<T_TOK, 256, 0, stream>>>(h, w_rms2, nullptr, nrm_bf);
    mfma_gemm<0, 0, 0, 1, 64, 128, 256><<<dim3(16, 32, 1), 256, 0, stream>>>(
        nrm_bf, WiT, bi, nullptr, nullptr, gv_bf, nullptr, nullptr, nullptr, T_TOK, 2048, 1024, 0);
    conv_gate_kernel<<<(T_TOK * D_MOD) / 256, 256, 0, stream>>>(gv_bf, conv_w, conv_b, ab_bf);
    mfma_gemm<0, 0, 1, 0, 64, 128, 256><<<dim3(8, 32, 1), 256, 0, stream>>>(
        ab_bf, WodT, bod, h, h, nullptr, nullptr, nullptr, nullptr, T_TOK, 1024, 1024, 0);

    // ---- 4. MoE (top-2 of 8), expert->XCD affinity grids ----
    rmsnorm_kernel<<<T_TOK, 256, 0, stream>>>(h, w_rms3, nrm, nrm_bf);
    hipMemsetAsync(counts, 0, N_E * sizeof(int), stream);
    route_kernel<<<T_TOK, 256, 0, stream>>>(nrm, w_gate, tIdx, tScore, counts);
    prefix_kernel<<<1, 64, 0, stream>>>(counts, offs, cursor);
    fill_kernel<<<(T_TOK + 255) / 256, 256, 0, stream>>>(tIdx, offs, cursor, list, pairRow);
    // MoE1: 256x256 tile, 8 waves; grid = nx(16) * ny(16) * 8 experts, 1-D
    mfma_gemm<1, 1, 0, 1, 256, 256, 512><<<16 * 16 * 8, 512, 0, stream>>>(
        nrm_bf, W1T, b1, nullptr, nullptr, hsel, list, offs, counts, T_TOK, FF_DIM, 1024, 16);
    // MoE2: 128x128 tile, 4 waves; grid = nx(8) * ny(32) * 8 experts, 1-D
    mfma_gemm<2, 0, 0, 1, 128, 128, 256><<<8 * 32 * 8, 256, 0, stream>>>(
        hsel, W2T, b2, nullptr, nullptr, ysel, list, offs, counts, T_TOK, 1024, FF_DIM, 8);
    combine_kernel<<<(T_TOK * D_MOD) / 256, 256, 0, stream>>>(ysel, tScore, pairRow, h);

    // ---- 5. final rmsnorm -> out ----
    rmsnorm_kernel<<<T_TOK, 256, 0, stream>>>(h, w_rms4, out, nullptr);
}

// Round 8
// 674.682 us; speedup vs baseline: 8.1172x; 1.0665x over previous
//
#include <hip/hip_runtime.h>
#include <hip/hip_bf16.h>
#include <math.h>

#define T_TOK 2048
#define B_SZ 2
#define L_SEQ 1024
#define D_MOD 1024
#define N_H 16
#define N_KV 4
#define N_CH 8
#define N_E 8
#define FF_DIM 4096
#define DC_K 4
#define EPS_F 1e-6f

typedef unsigned short u16;
typedef unsigned int u32;
typedef short s16x8 __attribute__((ext_vector_type(8)));
typedef u16 u16x8 __attribute__((ext_vector_type(8)));
typedef float f32x4 __attribute__((ext_vector_type(4)));
struct alignas(8) U16x4 { u16 a, b, c, d; };

__device__ __forceinline__ float gelu_exact(float x) {
    return 0.5f * x * (1.0f + erff(x * 0.70710678118654752f));
}
__device__ __forceinline__ u16 f2bf(float f) {  // RNE
    u32 x = __float_as_uint(f);
    return (u16)((x + 0x7fffu + ((x >> 16) & 1u)) >> 16);
}
__device__ __forceinline__ float b2f(u16 u) {
    return __uint_as_float(((u32)u) << 16);
}
__device__ __forceinline__ void gload_lds16(const u16* g, u16* l) {
    __builtin_amdgcn_global_load_lds(
        (const __attribute__((address_space(1))) u32*)g,
        (__attribute__((address_space(3))) u32*)l, 16, 0, 0);
}

// ---------------- transpose + fp32->bf16 convert: dst[c][r] = src[r][c] ----------------
__global__ __launch_bounds__(256) void transpose_cvt(const float* __restrict__ src,
                                                     u16* __restrict__ dst,
                                                     int R, int C, int dstStride, int dstRowOff) {
    __shared__ float ts[64][65];
    int e = blockIdx.z;
    src += (size_t)e * R * C;
    dst += (size_t)e * (size_t)C * dstStride;
    int c0 = blockIdx.x * 64, r0 = blockIdx.y * 64;
    int t = threadIdx.x;
#pragma unroll
    for (int k = 0; k < 4; ++k) {
        int fidx = k * 256 + t;
        int r = fidx >> 4, c4 = (fidx & 15) << 2;
        float4 v = *(const float4*)(src + (size_t)(r0 + r) * C + c0 + c4);
        ts[r][c4] = v.x; ts[r][c4 + 1] = v.y; ts[r][c4 + 2] = v.z; ts[r][c4 + 3] = v.w;
    }
    __syncthreads();
#pragma unroll
    for (int k = 0; k < 4; ++k) {
        int idx = k * 256 + t;
        int c = idx >> 4, r4 = (idx & 15) << 2;
        U16x4 o;
        o.a = f2bf(ts[r4][c]);
        o.b = f2bf(ts[r4 + 1][c]);
        o.c = f2bf(ts[r4 + 2][c]);
        o.d = f2bf(ts[r4 + 3][c]);
        *(U16x4*)(dst + (size_t)(dstRowOff + c0 + c) * dstStride + r0 + r4) = o;
    }
}

// ---------------- RMSNorm: fp32 in, optional fp32 + bf16 out ----------------
__global__ __launch_bounds__(256) void rmsnorm_kernel(const float* __restrict__ x,
                                                      const float* __restrict__ w,
                                                      float* __restrict__ fo,
                                                      u16* __restrict__ bo) {
    int row = blockIdx.x;
    int tid = threadIdx.x;
    const float* xr = x + (size_t)row * D_MOD;
    float4 v = ((const float4*)xr)[tid];
    float ss = v.x * v.x + v.y * v.y + v.z * v.z + v.w * v.w;
    __shared__ float red[256];
    red[tid] = ss;
    __syncthreads();
    for (int s = 128; s > 0; s >>= 1) {
        if (tid < s) red[tid] += red[tid + s];
        __syncthreads();
    }
    float inv = 1.0f / sqrtf(red[0] * (1.0f / D_MOD) + EPS_F);
    float4 wv = ((const float4*)w)[tid];
    float4 o;
    o.x = v.x * inv * wv.x;
    o.y = v.y * inv * wv.y;
    o.z = v.z * inv * wv.z;
    o.w = v.w * inv * wv.w;
    if (fo) ((float4*)(fo + (size_t)row * D_MOD))[tid] = o;
    if (bo) {
        U16x4 b;
        b.a = f2bf(o.x); b.b = f2bf(o.y); b.c = f2bf(o.z); b.d = f2bf(o.w);
        *(U16x4*)(bo + (size_t)row * D_MOD + tid * 4) = b;
    }
}

// ---------------- MFMA bf16 GEMM, 2-phase double-buffered, parametric tile ----------------
// C[M,N](f32/bf16) = A[M,K]bf16 @ BT[N,K]bf16. BM x BN tile, BK=32, NT threads.
// NT=256: 4 waves (2x2). NT=512: 8 waves (2x4).
// MODE 0: dense, 3-D grid. MODE 1/2 (MoE gather/compact): 1-D grid with
// expert->XCD affinity (e = id%8). Latency hiding comes from 2-5 co-resident
// blocks/CU (m114 wave-level overlap), not intra-block pipelining.
template <int MODE, int GELU, int OUTF, int OUTB, int BM, int BN, int NT>
__global__ __launch_bounds__(NT) void mfma_gemm(const u16* __restrict__ A,
                                                const u16* __restrict__ BT,
                                                const float* __restrict__ bias,
                                                const float* __restrict__ res,
                                                float* __restrict__ C,
                                                u16* __restrict__ Cb,
                                                const int* __restrict__ list,
                                                const int* __restrict__ offs,
                                                const int* __restrict__ counts,
                                                int M, int N, int K, int nx) {
    constexpr int WN = (NT == 512) ? 4 : 2;
    constexpr int PWR = BM / 2;
    constexpr int PWC = BN / WN;
    constexpr int MI = PWR / 16;
    constexpr int NI = PWC / 16;
    constexpr int NAI = (BM * 4) / NT;
    constexpr int NBI = (BN * 4) / NT;
    __shared__ u16 ldsA[2][BM * 32];
    __shared__ u16 ldsB[2][BN * 32];
    int tid = threadIdx.x;
    int lane = tid & 63, w = tid >> 6;
    int wr = w / WN, wc = w % WN;
    int bx, by, e;
    if (MODE == 0) {
        bx = blockIdx.x; by = blockIdx.y; e = 0;
    } else {
        int id = blockIdx.x;
        e = id & 7;
        int r = id >> 3;
        bx = r % nx;
        by = r / nx;
    }
    int cnt, off;
    if (MODE == 0) { cnt = M; off = 0; }
    else { cnt = counts[e]; off = offs[e]; }
    int m0 = by * BM;
    if (m0 >= cnt) return;
    int n0 = bx * BN;
    const u16* Bt = BT + (size_t)e * (size_t)N * K;

    const u16* aSrc[NAI];
    const u16* bSrc[NBI];
#pragma unroll
    for (int j = 0; j < NAI; ++j) {
        int rowA = j * (NT / 4) + w * 16 + (lane >> 2);
        int slot = lane & 3;
        int rl = m0 + rowA;
        if (rl >= cnt) rl = cnt - 1;
        size_t ga;
        if (MODE == 1) ga = (size_t)list[off + rl] * K;
        else if (MODE == 2) ga = (size_t)(off + rl) * K;
        else ga = (size_t)rl * K;
        aSrc[j] = A + ga + ((slot ^ ((rowA >> 1) & 3)) << 3);
    }
#pragma unroll
    for (int j = 0; j < NBI; ++j) {
        int rowB = j * (NT / 4) + w * 16 + (lane >> 2);
        int slot = lane & 3;
        bSrc[j] = Bt + (size_t)(n0 + rowB) * K + ((slot ^ ((rowB >> 1) & 3)) << 3);
    }

    auto stage = [&](int buf, int k0) {
#pragma unroll
        for (int j = 0; j < NAI; ++j)
            gload_lds16(aSrc[j] + k0, &ldsA[buf][(j * NT + w * 64) * 8]);
#pragma unroll
        for (int j = 0; j < NBI; ++j)
            gload_lds16(bSrc[j] + k0, &ldsB[buf][(j * NT + w * 64) * 8]);
    };

    f32x4 acc[MI][NI] = {};
    int r16 = lane & 15, cr = lane >> 4;

    stage(0, 0);
    __syncthreads();
    int cur = 0;
    for (int k0 = 0; k0 < K; k0 += 32) {
        if (k0 + 32 < K) stage(cur ^ 1, k0 + 32);
        s16x8 af[MI], bfr[NI];
#pragma unroll
        for (int mi = 0; mi < MI; ++mi) {
            int row = wr * PWR + mi * 16 + r16;
            af[mi] = *(const s16x8*)&ldsA[cur][row * 32 + ((cr ^ ((row >> 1) & 3)) << 3)];
        }
#pragma unroll
        for (int ni = 0; ni < NI; ++ni) {
            int row = wc * PWC + ni * 16 + r16;
            bfr[ni] = *(const s16x8*)&ldsB[cur][row * 32 + ((cr ^ ((row >> 1) & 3)) << 3)];
        }
#pragma unroll
        for (int mi = 0; mi < MI; ++mi)
#pragma unroll
            for (int ni = 0; ni < NI; ++ni)
                acc[mi][ni] = __builtin_amdgcn_mfma_f32_16x16x32_bf16(af[mi], bfr[ni],
                                                                      acc[mi][ni], 0, 0, 0);
        __syncthreads();
        cur ^= 1;
    }

    const float* bias_e = bias ? (bias + (MODE ? (size_t)e * N : 0)) : nullptr;
#pragma unroll
    for (int mi = 0; mi < MI; ++mi) {
#pragma unroll
        for (int ni = 0; ni < NI; ++ni) {
            int rloc = wr * PWR + mi * 16 + (lane >> 4) * 4;
            int col = n0 + wc * PWC + ni * 16 + (lane & 15);
#pragma unroll
            for (int jj = 0; jj < 4; ++jj) {
                int rl = m0 + rloc + jj;
                if (rl >= cnt) continue;
                float val = acc[mi][ni][jj];
                if (bias_e) val += bias_e[col];
                if (GELU) val = gelu_exact(val);
                size_t crow = (MODE == 0) ? (size_t)rl : (size_t)(off + rl);
                if (res) val += res[crow * N + col];
                if (OUTF) C[crow * N + col] = val;
                if (OUTB) Cb[crow * N + col] = f2bf(val);
            }
        }
    }
}

// ---------------- MFMA flash attention (unchanged) ----------------
template <int HD>
__global__ __launch_bounds__(256) void mfma_attn(const u16* __restrict__ Qb,
                                                 const u16* __restrict__ Kb,
                                                 const u16* __restrict__ Vb,
                                                 u16* __restrict__ O,
                                                 int stride, int ostride,
                                                 int nh, int nkv, float scale) {
    constexpr int KT = 64;
    constexpr int CH = HD / 8;
    constexpr int NF = HD / 32;
    constexpr int ND = HD / 16;
    constexpr int VSTR = 72;
    constexpr int NISS = (64 * CH) / (64 * 4);

    __shared__ u16 Kl[64 * HD];
    __shared__ u16 Vt[HD * VSTR];
    __shared__ u16 Pl[4][16 * 72];

    int tid = threadIdx.x, lane = tid & 63, w = tid >> 6;
    int g = lane >> 4, r16 = lane & 15;
    int q0 = blockIdx.x * 64, h = blockIdx.y, b = blockIdx.z;
    int kvh = h / (nh / nkv);

    const u16* Qp = Qb + (size_t)(b * L_SEQ + q0 + w * 16 + r16) * stride + h * HD + g * 8;
    s16x8 qf[NF];
#pragma unroll
    for (int f = 0; f < NF; ++f) qf[f] = *(const s16x8*)(Qp + f * 32);

    const u16* Kbase = Kb + (size_t)(b * L_SEQ) * stride + (size_t)kvh * HD;
    const u16* Vbase = Vb + (size_t)(b * L_SEQ) * stride + (size_t)kvh * HD;

    int srcOffK[NISS];
#pragma unroll
    for (int i = 0; i < NISS; ++i) {
        int ci = (w * NISS + i) * 64 + lane;
        int row = ci / CH;
        int ch = ci % CH;
        srcOffK[i] = row * stride + ((ch ^ (row & 7)) << 3);
    }

    f32x4 ofr[ND] = {};
    float m_r[4], l_r[4];
#pragma unroll
    for (int r = 0; r < 4; ++r) { m_r[r] = -1e30f; l_r[r] = 0.f; }

    for (int kt = 0; kt < L_SEQ / KT; ++kt) {
        const u16* Ksrc = Kbase + (size_t)(kt * KT) * stride;
        const u16* Vsrc = Vbase + (size_t)(kt * KT) * stride;
        __syncthreads();
#pragma unroll
        for (int i = 0; i < NISS; ++i)
            gload_lds16(Ksrc + srcOffK[i], Kl + (size_t)(w * NISS + i) * 512);
#pragma unroll
        for (int half = 0; half < HD / 64; ++half) {
            int dbase = w * 16 + half * 64;
            u16x8 v0 = *(const u16x8*)(Vsrc + (size_t)lane * stride + dbase);
            u16x8 v1 = *(const u16x8*)(Vsrc + (size_t)lane * stride + dbase + 8);
#pragma unroll
            for (int j = 0; j < 8; ++j) {
                Vt[(dbase + j) * VSTR + lane] = v0[j];
                Vt[(dbase + 8 + j) * VSTR + lane] = v1[j];
            }
        }
        __syncthreads();

        f32x4 s[4];
#pragma unroll
        for (int sub = 0; sub < 4; ++sub) {
            f32x4 acc = {};
#pragma unroll
            for (int f = 0; f < NF; ++f) {
                int row = sub * 16 + r16;
                int chunk = (f * 4 + g) ^ (row & 7);
                s16x8 kf = *(const s16x8*)&Kl[(row * CH + chunk) * 8];
                acc = __builtin_amdgcn_mfma_f32_16x16x32_bf16(qf[f], kf, acc, 0, 0, 0);
            }
            s[sub] = acc;
        }

#pragma unroll
        for (int sub = 0; sub < 4; ++sub)
#pragma unroll
            for (int r = 0; r < 4; ++r) s[sub][r] *= scale;
#pragma unroll
        for (int r = 0; r < 4; ++r) {
            float mx = fmaxf(fmaxf(s[0][r], s[1][r]), fmaxf(s[2][r], s[3][r]));
            mx = fmaxf(mx, __shfl_xor(mx, 1));
            mx = fmaxf(mx, __shfl_xor(mx, 2));
            mx = fmaxf(mx, __shfl_xor(mx, 4));
            mx = fmaxf(mx, __shfl_xor(mx, 8));
            float mo = m_r[r];
            float mn = fmaxf(mo, mx);
            float sc = __expf(mo - mn);
            m_r[r] = mn;
            float sum = 0.f;
#pragma unroll
            for (int sub = 0; sub < 4; ++sub) {
                float e = __expf(s[sub][r] - mn);
                s[sub][r] = e;
                sum += e;
            }
            sum += __shfl_xor(sum, 1);
            sum += __shfl_xor(sum, 2);
            sum += __shfl_xor(sum, 4);
            sum += __shfl_xor(sum, 8);
            l_r[r] = l_r[r] * sc + sum;
#pragma unroll
            for (int dsub = 0; dsub < ND; ++dsub) ofr[dsub][r] *= sc;
        }

        u16* Pw = Pl[w];
#pragma unroll
        for (int sub = 0; sub < 4; ++sub)
#pragma unroll
            for (int r = 0; r < 4; ++r) {
                int q = g * 4 + r;
                int k = sub * 16 + r16;
                Pw[q * 72 + (((k >> 3) ^ (q & 7)) << 3) + (k & 7)] = f2bf(s[sub][r]);
            }
        __syncthreads();

        s16x8 pf[2];
#pragma unroll
        for (int ks = 0; ks < 2; ++ks) {
            int chunk = (ks * 4 + g) ^ (r16 & 7);
            pf[ks] = *(const s16x8*)&Pw[r16 * 72 + chunk * 8];
        }
#pragma unroll
        for (int dsub = 0; dsub < ND; ++dsub)
#pragma unroll
            for (int ks = 0; ks < 2; ++ks) {
                s16x8 vf = *(const s16x8*)&Vt[(dsub * 16 + r16) * VSTR + ks * 32 + g * 8];
                ofr[dsub] = __builtin_amdgcn_mfma_f32_16x16x32_bf16(pf[ks], vf, ofr[dsub], 0, 0, 0);
            }
    }

    float inv[4];
#pragma unroll
    for (int r = 0; r < 4; ++r) inv[r] = 1.0f / l_r[r];
#pragma unroll
    for (int dsub = 0; dsub < ND; ++dsub)
#pragma unroll
        for (int r = 0; r < 4; ++r) {
            int q = q0 + w * 16 + g * 4 + r;
            O[(size_t)(b * L_SEQ + q) * ostride + h * HD + dsub * 16 + r16] =
                f2bf(ofr[dsub][r] * inv[r]);
        }
}

// ---------------- DeltaNet conv + gate (bf16 in/out, fp32 math) ----------------
__global__ __launch_bounds__(256) void conv_gate_kernel(const u16* __restrict__ gv,
                                                        const float* __restrict__ cw,
                                                        const float* __restrict__ cb,
                                                        u16* __restrict__ gated) {
    int idx = blockIdx.x * 256 + threadIdx.x;
    if (idx >= T_TOK * D_MOD) return;
    int d = idx & (D_MOD - 1);
    int t = idx >> 10;
    int l = t & (L_SEQ - 1);
    float conv = cb[d];
#pragma unroll
    for (int i = 0; i < DC_K; ++i) {
        int lp = l - (DC_K - 1) + i;
        if (lp >= 0)
            conv += b2f(gv[(size_t)(t - l + lp) * (2 * D_MOD) + D_MOD + d]) * cw[d * DC_K + i];
    }
    float gate = b2f(gv[(size_t)t * (2 * D_MOD) + d]);
    float sig = 1.0f / (1.0f + expf(-gate));
    gated[(size_t)t * D_MOD + d] = f2bf(conv * (gate * sig));
}

// ---------------- MoE routing (fp32 input) ----------------
__global__ __launch_bounds__(256) void route_kernel(const float* __restrict__ g,
                                                    const float* __restrict__ wg,
                                                    int* __restrict__ tIdx,
                                                    float* __restrict__ tScore,
                                                    int* __restrict__ counts) {
    int t = blockIdx.x, tid = threadIdx.x;
    __shared__ float gs[D_MOD];
    __shared__ float logits[N_E];
    ((float4*)gs)[tid] = ((const float4*)(g + (size_t)t * D_MOD))[tid];
    __syncthreads();
    int e = tid >> 5, lane = tid & 31;
    const float* w = wg + (size_t)e * D_MOD;
    float p = 0.f;
    for (int d = lane; d < D_MOD; d += 32) p += gs[d] * w[d];
    for (int o = 16; o > 0; o >>= 1) p += __shfl_down(p, o, 32);
    if (lane == 0) logits[e] = p;
    __syncthreads();
    if (tid == 0) {
        float mx = logits[0];
        for (int e2 = 1; e2 < N_E; ++e2) mx = fmaxf(mx, logits[e2]);
        float pe[N_E];
        float Z = 0.f;
        for (int e2 = 0; e2 < N_E; ++e2) {
            pe[e2] = expf(logits[e2] - mx);
            Z += pe[e2];
        }
        int i0 = 0;
        float b0 = pe[0];
        for (int e2 = 1; e2 < N_E; ++e2)
            if (pe[e2] > b0) { b0 = pe[e2]; i0 = e2; }
        int i1 = -1;
        float b1 = -1.f;
        for (int e2 = 0; e2 < N_E; ++e2)
            if (e2 != i0 && pe[e2] > b1) { b1 = pe[e2]; i1 = e2; }
        float invZ = 1.0f / Z;
        tIdx[t * 2] = i0;
        tIdx[t * 2 + 1] = i1;
        tScore[t * 2] = b0 * invZ;
        tScore[t * 2 + 1] = b1 * invZ;
        atomicAdd(&counts[i0], 1);
        atomicAdd(&counts[i1], 1);
    }
}

__global__ void prefix_kernel(const int* __restrict__ counts, int* __restrict__ offs,
                              int* __restrict__ cursor) {
    if (threadIdx.x == 0) {
        int acc = 0;
        for (int e = 0; e < N_E; ++e) {
            offs[e] = acc;
            acc += counts[e];
            cursor[e] = 0;
        }
    }
}

__global__ __launch_bounds__(256) void fill_kernel(const int* __restrict__ tIdx,
                                                   const int* __restrict__ offs,
                                                   int* __restrict__ cursor,
                                                   int* __restrict__ list,
                                                   int* __restrict__ pairRow) {
    int t = blockIdx.x * 256 + threadIdx.x;
    if (t >= T_TOK) return;
    for (int kk = 0; kk < 2; ++kk) {
        int e = tIdx[t * 2 + kk];
        int pos = atomicAdd(&cursor[e], 1);
        int slot = offs[e] + pos;
        list[slot] = t;
        pairRow[t * 2 + kk] = slot;
    }
}

// ---------------- MoE combine (bf16 ysel) ----------------
__global__ __launch_bounds__(256) void combine_kernel(const u16* __restrict__ ysel,
                                                      const float* __restrict__ tScore,
                                                      const int* __restrict__ pairRow,
                                                      float* __restrict__ h) {
    int idx = blockIdx.x * 256 + threadIdx.x;
    if (idx >= T_TOK * D_MOD) return;
    int t = idx >> 10;
    int d = idx & (D_MOD - 1);
    float acc = h[idx];
#pragma unroll
    for (int kk = 0; kk < 2; ++kk) {
        int r = pairRow[t * 2 + kk];
        acc += tScore[t * 2 + kk] * b2f(ysel[(size_t)r * D_MOD + d]);
    }
    h[idx] = acc;
}

extern "C" void kernel_launch(void* const* d_in, const int* in_sizes, int n_in,
                              void* d_out, int out_size, void* d_ws, size_t ws_size,
                              hipStream_t stream) {
    const float* x = (const float*)d_in[0];
    const float* w_rms1 = (const float*)d_in[2];
    const float* w_rms2 = (const float*)d_in[3];
    const float* w_rms3 = (const float*)d_in[4];
    const float* w_rms4 = (const float*)d_in[5];
    const float* Wq = (const float*)d_in[6];
    const float* Wk = (const float*)d_in[7];
    const float* Wv = (const float*)d_in[8];
    const float* Wo = (const float*)d_in[9];
    const float* Cq = (const float*)d_in[10];
    const float* Ck = (const float*)d_in[11];
    const float* Cv = (const float*)d_in[12];
    const float* Co = (const float*)d_in[13];
    const float* Wi = (const float*)d_in[14];
    const float* bi = (const float*)d_in[15];
    const float* conv_w = (const float*)d_in[16];
    const float* conv_b = (const float*)d_in[17];
    const float* Wod = (const float*)d_in[18];
    const float* bod = (const float*)d_in[19];
    const float* w_gate = (const float*)d_in[20];
    const float* W1 = (const float*)d_in[21];
    const float* b1 = (const float*)d_in[22];
    const float* W2 = (const float*)d_in[23];
    const float* b2 = (const float*)d_in[24];
    float* out = (float*)d_out;

    char* ws = (char*)d_ws;
    size_t off = 0;
    auto alloc_f = [&](size_t n) { float* p = (float*)(ws + off); off += n * 4; return p; };
    auto alloc_b = [&](size_t n) { u16* p = (u16*)(ws + off); off += n * 2; return p; };

    u16* qkvT = alloc_b((size_t)1536 * 1024);
    u16* cqkvT = alloc_b((size_t)3072 * 1024);
    u16* WoT = alloc_b((size_t)1024 * 1024);
    u16* CoT = alloc_b((size_t)1024 * 1024);
    u16* WiT = alloc_b((size_t)2048 * 1024);
    u16* WodT = alloc_b((size_t)1024 * 1024);
    u16* W1T = alloc_b((size_t)N_E * FF_DIM * 1024);
    u16* W2T = alloc_b((size_t)N_E * 1024 * FF_DIM);
    const size_t TD = (size_t)T_TOK * D_MOD;
    float* h = alloc_f(TD);
    float* nrm = alloc_f(TD);
    u16* nrm_bf = alloc_b(TD);
    u16* h_bf = alloc_b(TD);
    u16* ab_bf = alloc_b(TD);
    u16* qkv_bf = alloc_b((size_t)T_TOK * 3072);
    u16* gv_bf = alloc_b((size_t)T_TOK * 2048);
    u16* hsel = alloc_b((size_t)2 * T_TOK * FF_DIM);
    u16* ysel = alloc_b((size_t)2 * T_TOK * D_MOD);
    int* counts = (int*)(ws + off); off += N_E * 4;
    int* offs = (int*)(ws + off); off += N_E * 4;
    int* cursor = (int*)(ws + off); off += N_E * 4;
    int* tIdx = (int*)(ws + off); off += 2 * T_TOK * 4;
    int* list = (int*)(ws + off); off += 2 * T_TOK * 4;
    int* pairRow = (int*)(ws + off); off += 2 * T_TOK * 4;
    float* tScore = alloc_f(2 * T_TOK);

    // ---- 0. weight transpose+convert (64x64 tiles) ----
    transpose_cvt<<<dim3(16, 16, 1), 256, 0, stream>>>(Wq, qkvT, 1024, 1024, 1024, 0);
    transpose_cvt<<<dim3(4, 16, 1), 256, 0, stream>>>(Wk, qkvT, 1024, 256, 1024, 1024);
    transpose_cvt<<<dim3(4, 16, 1), 256, 0, stream>>>(Wv, qkvT, 1024, 256, 1024, 1280);
    transpose_cvt<<<dim3(16, 16, 1), 256, 0, stream>>>(Cq, cqkvT, 1024, 1024, 1024, 0);
    transpose_cvt<<<dim3(16, 16, 1), 256, 0, stream>>>(Ck, cqkvT, 1024, 1024, 1024, 1024);
    transpose_cvt<<<dim3(16, 16, 1), 256, 0, stream>>>(Cv, cqkvT, 1024, 1024, 1024, 2048);
    transpose_cvt<<<dim3(16, 16, 1), 256, 0, stream>>>(Wo, WoT, 1024, 1024, 1024, 0);
    transpose_cvt<<<dim3(16, 16, 1), 256, 0, stream>>>(Co, CoT, 1024, 1024, 1024, 0);
    transpose_cvt<<<dim3(32, 16, 1), 256, 0, stream>>>(Wi, WiT, 1024, 2048, 1024, 0);
    transpose_cvt<<<dim3(16, 16, 1), 256, 0, stream>>>(Wod, WodT, 1024, 1024, 1024, 0);
    transpose_cvt<<<dim3(64, 16, N_E), 256, 0, stream>>>(W1, W1T, 1024, FF_DIM, 1024, 0);
    transpose_cvt<<<dim3(16, 64, N_E), 256, 0, stream>>>(W2, W2T, FF_DIM, 1024, FF_DIM, 0);

    // ---- 1. attn1 (GQA 16h/4kv, hd=64) ----
    rmsnorm_kernel<<<T_TOK, 256, 0, stream>>>(x, w_rms1, nullptr, nrm_bf);
    mfma_gemm<0, 0, 0, 1, 64, 128, 256><<<dim3(12, 32, 1), 256, 0, stream>>>(
        nrm_bf, qkvT, nullptr, nullptr, nullptr, qkv_bf, nullptr, nullptr, nullptr,
        T_TOK, 1536, 1024, 0);
    mfma_attn<64><<<dim3(16, N_H, B_SZ), 256, 0, stream>>>(
        qkv_bf, qkv_bf + 1024, qkv_bf + 1280, ab_bf, 1536, 1024, N_H, N_KV, 0.125f);
    mfma_gemm<0, 0, 1, 1, 64, 128, 256><<<dim3(8, 32, 1), 256, 0, stream>>>(
        ab_bf, WoT, nullptr, x, h, h_bf, nullptr, nullptr, nullptr, T_TOK, 1024, 1024, 0);

    // ---- 2. ContextManager attention (8h/8kv, hd=128) ----
    mfma_gemm<0, 0, 0, 1, 64, 128, 256><<<dim3(24, 32, 1), 256, 0, stream>>>(
        h_bf, cqkvT, nullptr, nullptr, nullptr, qkv_bf, nullptr, nullptr, nullptr,
        T_TOK, 3072, 1024, 0);
    mfma_attn<128><<<dim3(16, N_CH, B_SZ), 256, 0, stream>>>(
        qkv_bf, qkv_bf + 1024, qkv_bf + 2048, ab_bf, 3072, 1024, N_CH, N_CH,
        0.088388347648318447f);
    mfma_gemm<0, 0, 1, 0, 64, 128, 256><<<dim3(8, 32, 1), 256, 0, stream>>>(
        ab_bf, CoT, nullptr, h, h, nullptr, nullptr, nullptr, nullptr, T_TOK, 1024, 1024, 0);

    // ---- 3. deltanet ----
    rmsnorm_kernel<<<T_TOK, 256, 0, stream>>>(h, w_rms2, nullptr, nrm_bf);
    mfma_gemm<0, 0, 0, 1, 64, 128, 256><<<dim3(16, 32, 1), 256, 0, stream>>>(
        nrm_bf, WiT, bi, nullptr, nullptr, gv_bf, nullptr, nullptr, nullptr, T_TOK, 2048, 1024, 0);
    conv_gate_kernel<<<(T_TOK * D_MOD) / 256, 256, 0, stream>>>(gv_bf, conv_w, conv_b, ab_bf);
    mfma_gemm<0, 0, 1, 0, 64, 128, 256><<<dim3(8, 32, 1), 256, 0, stream>>>(
        ab_bf, WodT, bod, h, h, nullptr, nullptr, nullptr, nullptr, T_TOK, 1024, 1024, 0);

    // ---- 4. MoE (top-2 of 8), expert->XCD affinity, small tiles for co-residency ----
    rmsnorm_kernel<<<T_TOK, 256, 0, stream>>>(h, w_rms3, nrm, nrm_bf);
    hipMemsetAsync(counts, 0, N_E * sizeof(int), stream);
    route_kernel<<<T_TOK, 256, 0, stream>>>(nrm, w_gate, tIdx, tScore, counts);
    prefix_kernel<<<1, 64, 0, stream>>>(counts, offs, cursor);
    fill_kernel<<<(T_TOK + 255) / 256, 256, 0, stream>>>(tIdx, offs, cursor, list, pairRow);
    // MoE1: 128x128 tile, 4 waves, 32KB LDS; grid = nx(32) * ny(16) * 8 experts (1-D)
    // typical active = 32*4*8 = 1024 blocks => ~4 blocks/CU co-resident
    mfma_gemm<1, 1, 0, 1, 128, 128, 256><<<32 * 16 * 8, 256, 0, stream>>>(
        nrm_bf, W1T, b1, nullptr, nullptr, hsel, list, offs, counts, T_TOK, FF_DIM, 1024, 32);
    // MoE2: 64x128 tile, 4 waves, 24KB LDS; grid = nx(8) * ny(32) * 8 experts (1-D)
    // typical active = 8*8*8 = 512 blocks => ~2 blocks/CU
    mfma_gemm<2, 0, 0, 1, 64, 128, 256><<<8 * 32 * 8, 256, 0, stream>>>(
        hsel, W2T, b2, nullptr, nullptr, ysel, list, offs, counts, T_TOK, 1024, FF_DIM, 8);
    combine_kernel<<<(T_TOK * D_MOD) / 256, 256, 0, stream>>>(ysel, tScore, pairRow, h);

    // ---- 5. final rmsnorm -> out ----
    rmsnorm_kernel<<<T_TOK, 256, 0, stream>>>(h, w_rms4, out, nullptr);
}